// Round 14
// baseline (1588.482 us; speedup 1.0000x reference)
//
#include <hip/hip_runtime.h>
#include <math.h>

#define NTOK 16130   // 1 + 127*127
#define NPAD 16384
#define PADF 254
#define NB   2
#define DM   512
#define NH   8
#define HD   64
#define LM   256
#define SEG  64

typedef __attribute__((ext_vector_type(8))) short short8v;
typedef __attribute__((ext_vector_type(4))) float f32x4;
typedef unsigned int u32;

// ---------------- helpers ----------------
__device__ __forceinline__ float wred_max(float v){
  #pragma unroll
  for(int o=32;o;o>>=1) v=fmaxf(v,__shfl_xor(v,o));
  return v;
}
__device__ __forceinline__ float wred_sum(float v){
  #pragma unroll
  for(int o=32;o;o>>=1) v+=__shfl_xor(v,o);
  return v;
}
__device__ __forceinline__ float block_max256(float v, float* s4){
  v=wred_max(v);
  if((threadIdx.x&63)==0) s4[threadIdx.x>>6]=v;
  __syncthreads();
  v=fmaxf(fmaxf(s4[0],s4[1]),fmaxf(s4[2],s4[3]));
  __syncthreads();
  return v;
}
__device__ __forceinline__ float block_sum256(float v, float* s4){
  v=wred_sum(v);
  if((threadIdx.x&63)==0) s4[threadIdx.x>>6]=v;
  __syncthreads();
  v=s4[0]+s4[1]+s4[2]+s4[3];
  __syncthreads();
  return v;
}
__device__ __forceinline__ unsigned short f2bf(float f){
  unsigned u=__float_as_uint(f);
  u = u + 0x7FFFu + ((u>>16)&1u);
  return (unsigned short)(u>>16);
}
__device__ __forceinline__ float bf2f(unsigned short u){
  return __uint_as_float(((unsigned)u)<<16);
}
__device__ __forceinline__ unsigned cvtpk(float a, float b){
  unsigned r;
  asm("v_cvt_pk_bf16_f32 %0, %1, %2" : "=v"(r) : "v"(a), "v"(b));
  return r;
}
// async global->LDS, 16B per lane
__device__ __forceinline__ void gl16(const unsigned short* g, unsigned short* l){
  __builtin_amdgcn_global_load_lds(
      (const __attribute__((address_space(1))) u32*)(g),
      (__attribute__((address_space(3))) u32*)(l), 16, 0, 0);
}

// ---------------- conversions ----------------
__global__ void k_f2bf4(const float* __restrict__ x, unsigned short* __restrict__ y, int n4){
  int i=blockIdx.x*256+threadIdx.x; if(i>=n4) return;
  float4 v=((const float4*)x)[i];
  ushort4 r; r.x=f2bf(v.x); r.y=f2bf(v.y); r.z=f2bf(v.z); r.w=f2bf(v.w);
  ((ushort4*)y)[i]=r;
}
// W[K][N] f32 -> Wt[N][K] bf16
__global__ void k_wconv_t(const float* __restrict__ W, unsigned short* __restrict__ Wt,
                          int K, int N){
  int idx=blockIdx.x*256+threadIdx.x; if(idx>=K*N) return;
  int k=idx/N, n=idx%N;
  Wt[(size_t)n*K+k]=f2bf(W[idx]);
}

// ---------------- MFMA bf16 GEMM: 128x128 tile, BK=32, XCD swizzle -----------
// ASRC 0: A bf16 row-major (global_load_lds staging)
// ASRC 3: A bf16 head-major [bb][8][NPAD][64] (global_load_lds staging)
template<int MODE, int ASRC>
__global__ __launch_bounds__(256) void k_mfma_gemm(
    const void* __restrict__ Ap, const unsigned short* __restrict__ Bt,
    int M, int N, int K,
    const float* __restrict__ bias,
    void* __restrict__ o0, void* __restrict__ o1, void* __restrict__ o2)
{
  __shared__ __align__(16) unsigned short Sh[128*64];   // As=Sh[0..4095], Bs=Sh[4096..]
  int t=threadIdx.x;
  int bx=blockIdx.x, by=blockIdx.y;
  { // bijective XCD swizzle (grid size divisible by 8)
    int gx=gridDim.x; int wg=by*gx+bx; int nwg=gx*gridDim.y;
    int cpx=nwg>>3; int x2=(wg&7)*cpx+(wg>>3);
    by=x2/gx; bx=x2-by*gx;
  }
  int row0=by*128, col0=bx*128;
  int lane=t&63, w=t>>6, wr=w>>1, wc=w&1, lr=lane&15, kg=lane>>4;
  f32x4 acc[4][4];
  #pragma unroll
  for(int m=0;m<4;m++)
    #pragma unroll
    for(int n=0;n<4;n++) acc[m][n]=(f32x4){0.f,0.f,0.f,0.f};

  for(int k0=0;k0<K;k0+=32){
    __syncthreads();   // previous tile fully consumed
    #pragma unroll
    for(int i=0;i<2;i++){
      int flat=i*256+t, r=flat>>2, k8=flat&3;
      int kofs=k0+k8*8;
      const unsigned short* asrc;
      if constexpr(ASRC==0){
        asrc=(const unsigned short*)Ap+(size_t)(row0+r)*K+kofs;
      } else {
        int rr2=row0+r; int bb=rr2>>14, ri=rr2&16383;
        int head=kofs>>6, dd=kofs&63;
        asrc=(const unsigned short*)Ap + (((size_t)bb*NH+head)*NPAD+ri)*HD + dd;
      }
      gl16(asrc, Sh+(size_t)flat*8);
      gl16(Bt+(size_t)(col0+r)*K+kofs, Sh+4096+(size_t)flat*8);
    }
    __syncthreads();   // data ready (vmcnt/lgkm drained before barrier)
    short8v af[4], bf[4];
    #pragma unroll
    for(int m=0;m<4;m++) af[m]=*(const short8v*)(Sh+(wr*64+m*16+lr)*32 + kg*8);
    #pragma unroll
    for(int n=0;n<4;n++) bf[n]=*(const short8v*)(Sh+4096+(wc*64+n*16+lr)*32 + kg*8);
    #pragma unroll
    for(int m=0;m<4;m++)
      #pragma unroll
      for(int n=0;n<4;n++)
        acc[m][n]=__builtin_amdgcn_mfma_f32_16x16x32_bf16(af[m],bf[n],acc[m][n],0,0,0);
  }
  // ---- epilogue ----
  if constexpr(MODE==1){
    // coalesced q/k/v store via LDS restage (2 passes of 64 rows x 128 cols bf16)
    #pragma unroll
    for(int p=0;p<2;p++){
      __syncthreads();
      #pragma unroll
      for(int mm=0;mm<2;mm++){
        int m=2*p+mm;
        #pragma unroll
        for(int n=0;n<4;n++){
          int cc=wc*64+n*16+lr;
          int c=col0+cc;
          float sc=((c>>9)==0)?0.125f:1.f;
          #pragma unroll
          for(int j=0;j<4;j++){
            int lrow=wr*32+mm*16+kg*4+j;
            Sh[lrow*128+cc]=f2bf(acc[m][n][j]*sc);
          }
        }
      }
      __syncthreads();
      #pragma unroll
      for(int i=0;i<4;i++){
        int p2=i*256+t;
        int r2=p2>>4, ck=p2&15;
        int grow=row0+(r2>>5)*64+(2*p+((r2>>4)&1))*16+(r2&15);
        int bb=grow>>14, rr=grow&16383;
        int c=col0+ck*8;
        int which=c>>9, hcol=c&511, head=hcol>>6, dd=hcol&63;
        unsigned short* dst=(which==0)?(unsigned short*)o0:
                            (which==1)?(unsigned short*)o1:(unsigned short*)o2;
        *(short8v*)(dst + (((size_t)bb*NH+head)*NPAD+rr)*HD+dd) =
            *(const short8v*)(Sh + r2*128 + ck*8);
      }
    }
  } else {
    #pragma unroll
    for(int m=0;m<4;m++){
      int rbase=row0 + wr*64 + m*16 + kg*4;
      #pragma unroll
      for(int j=0;j<4;j++){
        int r=rbase+j;
        #pragma unroll
        for(int n=0;n<4;n++){
          int c=col0 + wc*64 + n*16 + lr;
          float val=acc[m][n][j];
          if(MODE==0){
            float* h=(float*)o0;
            int bb=(r>=16000)?1:0, ii=r-bb*16000;
            float vv=fmaxf(val+bias[c],0.f);
            h[((size_t)bb*NTOK + 1 + ii)*DM + c]=vv;
            if(ii<129) h[((size_t)bb*NTOK + 16001 + ii)*DM + c]=vv;
          } else {
            float* h=(float*)o0;
            int bb=r>>14, rr=r&16383;
            if(rr>=PADF)
              h[((size_t)bb*NTOK + (rr-PADF))*DM + c]+=val+bias[c];
          }
        }
      }
    }
  }
}

__global__ void k_cls(const float* __restrict__ cls, float* __restrict__ h){
  int t=blockIdx.x*256+threadIdx.x;
  if(t<2*DM) h[(size_t)(t>>9)*NTOK*DM + (t&511)]=cls[t&511];
}

// ---------------- layernorm + front zero-pad -> bf16 ----------------
__global__ __launch_bounds__(256) void k_lnpad(
    const float* __restrict__ h, const float* __restrict__ g,
    const float* __restrict__ bta, unsigned short* __restrict__ xln)
{
  int r=blockIdx.x;
  int bb=r>>14, i=r&16383;
  int t=threadIdx.x;
  unsigned short* dst=xln+(size_t)r*DM;
  if(i<PADF){ dst[t]=0; dst[t+256]=0; return; }
  const float* src=h+((size_t)bb*NTOK + (i-PADF))*DM;
  float x0=src[t], x1=src[t+256];
  __shared__ float s4[4];
  float mu=block_sum256(x0+x1,s4)*(1.f/512.f);
  float d0=x0-mu, d1=x1-mu;
  float var=block_sum256(d0*d0+d1*d1,s4)*(1.f/512.f);
  float rst=rsqrtf(var+1e-5f);
  dst[t]    =f2bf(d0*rst*g[t]    +bta[t]);
  dst[t+256]=f2bf(d1*rst*g[t+256]+bta[t+256]);
}

// ---------------- landmark means, q and k in one launch ----------------
__global__ void k_lmean2(const unsigned short* __restrict__ qsrc,
                         const unsigned short* __restrict__ ksrc,
                         float* __restrict__ qlf, unsigned short* __restrict__ qlb_,
                         float* __restrict__ klf, unsigned short* __restrict__ klb_){
  int gid=blockIdx.x;
  const unsigned short* src; float* dstf; unsigned short* dstb;
  if(gid<4096){ src=qsrc; dstf=qlf; dstb=qlb_; }
  else        { src=ksrc; dstf=klf; dstb=klb_; gid-=4096; }
  int bh=gid>>8, s=gid&255, d=threadIdx.x;  // 64 threads
  const unsigned short* p=src + (((size_t)bh*NPAD)+s*SEG)*HD + d;
  float acc=0.f;
  #pragma unroll
  for(int l=0;l<SEG;l++) acc+=bf2f(p[(size_t)l*HD]);
  float m=acc*(1.f/64.f);
  dstf[((size_t)bh*LM+s)*HD+d]=m;
  dstb[((size_t)bh*LM+s)*HD+d]=f2bf(m);
}

// ---------------- v bf16 head-major -> vt bf16 [bh][64][NPAD] ----------------
__global__ __launch_bounds__(256) void k_vtrans(
    const unsigned short* __restrict__ v, unsigned short* __restrict__ vt)
{
  __shared__ unsigned short tile[64][72];
  int kt=blockIdx.x, bh=blockIdx.y;
  int t=threadIdx.x;
  int r=t>>2, sgq=t&3;
  const short8v* src=(const short8v*)(v + ((size_t)bh*NPAD + kt*64 + r)*HD + sgq*16);
  *(short8v*)(&tile[r][sgq*16])  =src[0];
  *(short8v*)(&tile[r][sgq*16+8])=src[1];
  __syncthreads();
  int d=t>>2;
  union{unsigned short u[16]; short8v v8[2];} pk;
  #pragma unroll
  for(int i=0;i<16;i++) pk.u[i]=tile[sgq*16+i][d];
  short8v* dst=(short8v*)(vt + ((size_t)bh*HD + d)*NPAD + kt*64 + sgq*16);
  dst[0]=pk.v8[0]; dst[1]=pk.v8[1];
}

// ---------------- attn2 = softmax(ql @ kl^T) f32 + fused hi/lo split --------
__global__ __launch_bounds__(256) void k_attn2(
    const float* __restrict__ ql, const float* __restrict__ kl,
    float* __restrict__ attn2,
    unsigned short* __restrict__ a2h, unsigned short* __restrict__ a2l)
{
  __shared__ float qrow[64]; __shared__ float s4[4];
  int bh=blockIdx.x>>8, i=blockIdx.x&255, j=threadIdx.x;
  if(j<64) qrow[j]=ql[((size_t)bh*LM+i)*HD+j];
  __syncthreads();
  const float* kp=kl+((size_t)bh*LM+j)*HD;
  float l=0.f;
  #pragma unroll
  for(int d=0;d<64;d++) l+=qrow[d]*kp[d];
  float m=block_max256(l,s4);
  float e=__expf(l-m);
  float s=block_sum256(e,s4);
  float pv=e/s;
  size_t o=((size_t)bh*LM+i)*LM+j;
  attn2[o]=pv;
  unsigned short hh=f2bf(pv);
  a2h[o]=hh; a2l[o]=f2bf(pv-bf2f(hh));
}

// ---------------- pinv helpers (rowsum of softmax == 1, skip it) ------------
__global__ void k_colsum(const float* __restrict__ x, float* __restrict__ cs){
  int bh=blockIdx.x, j=threadIdx.x;
  const float* p=x+(size_t)bh*65536;
  float s=0.f;
  for(int i=0;i<256;i++) s+=p[(size_t)i*256+j];
  cs[bh*256+j]=s;
}
__global__ void k_pinvscale(const float* __restrict__ cs, float* __restrict__ scale){
  __shared__ float s4[4];
  float mc=-1e30f;
  for(int i=threadIdx.x;i<4096;i+=256) mc=fmaxf(mc,cs[i]);
  mc=block_max256(mc,s4);
  if(threadIdx.x==0) scale[0]=1.f/mc;
}
__global__ void k_zinit_hl(const float* __restrict__ x, const float* __restrict__ scale,
    unsigned short* __restrict__ zh, unsigned short* __restrict__ zl,
    unsigned short* __restrict__ zth, unsigned short* __restrict__ ztl){
  int bh=blockIdx.x>>8, i=blockIdx.x&255, j=threadIdx.x;
  float s=scale[0];
  size_t base=(size_t)bh*65536;
  float vn=x[base+(size_t)j*256+i]*s;   // z0[i][j] = X^T * s
  float vt=x[base+(size_t)i*256+j]*s;   // z0^T[i][j]
  size_t o=base+(size_t)i*256+j;
  unsigned short h=f2bf(vn); zh[o]=h; zl[o]=f2bf(vn-bf2f(h));
  h=f2bf(vt); zth[o]=h; ztl[o]=f2bf(vt-bf2f(h));
}

// ---------------- hi/lo split bf16 MFMA batched GEMM (pinv chain) -----------
// MODE 0: C=A@B (emit normal+trans)    MODE 1: C=15I-7X+acc (trans only)
// MODE 2: C=13I-acc (trans only)       MODE 3: C=0.25*acc (normal+trans)
// MODE 4: C=acc (trans only, hi only; Ndim=64)
// PREC 0: single bf16 product; PREC 1: hi/lo 3-product (f32-equivalent)
template<int MODE, int PREC>
__global__ __launch_bounds__(256) void k_bmm3(
    const unsigned short* __restrict__ Ah, const unsigned short* __restrict__ Al,
    const unsigned short* __restrict__ Bth, const unsigned short* __restrict__ Btl,
    const unsigned short* __restrict__ Xh, const unsigned short* __restrict__ Xl,
    unsigned short* __restrict__ Cnh, unsigned short* __restrict__ Cnl,
    unsigned short* __restrict__ Cth, unsigned short* __restrict__ Ctl,
    int Ndim)
{
  __shared__ unsigned short AsH[64*40], BsH[64*40];
  __shared__ unsigned short AsL[PREC?64*40:8], BsL[PREC?64*40:8];
  int bh=blockIdx.z;
  int n0=blockIdx.x*64, m0=blockIdx.y*64;
  int t=threadIdx.x, lane=t&63, w=t>>6;
  int c=lane&15, g=lane>>4;
  int wr=(w>>1)*32, wc=(w&1)*32;
  f32x4 acc[2][2];
  #pragma unroll
  for(int i=0;i<2;i++)
    #pragma unroll
    for(int j=0;j<2;j++) acc[i][j]=(f32x4){0.f,0.f,0.f,0.f};
  size_t Abase=(size_t)bh*65536;
  size_t Bbase=(size_t)bh*(size_t)Ndim*256;
  int r=t>>2, sg=t&3;
  const unsigned short* Aptr=Ah +Abase+(size_t)(m0+r)*256+sg*8;
  const unsigned short* Bptr=Bth+Bbase+(size_t)(n0+r)*256+sg*8;
  const unsigned short* Alptr=Al +Abase+(size_t)(m0+r)*256+sg*8;
  const unsigned short* Blptr=Btl+Bbase+(size_t)(n0+r)*256+sg*8;
  short8v rah, rbh, ral, rbl;
  rah=*(const short8v*)(Aptr);
  rbh=*(const short8v*)(Bptr);
  if constexpr(PREC==1){ ral=*(const short8v*)(Alptr); rbl=*(const short8v*)(Blptr); }
  int k0=0;
  for(;;){
    __syncthreads();
    *(short8v*)(AsH+r*40+sg*8)=rah;
    *(short8v*)(BsH+r*40+sg*8)=rbh;
    if constexpr(PREC==1){
      *(short8v*)(AsL+r*40+sg*8)=ral;
      *(short8v*)(BsL+r*40+sg*8)=rbl;
    }
    __syncthreads();
    int kn=k0+32;
    if(kn<256){
      rah=*(const short8v*)(Aptr+kn);
      rbh=*(const short8v*)(Bptr+kn);
      if constexpr(PREC==1){
        ral=*(const short8v*)(Alptr+kn);
        rbl=*(const short8v*)(Blptr+kn);
      }
    }
    short8v bhf[2], blf[2];
    #pragma unroll
    for(int nt=0;nt<2;nt++){
      bhf[nt]=*(const short8v*)(BsH+(wc+nt*16+c)*40+g*8);
      if constexpr(PREC==1) blf[nt]=*(const short8v*)(BsL+(wc+nt*16+c)*40+g*8);
    }
    #pragma unroll
    for(int mt=0;mt<2;mt++){
      short8v ahh=*(const short8v*)(AsH+(wr+mt*16+c)*40+g*8);
      short8v all;
      if constexpr(PREC==1) all=*(const short8v*)(AsL+(wr+mt*16+c)*40+g*8);
      #pragma unroll
      for(int nt=0;nt<2;nt++){
        acc[mt][nt]=__builtin_amdgcn_mfma_f32_16x16x32_bf16(ahh,bhf[nt],acc[mt][nt],0,0,0);
        if constexpr(PREC==1){
          acc[mt][nt]=__builtin_amdgcn_mfma_f32_16x16x32_bf16(ahh,blf[nt],acc[mt][nt],0,0,0);
          acc[mt][nt]=__builtin_amdgcn_mfma_f32_16x16x32_bf16(all,bhf[nt],acc[mt][nt],0,0,0);
        }
      }
    }
    if(kn>=256) break;
    k0=kn;
  }
  #pragma unroll
  for(int mt=0;mt<2;mt++)
    #pragma unroll
    for(int nt=0;nt<2;nt++){
      int rb=m0+wr+mt*16+g*4;
      int cc=n0+wc+nt*16+c;
      float vv[4];
      #pragma unroll
      for(int j=0;j<4;j++){
        float a=acc[mt][nt][j];
        int rr=rb+j;
        if(MODE==1){
          float xv=bf2f(Xh[Abase+(size_t)rr*256+cc])+bf2f(Xl[Abase+(size_t)rr*256+cc]);
          a=(rr==cc?15.f:0.f)-7.f*xv+a;
        } else if(MODE==2){
          a=(rr==cc?13.f:0.f)-a;
        } else if(MODE==3){
          a*=0.25f;
        }
        vv[j]=a;
      }
      if(MODE==0||MODE==3){
        #pragma unroll
        for(int j=0;j<4;j++){
          unsigned short h=f2bf(vv[j]);
          Cnh[Abase+(size_t)(rb+j)*256+cc]=h;
          Cnl[Abase+(size_t)(rb+j)*256+cc]=f2bf(vv[j]-bf2f(h));
        }
      }
      {
        ushort4 hv, lv;
        hv.x=f2bf(vv[0]); hv.y=f2bf(vv[1]); hv.z=f2bf(vv[2]); hv.w=f2bf(vv[3]);
        lv.x=f2bf(vv[0]-bf2f(hv.x)); lv.y=f2bf(vv[1]-bf2f(hv.y));
        lv.z=f2bf(vv[2]-bf2f(hv.z)); lv.w=f2bf(vv[3]-bf2f(hv.w));
        size_t co=((size_t)bh*Ndim+cc)*256+rb;
        *(ushort4*)(Cth+co)=hv;
        if(MODE!=4) *(ushort4*)(Ctl+co)=lv;
      }
    }
}

// ---------------- attn3@v : MFMA flash, split-K 16 chunks --------------------
__global__ __launch_bounds__(512) void k_attn3m(
    const unsigned short* __restrict__ qlb,
    const unsigned short* __restrict__ kb,
    const unsigned short* __restrict__ vtb,
    float* __restrict__ pacc, float* __restrict__ pms)
{
  __shared__ unsigned short Ks[64*72];
  __shared__ unsigned short Vs[64*72];
  int ck=blockIdx.x, bh=blockIdx.y;
  int t=threadIdx.x, lane=t&63, w=t>>6;
  int c=lane&15, g=lane>>4;
  short8v Qf[2][2];
  #pragma unroll
  for(int n=0;n<2;n++)
    #pragma unroll
    for(int kw=0;kw<2;kw++)
      Qf[n][kw]=*(const short8v*)(qlb + ((size_t)bh*LM + w*32 + n*16 + c)*HD + kw*32 + g*8);
  f32x4 accO[4][2];
  float mrun[2], srun[2];
  #pragma unroll
  for(int n=0;n<2;n++){
    mrun[n]=-3e38f; srun[n]=0.f;
    #pragma unroll
    for(int d=0;d<4;d++) accO[d][n]=(f32x4){0.f,0.f,0.f,0.f};
  }
  int sr=t>>3, sgk=t&7;
  for(int sc=0;sc<16;++sc){
    int key0=ck*1024 + sc*64;
    __syncthreads();
    *(short8v*)(Ks + sr*72 + sgk*8) =
      *(const short8v*)(kb + ((size_t)bh*NPAD + key0 + sr)*HD + sgk*8);
    *(short8v*)(Vs + sr*72 + sgk*8) =
      *(const short8v*)(vtb + ((size_t)bh*HD + sr)*NPAD + key0 + sgk*8);
    __syncthreads();
    f32x4 s[4][2];
    #pragma unroll
    for(int mt=0;mt<4;mt++){
      short8v a0=*(const short8v*)(Ks + (mt*16+c)*72 + g*8);
      short8v a1=*(const short8v*)(Ks + (mt*16+c)*72 + 32 + g*8);
      #pragma unroll
      for(int n=0;n<2;n++){
        f32x4 z=(f32x4){0.f,0.f,0.f,0.f};
        z=__builtin_amdgcn_mfma_f32_16x16x32_bf16(a0,Qf[n][0],z,0,0,0);
        z=__builtin_amdgcn_mfma_f32_16x16x32_bf16(a1,Qf[n][1],z,0,0,0);
        s[mt][n]=z;
      }
    }
    unsigned U[2][4][2];
    #pragma unroll
    for(int n=0;n<2;n++){
      float cm=-3e38f;
      #pragma unroll
      for(int mt=0;mt<4;mt++)
        #pragma unroll
        for(int j=0;j<4;j++) cm=fmaxf(cm,s[mt][n][j]);
      cm=fmaxf(cm,__shfl_xor(cm,16));
      cm=fmaxf(cm,__shfl_xor(cm,32));
      float mnew=fmaxf(mrun[n],cm);
      float f=__expf(mrun[n]-mnew);
      mrun[n]=mnew;
      float ps=0.f;
      #pragma unroll
      for(int mt=0;mt<4;mt++){
        float p0=__expf(s[mt][n][0]-mnew);
        float p1=__expf(s[mt][n][1]-mnew);
        float p2=__expf(s[mt][n][2]-mnew);
        float p3=__expf(s[mt][n][3]-mnew);
        ps+=p0+p1+p2+p3;
        U[n][mt][0]=cvtpk(p0,p1);
        U[n][mt][1]=cvtpk(p2,p3);
      }
      ps+=__shfl_xor(ps,16); ps+=__shfl_xor(ps,32);
      srun[n]=srun[n]*f+ps;
      #pragma unroll
      for(int d=0;d<4;d++){
        accO[d][n][0]*=f; accO[d][n][1]*=f; accO[d][n][2]*=f; accO[d][n][3]*=f;
      }
    }
    #pragma unroll
    for(int kw=0;kw<2;kw++){
      short8v pf[2];
      #pragma unroll
      for(int n=0;n<2;n++){
        union{unsigned u[4]; short8v v;} pk;
        #pragma unroll
        for(int wd=0;wd<4;wd++){
          int sl=c+16*(((g&1)<<1)+(wd>>1));
          unsigned va=(unsigned)__shfl((int)U[n][kw*2  ][wd&1],sl);
          unsigned vb=(unsigned)__shfl((int)U[n][kw*2+1][wd&1],sl);
          pk.u[wd]=(lane>=32)?vb:va;
        }
        pf[n]=pk.v;
      }
      #pragma unroll
      for(int d=0;d<4;d++){
        short8v vf=*(const short8v*)(Vs + (d*16+c)*72 + kw*32 + g*8);
        accO[d][0]=__builtin_amdgcn_mfma_f32_16x16x32_bf16(vf,pf[0],accO[d][0],0,0,0);
        accO[d][1]=__builtin_amdgcn_mfma_f32_16x16x32_bf16(vf,pf[1],accO[d][1],0,0,0);
      }
    }
  }
  size_t pb=((size_t)bh*16+ck)*LM;
  #pragma unroll
  for(int n=0;n<2;n++){
    int q=w*32+n*16+c;
    #pragma unroll
    for(int d=0;d<4;d++)
      *(f32x4*)(pacc + (pb+q)*HD + d*16 + g*4)=accO[d][n];
    if(g==0){ pms[(pb+q)*2]=mrun[n]; pms[(pb+q)*2+1]=srun[n]; }
  }
}
__global__ __launch_bounds__(256) void k_attn3vc(
    const float* __restrict__ pacc, const float* __restrict__ pms,
    unsigned short* __restrict__ a3vth, unsigned short* __restrict__ a3vtl)
{
  int gid=blockIdx.x*4+(threadIdx.x>>6);
  int bh=gid>>8, row=gid&255, lane=threadIdx.x&63;
  float M=-3e38f;
  float ms[16], ss[16];
  #pragma unroll
  for(int c=0;c<16;c++){
    size_t pb=((size_t)bh*16+c)*LM+row;
    ms[c]=pms[pb*2]; ss[c]=pms[pb*2+1];
    M=fmaxf(M,ms[c]);
  }
  float S=0.f,a=0.f;
  #pragma unroll
  for(int c=0;c<16;c++){
    float f=__expf(ms[c]-M);
    S+=ss[c]*f;
    a+=pacc[(((size_t)bh*16+c)*LM+row)*HD+lane]*f;
  }
  float v=a/S;
  unsigned short hi=f2bf(v);
  a3vth[((size_t)bh*HD+lane)*LM+row]=hi;
  a3vtl[((size_t)bh*HD+lane)*LM+row]=f2bf(v-bf2f(hi));
}

// ---------------- attn1 @ W2 : MFMA, 256 landmarks one-shot; bf16 out --------
__global__ __launch_bounds__(512) void k_attn1m(
    const unsigned short* __restrict__ qb,
    const unsigned short* __restrict__ klb,
    const unsigned short* __restrict__ w2t,
    unsigned short* __restrict__ aohb)
{
  __shared__ unsigned short klS[256*72];
  __shared__ unsigned short w2S[64*264];
  int qt=blockIdx.x, bh=blockIdx.y;
  int t=threadIdx.x, lane=t&63, w=t>>6;
  int c=lane&15, g=lane>>4;
  {
    int r=t>>1, hf=t&1;
    const short8v* s=(const short8v*)(klb + ((size_t)bh*LM+r)*HD + hf*32);
    short8v* d=(short8v*)(klS + r*72 + hf*32);
    d[0]=s[0]; d[1]=s[1]; d[2]=s[2]; d[3]=s[3];
    int r2=t>>3, sg2=t&7;
    const short8v* s2=(const short8v*)(w2t + ((size_t)bh*HD+r2)*LM + sg2*32);
    short8v* d2=(short8v*)(w2S + r2*264 + sg2*32);
    d2[0]=s2[0]; d2[1]=s2[1]; d2[2]=s2[2]; d2[3]=s2[3];
  }
  __syncthreads();
  int q0=qt*256 + w*32;
  #pragma unroll
  for(int n=0;n<2;n++){
    const unsigned short* qrow=qb + ((size_t)bh*NPAD + q0 + n*16 + c)*HD;
    short8v qf0=*(const short8v*)(qrow + g*8);
    short8v qf1=*(const short8v*)(qrow + 32 + g*8);
    f32x4 s[16];
    #pragma unroll
    for(int mt=0;mt<16;mt++){
      short8v a0=*(const short8v*)(klS + (mt*16+c)*72 + g*8);
      short8v a1=*(const short8v*)(klS + (mt*16+c)*72 + 32 + g*8);
      f32x4 z=(f32x4){0.f,0.f,0.f,0.f};
      z=__builtin_amdgcn_mfma_f32_16x16x32_bf16(a0,qf0,z,0,0,0);
      z=__builtin_amdgcn_mfma_f32_16x16x32_bf16(a1,qf1,z,0,0,0);
      s[mt]=z;
    }
    float M=-3e38f;
    #pragma unroll
    for(int mt=0;mt<16;mt++)
      #pragma unroll
      for(int j=0;j<4;j++) M=fmaxf(M,s[mt][j]);
    M=fmaxf(M,__shfl_xor(M,16));
    M=fmaxf(M,__shfl_xor(M,32));
    float sum=0.f;
    unsigned U[16][2];
    #pragma unroll
    for(int mt=0;mt<16;mt++){
      float p0=__expf(s[mt][0]-M);
      float p1=__expf(s[mt][1]-M);
      float p2=__expf(s[mt][2]-M);
      float p3=__expf(s[mt][3]-M);
      sum+=p0+p1+p2+p3;
      U[mt][0]=cvtpk(p0,p1);
      U[mt][1]=cvtpk(p2,p3);
    }
    sum+=__shfl_xor(sum,16); sum+=__shfl_xor(sum,32);
    float inv=1.f/sum;
    f32x4 accO[4];
    #pragma unroll
    for(int d=0;d<4;d++) accO[d]=(f32x4){0.f,0.f,0.f,0.f};
    #pragma unroll
    for(int kw=0;kw<8;kw++){
      union{unsigned u[4]; short8v v;} pk;
      #pragma unroll
      for(int wd=0;wd<4;wd++){
        int sl=c+16*(((g&1)<<1)+(wd>>1));
        unsigned va=(unsigned)__shfl((int)U[kw*2  ][wd&1],sl);
        unsigned vb=(unsigned)__shfl((int)U[kw*2+1][wd&1],sl);
        pk.u[wd]=(lane>=32)?vb:va;
      }
      #pragma unroll
      for(int d=0;d<4;d++){
        short8v vf=*(const short8v*)(w2S + (d*16+c)*264 + kw*32 + g*8);
        accO[d]=__builtin_amdgcn_mfma_f32_16x16x32_bf16(vf,pk.v,accO[d],0,0,0);
      }
    }
    int q=q0+n*16+c;
    #pragma unroll
    for(int d=0;d<4;d++){
      f32x4 o=accO[d];
      uint2 pk2;
      pk2.x=cvtpk(o[0]*inv, o[1]*inv);
      pk2.y=cvtpk(o[2]*inv, o[3]*inv);
      *(uint2*)(aohb + ((size_t)bh*NPAD+q)*HD + d*16 + g*4)=pk2;
    }
  }
}

// ---------------- depthwise 33-tap conv from vt; aoh bf16 += -----------------
__global__ __launch_bounds__(256) void k_resconv2(
    const unsigned short* __restrict__ vt, const float* __restrict__ rw,
    unsigned short* __restrict__ aohb){
  int bx=blockIdx.x, bh=blockIdx.y;
  int t=threadIdx.x, d=t&63, g=t>>6;
  int i0=bx*32+g*8;
  int hh=bh&7;
  const unsigned short* vr=vt + ((size_t)bh*HD + d)*NPAD;
  float wv[40];
  int start=i0-16;
  if(start>=0 && start+40<=NPAD){
    #pragma unroll
    for(int b=0;b<5;b++){
      short8v v8=*(const short8v*)(vr+start+b*8);
      #pragma unroll
      for(int j=0;j<8;j++) wv[b*8+j]=bf2f((unsigned short)v8[j]);
    }
  } else {
    #pragma unroll
    for(int t2=0;t2<40;t2++){
      int src=start+t2;
      wv[t2]=(src>=0&&src<NPAD)?bf2f(vr[src]):0.f;
    }
  }
  const float* wt=rw+hh*33;
  #pragma unroll
  for(int p=0;p<8;p++){
    float a=0.f;
    #pragma unroll
    for(int tk=0;tk<33;tk++) a+=wv[p+tk]*wt[tk];
    size_t o=((size_t)bh*NPAD+i0+p)*HD+d;
    aohb[o]=f2bf(bf2f(aohb[o])+a);
  }
}

// ---------------- PPEG weight prep: combined 7x7 tap table (bf16) -----------
__global__ void k_wprep(const float* __restrict__ w7, const float* __restrict__ b7,
                        const float* __restrict__ w5, const float* __restrict__ b5,
                        const float* __restrict__ w3, const float* __restrict__ b3,
                        unsigned short* __restrict__ wcat){
  int t=blockIdx.x*256+threadIdx.x;
  if(t>=50*512) return;
  int r=t>>9, c=t&511;
  float v;
  if(r<49){
    int ky=r/7, kx=r%7;
    v=w7[(size_t)c*49+r];
    if(ky>=1&&ky<=5&&kx>=1&&kx<=5) v+=w5[(size_t)c*25+(ky-1)*5+(kx-1)];
    if(ky>=2&&ky<=4&&kx>=2&&kx<=4) v+=w3[(size_t)c*9+(ky-2)*3+(kx-2)];
  } else {
    v=b7[c]+b5[c]+b3[c];
  }
  wcat[t]=f2bf(v);
}

// ---------------- PPEG: 8x8 tile x 32ch, f32 patch, sliding row window ------
__global__ __launch_bounds__(256,5) void k_ppeg4(
    const float* __restrict__ src, const unsigned short* __restrict__ wcat,
    float* __restrict__ dst)
{
  __shared__ float patch[196][32];   // 14x14 halo
  __shared__ float wsf[50][32];
  int bx=blockIdx.x;
  int cz=blockIdx.y, bb=blockIdx.z;
  int t=threadIdx.x, c=t&31, g=t>>5;   // 32ch x 8 groups
  int ty0=(bx>>4)*8, tx0=(bx&15)*8;
  const float* base=src+((size_t)bb*NTOK+1)*DM + cz*32 + c;
  #pragma unroll
  for(int i=0;i<25;i++){
    int p=g+8*i;
    if(p<196){
      int py=p/14, px=p%14;
      int yy=ty0-3+py, xx=tx0-3+px;
      float v=0.f;
      if(yy>=0&&yy<127&&xx>=0&&xx<127) v=base[(size_t)(yy*127+xx)*DM];
      patch[p][c]=v;
    }
  }
  #pragma unroll
  for(int i=0;i<7;i++){
    int r=g+8*i; if(r<50) wsf[r][c]=bf2f(wcat[(size_t)r*DM + cz*32 + c]);
  }
  __syncthreads();
  float acc[8];
  float bias=wsf[49][c];
  #pragma unroll
  for(int j=0;j<8;j++) acc[j]=patch[(g+3)*14+(j+3)][c]+bias;  // exact identity
  #pragma unroll
  for(int ky=0;ky<7;ky++){
    float win[14];
    #pragma unroll
    for(int x=0;x<14;x++) win[x]=patch[(g+ky)*14+x][c];
    #pragma unroll
    for(int kx=0;kx<7;kx++){
      float wv=wsf[ky*7+kx][c];
      #pragma unroll
      for(int j=0;j<8;j++) acc[j]+=win[j+kx]*wv;
    }
  }
  int y=ty0+g;
  if(y<127){
    #pragma unroll
    for(int j=0;j<8;j++){
      int x=tx0+j;
      if(x<127)
        dst[((size_t)bb*NTOK+1+(size_t)(y*127+x))*DM + cz*32 + c]=acc[j];
    }
  }
}

// copy cls row h -> dst
__global__ void k_cpcls(const float* __restrict__ h, float* __restrict__ dst){
  int t=blockIdx.x*256+threadIdx.x;
  if(t<2*DM) dst[(size_t)(t>>9)*NTOK*DM + (t&511)]=h[(size_t)(t>>9)*NTOK*DM + (t&511)];
}

// ---------------- final: LN(h[:,0]) @ fc2 + b ----------------
__global__ __launch_bounds__(256) void k_final(
    const float* __restrict__ h, const float* __restrict__ g, const float* __restrict__ bta,
    const float* __restrict__ w, const float* __restrict__ fb, float* __restrict__ out)
{
  int bb=blockIdx.x, t=threadIdx.x;
  const float* src=h+(size_t)bb*NTOK*DM;
  float x0=src[t], x1=src[t+256];
  __shared__ float s4[4];
  float mu=block_sum256(x0+x1,s4)*(1.f/512.f);
  float d0=x0-mu, d1=x1-mu;
  float var=block_sum256(d0*d0+d1*d1,s4)*(1.f/512.f);
  float rst=rsqrtf(var+1e-5f);
  float y0=d0*rst*g[t]+bta[t], y1=d1*rst*g[t+256]+bta[t+256];
  float dot=block_sum256(y0*w[t]+y1*w[t+256],s4);
  if(t==0) out[bb]=dot+fb[0];
}

// =======================================================================
extern "C" void kernel_launch(void* const* d_in, const int* in_sizes, int n_in,
                              void* d_out, int out_size, void* d_ws, size_t ws_size,
                              hipStream_t stream){
  (void)in_sizes; (void)n_in; (void)out_size; (void)ws_size;
  const float* features=(const float*)d_in[0];
  const float* fc1_w  =(const float*)d_in[1];
  const float* fc1_b  =(const float*)d_in[2];
  const float* cls_tok=(const float*)d_in[3];
  const float* fc2_w  =(const float*)d_in[24];
  const float* fc2_b  =(const float*)d_in[25];
  float* out=(float*)d_out;

  char* wp=(char*)d_ws;
  auto allocB=[&](size_t bytes)->char*{
    char* p=wp; wp+=((bytes+255)/256)*256; return p;
  };
  float* h    =(float*)allocB((size_t)NB*NTOK*DM*4);
  float* h2   =(float*)allocB((size_t)NB*NTOK*DM*4);
  unsigned short* vb  =(unsigned short*)allocB((size_t)NB*NPAD*DM*2);
  unsigned short* xlnb=(unsigned short*)allocB((size_t)NB*NPAD*DM*2);
  unsigned short* qb  =(unsigned short*)allocB((size_t)NB*NPAD*DM*2);
  unsigned short* kb  =(unsigned short*)allocB((size_t)NB*NPAD*DM*2);
  unsigned short* vtb =(unsigned short*)allocB((size_t)NB*NPAD*DM*2);
  unsigned short* aohb=(unsigned short*)allocB((size_t)NB*NPAD*DM*2);
  unsigned short* wtf=(unsigned short*)allocB((size_t)512*1024*2);
  unsigned short* wtq=(unsigned short*)allocB((size_t)1536*512*2);
  unsigned short* wtp=(unsigned short*)allocB((size_t)512*512*2);
  float* ql =(float*)allocB((size_t)16*LM*HD*4);
  float* kl =(float*)allocB((size_t)16*LM*HD*4);
  unsigned short* qlb=(unsigned short*)allocB((size_t)16*LM*HD*2);
  unsigned short* klb=(unsigned short*)allocB((size_t)16*LM*HD*2);
  float* attn2=(float*)allocB((size_t)16*LM*LM*4);
  unsigned short* a2h=(unsigned short*)allocB((size_t)16*LM*LM*2);
  unsigned short* a2l=(unsigned short*)allocB((size_t)16*LM*LM*2);
  unsigned short* zb[8];
  for(int i=0;i<8;i++) zb[i]=(unsigned short*)allocB((size_t)16*LM*LM*2);
  unsigned short* Abh=(unsigned short*)allocB((size_t)16*LM*LM*2);
  unsigned short* Abl=(unsigned short*)allocB((size_t)16*LM*LM*2);
  unsigned short* Abth=(unsigned short*)allocB((size_t)16*LM*LM*2);
  unsigned short* Abtl=(unsigned short*)allocB((size_t)16*LM*LM*2);
  unsigned short* Ubth=(unsigned short*)allocB((size_t)16*LM*LM*2);
  unsigned short* Ubtl=(unsigned short*)allocB((size_t)16*LM*LM*2);
  unsigned short* Tbth=(unsigned short*)allocB((size_t)16*LM*LM*2);
  unsigned short* Tbtl=(unsigned short*)allocB((size_t)16*LM*LM*2);
  unsigned short* a3vth=(unsigned short*)allocB((size_t)16*HD*LM*2);
  unsigned short* a3vtl=(unsigned short*)allocB((size_t)16*HD*LM*2);
  unsigned short* w2t=(unsigned short*)allocB((size_t)16*HD*LM*2);
  float* pacc=(float*)allocB((size_t)16*16*LM*HD*4);
  float* pms =(float*)allocB((size_t)16*16*LM*2*4);
  float* cs  =(float*)allocB(4096*4);
  float* scl =(float*)allocB(64*4);

  auto nystrom=[&](float* hbuf, const float* ng, const float* nbias, const float* qkvw,
                   const float* outw, const float* outb, const float* resw){
    k_lnpad<<<NB*NPAD,256,0,stream>>>(hbuf, ng, nbias, xlnb);
    k_wconv_t<<<(512*1536+255)/256,256,0,stream>>>(qkvw, wtq, 512, 1536);
    k_mfma_gemm<1,0><<<dim3(12,256),256,0,stream>>>(xlnb, wtq, 32768,1536,512,
                                                    nullptr, qb, kb, vb);
    k_lmean2<<<8192,64,0,stream>>>(qb, kb, ql, qlb, kl, klb);
    k_vtrans<<<dim3(256,16),256,0,stream>>>(vb, vtb);
    k_attn2<<<4096,256,0,stream>>>(ql, kl, attn2, a2h, a2l);
    k_colsum<<<16,256,0,stream>>>(attn2, cs);
    k_pinvscale<<<1,256,0,stream>>>(cs, scl);
    k_zinit_hl<<<4096,256,0,stream>>>(attn2, scl, zb[0],zb[1],zb[2],zb[3]);
    unsigned short *zch=zb[0],*zcl=zb[1],*zcth=zb[2],*zctl=zb[3];
    unsigned short *znh=zb[4],*znl=zb[5],*znth=zb[6],*zntl=zb[7];
    for(int it=0;it<6;it++){
      if(it<5){
        k_bmm3<0,0><<<dim3(4,4,16),256,0,stream>>>(a2h,a2l, zcth,zctl, nullptr,nullptr,
                                                   Abh,Abl, Abth,Abtl, 256);
        k_bmm3<1,0><<<dim3(4,4,16),256,0,stream>>>(Abh,Abl, Abth,Abtl, Abh,Abl,
                                                   nullptr,nullptr, Ubth,Ubtl, 256);
        k_bmm3<2,0><<<dim3(4,4,16),256,0,stream>>>(Abh,Abl, Ubth,Ubtl, nullptr,nullptr,
                                                   nullptr,nullptr, Tbth,Tbtl, 256);
        k_bmm3<3,0><<<dim3(4,4,16),256,0,stream>>>(zch,zcl, Tbth,Tbtl, nullptr,nullptr,
                                                   znh,znl, znth,zntl, 256);
      } else {
        k_bmm3<0,1><<<dim3(4,4,16),256,0,stream>>>(a2h,a2l, zcth,zctl, nullptr,nullptr,
                                                   Abh,Abl, Abth,Abtl, 256);
        k_bmm3<1,1><<<dim3(4,4,16),256,0,stream>>>(Abh,Abl, Abth,Abtl, Abh,Abl,
                                                   nullptr,nullptr, Ubth,Ubtl, 256);
        k_bmm3<2,1><<<dim3(4,4,16),256,0,stream>>>(Abh,Abl, Ubth,Ubtl, nullptr,nullptr,
                                                   nullptr,nullptr, Tbth,Tbtl, 256);
        k_bmm3<3,1><<<dim3(4,4,16),256,0,stream>>>(zch,zcl, Tbth,Tbtl, nullptr,nullptr,
                                                   znh,znl, znth,zntl, 256);
      }
      unsigned short* tp;
      tp=zch; zch=znh; znh=tp;  tp=zcl; zcl=znl; znl=tp;
      tp=zcth; zcth=znth; znth=tp;  tp=zctl; zctl=zntl; zntl=tp;
    }
    k_attn3m<<<dim3(16,16),512,0,stream>>>(qlb, kb, vtb, pacc, pms);
    k_attn3vc<<<1024,256,0,stream>>>(pacc, pms, a3vth, a3vtl);
    k_bmm3<4,1><<<dim3(1,4,16),256,0,stream>>>(zch,zcl, a3vth,a3vtl, nullptr,nullptr,
                                               nullptr,nullptr, w2t,nullptr, 64);
    k_attn1m<<<dim3(64,16),512,0,stream>>>(qb, klb, w2t, aohb);
    k_resconv2<<<dim3(512,16),256,0,stream>>>(vtb, resw, aohb);
    k_wconv_t<<<(512*512+255)/256,256,0,stream>>>(outw, wtp, 512, 512);
    k_mfma_gemm<2,3><<<dim3(4,256),256,0,stream>>>(aohb, wtp, 32768,512,512,
                                                   outb, hbuf, nullptr, nullptr);
  };

  // fc1: features -> bf16 (h2 overlay), then MFMA GEMM via global_load_lds
  unsigned short* featbf=(unsigned short*)h2;   // dead before PPEG
  k_f2bf4<<<32000,256,0,stream>>>(features, featbf, 32000*1024/4);
  k_wconv_t<<<(1024*512+255)/256,256,0,stream>>>(fc1_w, wtf, 1024, 512);
  k_mfma_gemm<0,0><<<dim3(4,250),256,0,stream>>>(featbf, wtf, 32000,512,1024,
                                                 fc1_b, h, nullptr, nullptr);
  k_cls<<<4,256,0,stream>>>(cls_tok, h);

  // layer 1 attention (on h)
  nystrom(h, (const float*)d_in[4],(const float*)d_in[5],(const float*)d_in[6],
          (const float*)d_in[7],(const float*)d_in[8],(const float*)d_in[9]);

  // PPEG: combined-tap stencil h -> h2 (no copy-back; layer 2 runs on h2)
  {
    unsigned short* wcat=(unsigned short*)attn2;  // free at this point
    k_wprep<<<100,256,0,stream>>>(
        (const float*)d_in[10],(const float*)d_in[11],
        (const float*)d_in[12],(const float*)d_in[13],
        (const float*)d_in[14],(const float*)d_in[15], wcat);
    k_cpcls<<<4,256,0,stream>>>(h, h2);
    k_ppeg4<<<dim3(256,16,2),256,0,stream>>>(h, wcat, h2);
  }

  // layer 2 attention (on h2)
  nystrom(h2, (const float*)d_in[16],(const float*)d_in[17],(const float*)d_in[18],
          (const float*)d_in[19],(const float*)d_in[20],(const float*)d_in[21]);

  // final LN(h2[:,0]) @ fc2
  k_final<<<2,256,0,stream>>>(h2,(const float*)d_in[22],(const float*)d_in[23],
                              fc2_w, fc2_b, out);
}

// Round 15
// 1329.839 us; speedup vs baseline: 1.1945x; 1.1945x over previous
//
#include <hip/hip_runtime.h>
#include <math.h>

#define NTOK 16130   // 1 + 127*127
#define NPAD 16384
#define PADF 254
#define NB   2
#define DM   512
#define NH   8
#define HD   64
#define LM   256
#define SEG  64

typedef __attribute__((ext_vector_type(8))) short short8v;
typedef __attribute__((ext_vector_type(4))) float f32x4;
typedef unsigned int u32;

// ---------------- helpers ----------------
__device__ __forceinline__ float wred_max(float v){
  #pragma unroll
  for(int o=32;o;o>>=1) v=fmaxf(v,__shfl_xor(v,o));
  return v;
}
__device__ __forceinline__ float wred_sum(float v){
  #pragma unroll
  for(int o=32;o;o>>=1) v+=__shfl_xor(v,o);
  return v;
}
__device__ __forceinline__ float block_max256(float v, float* s4){
  v=wred_max(v);
  if((threadIdx.x&63)==0) s4[threadIdx.x>>6]=v;
  __syncthreads();
  v=fmaxf(fmaxf(s4[0],s4[1]),fmaxf(s4[2],s4[3]));
  __syncthreads();
  return v;
}
__device__ __forceinline__ float block_sum256(float v, float* s4){
  v=wred_sum(v);
  if((threadIdx.x&63)==0) s4[threadIdx.x>>6]=v;
  __syncthreads();
  v=s4[0]+s4[1]+s4[2]+s4[3];
  __syncthreads();
  return v;
}
__device__ __forceinline__ unsigned short f2bf(float f){
  unsigned u=__float_as_uint(f);
  u = u + 0x7FFFu + ((u>>16)&1u);
  return (unsigned short)(u>>16);
}
__device__ __forceinline__ float bf2f(unsigned short u){
  return __uint_as_float(((unsigned)u)<<16);
}
__device__ __forceinline__ unsigned cvtpk(float a, float b){
  unsigned r;
  asm("v_cvt_pk_bf16_f32 %0, %1, %2" : "=v"(r) : "v"(a), "v"(b));
  return r;
}
// async global->LDS, 16B per lane
__device__ __forceinline__ void gl16(const unsigned short* g, unsigned short* l){
  __builtin_amdgcn_global_load_lds(
      (const __attribute__((address_space(1))) u32*)(g),
      (__attribute__((address_space(3))) u32*)(l), 16, 0, 0);
}

// ---------------- conversions ----------------
__global__ void k_f2bf4(const float* __restrict__ x, unsigned short* __restrict__ y, int n4){
  int i=blockIdx.x*256+threadIdx.x; if(i>=n4) return;
  float4 v=((const float4*)x)[i];
  ushort4 r; r.x=f2bf(v.x); r.y=f2bf(v.y); r.z=f2bf(v.z); r.w=f2bf(v.w);
  ((ushort4*)y)[i]=r;
}
// W[K][N] f32 -> Wt[N][K] bf16
__global__ void k_wconv_t(const float* __restrict__ W, unsigned short* __restrict__ Wt,
                          int K, int N){
  int idx=blockIdx.x*256+threadIdx.x; if(idx>=K*N) return;
  int k=idx/N, n=idx%N;
  Wt[(size_t)n*K+k]=f2bf(W[idx]);
}

// ---------------- MFMA bf16 GEMM: 128x128 tile, BK=32, XCD swizzle -----------
// ASRC 0: A bf16 row-major (global_load_lds staging)
// ASRC 3: A bf16 head-major [bb][8][NPAD][64] (global_load_lds staging)
template<int MODE, int ASRC>
__global__ __launch_bounds__(256) void k_mfma_gemm(
    const void* __restrict__ Ap, const unsigned short* __restrict__ Bt,
    int M, int N, int K,
    const float* __restrict__ bias,
    void* __restrict__ o0, void* __restrict__ o1, void* __restrict__ o2)
{
  __shared__ __align__(16) unsigned short Sh[128*64];   // As=Sh[0..4095], Bs=Sh[4096..]
  int t=threadIdx.x;
  int bx=blockIdx.x, by=blockIdx.y;
  { // bijective XCD swizzle (grid size divisible by 8)
    int gx=gridDim.x; int wg=by*gx+bx; int nwg=gx*gridDim.y;
    int cpx=nwg>>3; int x2=(wg&7)*cpx+(wg>>3);
    by=x2/gx; bx=x2-by*gx;
  }
  int row0=by*128, col0=bx*128;
  int lane=t&63, w=t>>6, wr=w>>1, wc=w&1, lr=lane&15, kg=lane>>4;
  f32x4 acc[4][4];
  #pragma unroll
  for(int m=0;m<4;m++)
    #pragma unroll
    for(int n=0;n<4;n++) acc[m][n]=(f32x4){0.f,0.f,0.f,0.f};

  for(int k0=0;k0<K;k0+=32){
    __syncthreads();   // previous tile fully consumed
    #pragma unroll
    for(int i=0;i<2;i++){
      int flat=i*256+t, r=flat>>2, k8=flat&3;
      int kofs=k0+k8*8;
      const unsigned short* asrc;
      if constexpr(ASRC==0){
        asrc=(const unsigned short*)Ap+(size_t)(row0+r)*K+kofs;
      } else {
        int rr2=row0+r; int bb=rr2>>14, ri=rr2&16383;
        int head=kofs>>6, dd=kofs&63;
        asrc=(const unsigned short*)Ap + (((size_t)bb*NH+head)*NPAD+ri)*HD + dd;
      }
      gl16(asrc, Sh+(size_t)flat*8);
      gl16(Bt+(size_t)(col0+r)*K+kofs, Sh+4096+(size_t)flat*8);
    }
    __syncthreads();   // data ready (vmcnt/lgkm drained before barrier)
    short8v af[4], bf[4];
    #pragma unroll
    for(int m=0;m<4;m++) af[m]=*(const short8v*)(Sh+(wr*64+m*16+lr)*32 + kg*8);
    #pragma unroll
    for(int n=0;n<4;n++) bf[n]=*(const short8v*)(Sh+4096+(wc*64+n*16+lr)*32 + kg*8);
    #pragma unroll
    for(int m=0;m<4;m++)
      #pragma unroll
      for(int n=0;n<4;n++)
        acc[m][n]=__builtin_amdgcn_mfma_f32_16x16x32_bf16(af[m],bf[n],acc[m][n],0,0,0);
  }
  // ---- epilogue ----
  if constexpr(MODE==1){
    // coalesced q/k/v store via LDS restage (2 passes of 64 rows x 128 cols bf16)
    #pragma unroll
    for(int p=0;p<2;p++){
      __syncthreads();
      #pragma unroll
      for(int mm=0;mm<2;mm++){
        int m=2*p+mm;
        #pragma unroll
        for(int n=0;n<4;n++){
          int cc=wc*64+n*16+lr;
          int c=col0+cc;
          float sc=((c>>9)==0)?0.125f:1.f;
          #pragma unroll
          for(int j=0;j<4;j++){
            int lrow=wr*32+mm*16+kg*4+j;
            Sh[lrow*128+cc]=f2bf(acc[m][n][j]*sc);
          }
        }
      }
      __syncthreads();
      #pragma unroll
      for(int i=0;i<4;i++){
        int p2=i*256+t;
        int r2=p2>>4, ck=p2&15;
        int grow=row0+(r2>>5)*64+(2*p+((r2>>4)&1))*16+(r2&15);
        int bb=grow>>14, rr=grow&16383;
        int c=col0+ck*8;
        int which=c>>9, hcol=c&511, head=hcol>>6, dd=hcol&63;
        unsigned short* dst=(which==0)?(unsigned short*)o0:
                            (which==1)?(unsigned short*)o1:(unsigned short*)o2;
        *(short8v*)(dst + (((size_t)bb*NH+head)*NPAD+rr)*HD+dd) =
            *(const short8v*)(Sh + r2*128 + ck*8);
      }
    }
  } else {
    #pragma unroll
    for(int m=0;m<4;m++){
      int rbase=row0 + wr*64 + m*16 + kg*4;
      #pragma unroll
      for(int j=0;j<4;j++){
        int r=rbase+j;
        #pragma unroll
        for(int n=0;n<4;n++){
          int c=col0 + wc*64 + n*16 + lr;
          float val=acc[m][n][j];
          if(MODE==0){
            float* h=(float*)o0;
            int bb=(r>=16000)?1:0, ii=r-bb*16000;
            float vv=fmaxf(val+bias[c],0.f);
            h[((size_t)bb*NTOK + 1 + ii)*DM + c]=vv;
            if(ii<129) h[((size_t)bb*NTOK + 16001 + ii)*DM + c]=vv;
          } else {
            float* h=(float*)o0;
            int bb=r>>14, rr=r&16383;
            if(rr>=PADF)
              h[((size_t)bb*NTOK + (rr-PADF))*DM + c]+=val+bias[c];
          }
        }
      }
    }
  }
}

__global__ void k_cls(const float* __restrict__ cls, float* __restrict__ h){
  int t=blockIdx.x*256+threadIdx.x;
  if(t<2*DM) h[(size_t)(t>>9)*NTOK*DM + (t&511)]=cls[t&511];
}

// ---------------- layernorm + front zero-pad -> bf16 ----------------
__global__ __launch_bounds__(256) void k_lnpad(
    const float* __restrict__ h, const float* __restrict__ g,
    const float* __restrict__ bta, unsigned short* __restrict__ xln)
{
  int r=blockIdx.x;
  int bb=r>>14, i=r&16383;
  int t=threadIdx.x;
  unsigned short* dst=xln+(size_t)r*DM;
  if(i<PADF){ dst[t]=0; dst[t+256]=0; return; }
  const float* src=h+((size_t)bb*NTOK + (i-PADF))*DM;
  float x0=src[t], x1=src[t+256];
  __shared__ float s4[4];
  float mu=block_sum256(x0+x1,s4)*(1.f/512.f);
  float d0=x0-mu, d1=x1-mu;
  float var=block_sum256(d0*d0+d1*d1,s4)*(1.f/512.f);
  float rst=rsqrtf(var+1e-5f);
  dst[t]    =f2bf(d0*rst*g[t]    +bta[t]);
  dst[t+256]=f2bf(d1*rst*g[t+256]+bta[t+256]);
}

// ---------------- landmark means, q and k in one launch ----------------
__global__ void k_lmean2(const unsigned short* __restrict__ qsrc,
                         const unsigned short* __restrict__ ksrc,
                         float* __restrict__ qlf, unsigned short* __restrict__ qlb_,
                         float* __restrict__ klf, unsigned short* __restrict__ klb_){
  int gid=blockIdx.x;
  const unsigned short* src; float* dstf; unsigned short* dstb;
  if(gid<4096){ src=qsrc; dstf=qlf; dstb=qlb_; }
  else        { src=ksrc; dstf=klf; dstb=klb_; gid-=4096; }
  int bh=gid>>8, s=gid&255, d=threadIdx.x;  // 64 threads
  const unsigned short* p=src + (((size_t)bh*NPAD)+s*SEG)*HD + d;
  float acc=0.f;
  #pragma unroll
  for(int l=0;l<SEG;l++) acc+=bf2f(p[(size_t)l*HD]);
  float m=acc*(1.f/64.f);
  dstf[((size_t)bh*LM+s)*HD+d]=m;
  dstb[((size_t)bh*LM+s)*HD+d]=f2bf(m);
}

// ---------------- v bf16 head-major -> vt bf16 [bh][64][NPAD] ----------------
__global__ __launch_bounds__(256) void k_vtrans(
    const unsigned short* __restrict__ v, unsigned short* __restrict__ vt)
{
  __shared__ unsigned short tile[64][72];
  int kt=blockIdx.x, bh=blockIdx.y;
  int t=threadIdx.x;
  int r=t>>2, sgq=t&3;
  const short8v* src=(const short8v*)(v + ((size_t)bh*NPAD + kt*64 + r)*HD + sgq*16);
  *(short8v*)(&tile[r][sgq*16])  =src[0];
  *(short8v*)(&tile[r][sgq*16+8])=src[1];
  __syncthreads();
  int d=t>>2;
  union{unsigned short u[16]; short8v v8[2];} pk;
  #pragma unroll
  for(int i=0;i<16;i++) pk.u[i]=tile[sgq*16+i][d];
  short8v* dst=(short8v*)(vt + ((size_t)bh*HD + d)*NPAD + kt*64 + sgq*16);
  dst[0]=pk.v8[0]; dst[1]=pk.v8[1];
}

// ---------------- attn2 = softmax(ql @ kl^T) f32 + fused hi/lo split --------
__global__ __launch_bounds__(256) void k_attn2(
    const float* __restrict__ ql, const float* __restrict__ kl,
    float* __restrict__ attn2,
    unsigned short* __restrict__ a2h, unsigned short* __restrict__ a2l)
{
  __shared__ float qrow[64]; __shared__ float s4[4];
  int bh=blockIdx.x>>8, i=blockIdx.x&255, j=threadIdx.x;
  if(j<64) qrow[j]=ql[((size_t)bh*LM+i)*HD+j];
  __syncthreads();
  const float* kp=kl+((size_t)bh*LM+j)*HD;
  float l=0.f;
  #pragma unroll
  for(int d=0;d<64;d++) l+=qrow[d]*kp[d];
  float m=block_max256(l,s4);
  float e=__expf(l-m);
  float s=block_sum256(e,s4);
  float pv=e/s;
  size_t o=((size_t)bh*LM+i)*LM+j;
  attn2[o]=pv;
  unsigned short hh=f2bf(pv);
  a2h[o]=hh; a2l[o]=f2bf(pv-bf2f(hh));
}

// ---------------- pinv helpers (rowsum of softmax == 1, skip it) ------------
__global__ void k_colsum(const float* __restrict__ x, float* __restrict__ cs){
  int bh=blockIdx.x, j=threadIdx.x;
  const float* p=x+(size_t)bh*65536;
  float s=0.f;
  for(int i=0;i<256;i++) s+=p[(size_t)i*256+j];
  cs[bh*256+j]=s;
}
__global__ void k_pinvscale(const float* __restrict__ cs, float* __restrict__ scale){
  __shared__ float s4[4];
  float mc=-1e30f;
  for(int i=threadIdx.x;i<4096;i+=256) mc=fmaxf(mc,cs[i]);
  mc=block_max256(mc,s4);
  if(threadIdx.x==0) scale[0]=1.f/mc;
}
__global__ void k_zinit_hl(const float* __restrict__ x, const float* __restrict__ scale,
    unsigned short* __restrict__ zh, unsigned short* __restrict__ zl,
    unsigned short* __restrict__ zth, unsigned short* __restrict__ ztl){
  int bh=blockIdx.x>>8, i=blockIdx.x&255, j=threadIdx.x;
  float s=scale[0];
  size_t base=(size_t)bh*65536;
  float vn=x[base+(size_t)j*256+i]*s;   // z0[i][j] = X^T * s
  float vt=x[base+(size_t)i*256+j]*s;   // z0^T[i][j]
  size_t o=base+(size_t)i*256+j;
  unsigned short h=f2bf(vn); zh[o]=h; zl[o]=f2bf(vn-bf2f(h));
  h=f2bf(vt); zth[o]=h; ztl[o]=f2bf(vt-bf2f(h));
}

// ---------------- hi/lo split bf16 MFMA batched GEMM (pinv chain) -----------
// MODE 0: C=A@B (emit normal+trans)    MODE 1: C=15I-7X+acc (trans only)
// MODE 2: C=13I-acc (trans only)       MODE 3: C=0.25*acc (normal+trans)
// MODE 4: C=acc (trans only, hi only; Ndim=64)
// PREC 0: single bf16 product; PREC 1: hi/lo 3-product (f32-equivalent)
template<int MODE, int PREC>
__global__ __launch_bounds__(256) void k_bmm3(
    const unsigned short* __restrict__ Ah, const unsigned short* __restrict__ Al,
    const unsigned short* __restrict__ Bth, const unsigned short* __restrict__ Btl,
    const unsigned short* __restrict__ Xh, const unsigned short* __restrict__ Xl,
    unsigned short* __restrict__ Cnh, unsigned short* __restrict__ Cnl,
    unsigned short* __restrict__ Cth, unsigned short* __restrict__ Ctl,
    int Ndim)
{
  __shared__ unsigned short AsH[64*40], BsH[64*40];
  __shared__ unsigned short AsL[PREC?64*40:8], BsL[PREC?64*40:8];
  int bh=blockIdx.z;
  int n0=blockIdx.x*64, m0=blockIdx.y*64;
  int t=threadIdx.x, lane=t&63, w=t>>6;
  int c=lane&15, g=lane>>4;
  int wr=(w>>1)*32, wc=(w&1)*32;
  f32x4 acc[2][2];
  #pragma unroll
  for(int i=0;i<2;i++)
    #pragma unroll
    for(int j=0;j<2;j++) acc[i][j]=(f32x4){0.f,0.f,0.f,0.f};
  size_t Abase=(size_t)bh*65536;
  size_t Bbase=(size_t)bh*(size_t)Ndim*256;
  int r=t>>2, sg=t&3;
  const unsigned short* Aptr=Ah +Abase+(size_t)(m0+r)*256+sg*8;
  const unsigned short* Bptr=Bth+Bbase+(size_t)(n0+r)*256+sg*8;
  const unsigned short* Alptr=Al +Abase+(size_t)(m0+r)*256+sg*8;
  const unsigned short* Blptr=Btl+Bbase+(size_t)(n0+r)*256+sg*8;
  short8v rah, rbh, ral, rbl;
  rah=*(const short8v*)(Aptr);
  rbh=*(const short8v*)(Bptr);
  if constexpr(PREC==1){ ral=*(const short8v*)(Alptr); rbl=*(const short8v*)(Blptr); }
  int k0=0;
  for(;;){
    __syncthreads();
    *(short8v*)(AsH+r*40+sg*8)=rah;
    *(short8v*)(BsH+r*40+sg*8)=rbh;
    if constexpr(PREC==1){
      *(short8v*)(AsL+r*40+sg*8)=ral;
      *(short8v*)(BsL+r*40+sg*8)=rbl;
    }
    __syncthreads();
    int kn=k0+32;
    if(kn<256){
      rah=*(const short8v*)(Aptr+kn);
      rbh=*(const short8v*)(Bptr+kn);
      if constexpr(PREC==1){
        ral=*(const short8v*)(Alptr+kn);
        rbl=*(const short8v*)(Blptr+kn);
      }
    }
    short8v bhf[2], blf[2];
    #pragma unroll
    for(int nt=0;nt<2;nt++){
      bhf[nt]=*(const short8v*)(BsH+(wc+nt*16+c)*40+g*8);
      if constexpr(PREC==1) blf[nt]=*(const short8v*)(BsL+(wc+nt*16+c)*40+g*8);
    }
    #pragma unroll
    for(int mt=0;mt<2;mt++){
      short8v ahh=*(const short8v*)(AsH+(wr+mt*16+c)*40+g*8);
      short8v all;
      if constexpr(PREC==1) all=*(const short8v*)(AsL+(wr+mt*16+c)*40+g*8);
      #pragma unroll
      for(int nt=0;nt<2;nt++){
        acc[mt][nt]=__builtin_amdgcn_mfma_f32_16x16x32_bf16(ahh,bhf[nt],acc[mt][nt],0,0,0);
        if constexpr(PREC==1){
          acc[mt][nt]=__builtin_amdgcn_mfma_f32_16x16x32_bf16(ahh,blf[nt],acc[mt][nt],0,0,0);
          acc[mt][nt]=__builtin_amdgcn_mfma_f32_16x16x32_bf16(all,bhf[nt],acc[mt][nt],0,0,0);
        }
      }
    }
    if(kn>=256) break;
    k0=kn;
  }
  #pragma unroll
  for(int mt=0;mt<2;mt++)
    #pragma unroll
    for(int nt=0;nt<2;nt++){
      int rb=m0+wr+mt*16+g*4;
      int cc=n0+wc+nt*16+c;
      float vv[4];
      #pragma unroll
      for(int j=0;j<4;j++){
        float a=acc[mt][nt][j];
        int rr=rb+j;
        if(MODE==1){
          float xv=bf2f(Xh[Abase+(size_t)rr*256+cc])+bf2f(Xl[Abase+(size_t)rr*256+cc]);
          a=(rr==cc?15.f:0.f)-7.f*xv+a;
        } else if(MODE==2){
          a=(rr==cc?13.f:0.f)-a;
        } else if(MODE==3){
          a*=0.25f;
        }
        vv[j]=a;
      }
      if(MODE==0||MODE==3){
        #pragma unroll
        for(int j=0;j<4;j++){
          unsigned short h=f2bf(vv[j]);
          Cnh[Abase+(size_t)(rb+j)*256+cc]=h;
          Cnl[Abase+(size_t)(rb+j)*256+cc]=f2bf(vv[j]-bf2f(h));
        }
      }
      {
        ushort4 hv, lv;
        hv.x=f2bf(vv[0]); hv.y=f2bf(vv[1]); hv.z=f2bf(vv[2]); hv.w=f2bf(vv[3]);
        lv.x=f2bf(vv[0]-bf2f(hv.x)); lv.y=f2bf(vv[1]-bf2f(hv.y));
        lv.z=f2bf(vv[2]-bf2f(hv.z)); lv.w=f2bf(vv[3]-bf2f(hv.w));
        size_t co=((size_t)bh*Ndim+cc)*256+rb;
        *(ushort4*)(Cth+co)=hv;
        if(MODE!=4) *(ushort4*)(Ctl+co)=lv;
      }
    }
}

// ---------------- attn3@v : MFMA flash, split-K 16 chunks --------------------
__global__ __launch_bounds__(512) void k_attn3m(
    const unsigned short* __restrict__ qlb,
    const unsigned short* __restrict__ kb,
    const unsigned short* __restrict__ vtb,
    float* __restrict__ pacc, float* __restrict__ pms)
{
  __shared__ unsigned short Ks[64*72];
  __shared__ unsigned short Vs[64*72];
  int ck=blockIdx.x, bh=blockIdx.y;
  int t=threadIdx.x, lane=t&63, w=t>>6;
  int c=lane&15, g=lane>>4;
  short8v Qf[2][2];
  #pragma unroll
  for(int n=0;n<2;n++)
    #pragma unroll
    for(int kw=0;kw<2;kw++)
      Qf[n][kw]=*(const short8v*)(qlb + ((size_t)bh*LM + w*32 + n*16 + c)*HD + kw*32 + g*8);
  f32x4 accO[4][2];
  float mrun[2], srun[2];
  #pragma unroll
  for(int n=0;n<2;n++){
    mrun[n]=-3e38f; srun[n]=0.f;
    #pragma unroll
    for(int d=0;d<4;d++) accO[d][n]=(f32x4){0.f,0.f,0.f,0.f};
  }
  int sr=t>>3, sgk=t&7;
  for(int sc=0;sc<16;++sc){
    int key0=ck*1024 + sc*64;
    __syncthreads();
    *(short8v*)(Ks + sr*72 + sgk*8) =
      *(const short8v*)(kb + ((size_t)bh*NPAD + key0 + sr)*HD + sgk*8);
    *(short8v*)(Vs + sr*72 + sgk*8) =
      *(const short8v*)(vtb + ((size_t)bh*HD + sr)*NPAD + key0 + sgk*8);
    __syncthreads();
    f32x4 s[4][2];
    #pragma unroll
    for(int mt=0;mt<4;mt++){
      short8v a0=*(const short8v*)(Ks + (mt*16+c)*72 + g*8);
      short8v a1=*(const short8v*)(Ks + (mt*16+c)*72 + 32 + g*8);
      #pragma unroll
      for(int n=0;n<2;n++){
        f32x4 z=(f32x4){0.f,0.f,0.f,0.f};
        z=__builtin_amdgcn_mfma_f32_16x16x32_bf16(a0,Qf[n][0],z,0,0,0);
        z=__builtin_amdgcn_mfma_f32_16x16x32_bf16(a1,Qf[n][1],z,0,0,0);
        s[mt][n]=z;
      }
    }
    unsigned U[2][4][2];
    #pragma unroll
    for(int n=0;n<2;n++){
      float cm=-3e38f;
      #pragma unroll
      for(int mt=0;mt<4;mt++)
        #pragma unroll
        for(int j=0;j<4;j++) cm=fmaxf(cm,s[mt][n][j]);
      cm=fmaxf(cm,__shfl_xor(cm,16));
      cm=fmaxf(cm,__shfl_xor(cm,32));
      float mnew=fmaxf(mrun[n],cm);
      float f=__expf(mrun[n]-mnew);
      mrun[n]=mnew;
      float ps=0.f;
      #pragma unroll
      for(int mt=0;mt<4;mt++){
        float p0=__expf(s[mt][n][0]-mnew);
        float p1=__expf(s[mt][n][1]-mnew);
        float p2=__expf(s[mt][n][2]-mnew);
        float p3=__expf(s[mt][n][3]-mnew);
        ps+=p0+p1+p2+p3;
        U[n][mt][0]=cvtpk(p0,p1);
        U[n][mt][1]=cvtpk(p2,p3);
      }
      ps+=__shfl_xor(ps,16); ps+=__shfl_xor(ps,32);
      srun[n]=srun[n]*f+ps;
      #pragma unroll
      for(int d=0;d<4;d++){
        accO[d][n][0]*=f; accO[d][n][1]*=f; accO[d][n][2]*=f; accO[d][n][3]*=f;
      }
    }
    #pragma unroll
    for(int kw=0;kw<2;kw++){
      short8v pf[2];
      #pragma unroll
      for(int n=0;n<2;n++){
        union{unsigned u[4]; short8v v;} pk;
        #pragma unroll
        for(int wd=0;wd<4;wd++){
          int sl=c+16*(((g&1)<<1)+(wd>>1));
          unsigned va=(unsigned)__shfl((int)U[n][kw*2  ][wd&1],sl);
          unsigned vb=(unsigned)__shfl((int)U[n][kw*2+1][wd&1],sl);
          pk.u[wd]=(lane>=32)?vb:va;
        }
        pf[n]=pk.v;
      }
      #pragma unroll
      for(int d=0;d<4;d++){
        short8v vf=*(const short8v*)(Vs + (d*16+c)*72 + kw*32 + g*8);
        accO[d][0]=__builtin_amdgcn_mfma_f32_16x16x32_bf16(vf,pf[0],accO[d][0],0,0,0);
        accO[d][1]=__builtin_amdgcn_mfma_f32_16x16x32_bf16(vf,pf[1],accO[d][1],0,0,0);
      }
    }
  }
  size_t pb=((size_t)bh*16+ck)*LM;
  #pragma unroll
  for(int n=0;n<2;n++){
    int q=w*32+n*16+c;
    #pragma unroll
    for(int d=0;d<4;d++)
      *(f32x4*)(pacc + (pb+q)*HD + d*16 + g*4)=accO[d][n];
    if(g==0){ pms[(pb+q)*2]=mrun[n]; pms[(pb+q)*2+1]=srun[n]; }
  }
}
__global__ __launch_bounds__(256) void k_attn3vc(
    const float* __restrict__ pacc, const float* __restrict__ pms,
    unsigned short* __restrict__ a3vth, unsigned short* __restrict__ a3vtl)
{
  int gid=blockIdx.x*4+(threadIdx.x>>6);
  int bh=gid>>8, row=gid&255, lane=threadIdx.x&63;
  float M=-3e38f;
  float ms[16], ss[16];
  #pragma unroll
  for(int c=0;c<16;c++){
    size_t pb=((size_t)bh*16+c)*LM+row;
    ms[c]=pms[pb*2]; ss[c]=pms[pb*2+1];
    M=fmaxf(M,ms[c]);
  }
  float S=0.f,a=0.f;
  #pragma unroll
  for(int c=0;c<16;c++){
    float f=__expf(ms[c]-M);
    S+=ss[c]*f;
    a+=pacc[(((size_t)bh*16+c)*LM+row)*HD+lane]*f;
  }
  float v=a/S;
  unsigned short hi=f2bf(v);
  a3vth[((size_t)bh*HD+lane)*LM+row]=hi;
  a3vtl[((size_t)bh*HD+lane)*LM+row]=f2bf(v-bf2f(hi));
}

// ---------------- attn1 @ W2 : MFMA, 256 landmarks one-shot; bf16 out --------
__global__ __launch_bounds__(512) void k_attn1m(
    const unsigned short* __restrict__ qb,
    const unsigned short* __restrict__ klb,
    const unsigned short* __restrict__ w2t,
    unsigned short* __restrict__ aohb)
{
  __shared__ unsigned short klS[256*72];
  __shared__ unsigned short w2S[64*264];
  int qt=blockIdx.x, bh=blockIdx.y;
  int t=threadIdx.x, lane=t&63, w=t>>6;
  int c=lane&15, g=lane>>4;
  {
    int r=t>>1, hf=t&1;
    const short8v* s=(const short8v*)(klb + ((size_t)bh*LM+r)*HD + hf*32);
    short8v* d=(short8v*)(klS + r*72 + hf*32);
    d[0]=s[0]; d[1]=s[1]; d[2]=s[2]; d[3]=s[3];
    int r2=t>>3, sg2=t&7;
    const short8v* s2=(const short8v*)(w2t + ((size_t)bh*HD+r2)*LM + sg2*32);
    short8v* d2=(short8v*)(w2S + r2*264 + sg2*32);
    d2[0]=s2[0]; d2[1]=s2[1]; d2[2]=s2[2]; d2[3]=s2[3];
  }
  __syncthreads();
  int q0=qt*256 + w*32;
  #pragma unroll
  for(int n=0;n<2;n++){
    const unsigned short* qrow=qb + ((size_t)bh*NPAD + q0 + n*16 + c)*HD;
    short8v qf0=*(const short8v*)(qrow + g*8);
    short8v qf1=*(const short8v*)(qrow + 32 + g*8);
    f32x4 s[16];
    #pragma unroll
    for(int mt=0;mt<16;mt++){
      short8v a0=*(const short8v*)(klS + (mt*16+c)*72 + g*8);
      short8v a1=*(const short8v*)(klS + (mt*16+c)*72 + 32 + g*8);
      f32x4 z=(f32x4){0.f,0.f,0.f,0.f};
      z=__builtin_amdgcn_mfma_f32_16x16x32_bf16(a0,qf0,z,0,0,0);
      z=__builtin_amdgcn_mfma_f32_16x16x32_bf16(a1,qf1,z,0,0,0);
      s[mt]=z;
    }
    float M=-3e38f;
    #pragma unroll
    for(int mt=0;mt<16;mt++)
      #pragma unroll
      for(int j=0;j<4;j++) M=fmaxf(M,s[mt][j]);
    M=fmaxf(M,__shfl_xor(M,16));
    M=fmaxf(M,__shfl_xor(M,32));
    float sum=0.f;
    unsigned U[16][2];
    #pragma unroll
    for(int mt=0;mt<16;mt++){
      float p0=__expf(s[mt][0]-M);
      float p1=__expf(s[mt][1]-M);
      float p2=__expf(s[mt][2]-M);
      float p3=__expf(s[mt][3]-M);
      sum+=p0+p1+p2+p3;
      U[mt][0]=cvtpk(p0,p1);
      U[mt][1]=cvtpk(p2,p3);
    }
    sum+=__shfl_xor(sum,16); sum+=__shfl_xor(sum,32);
    float inv=1.f/sum;
    f32x4 accO[4];
    #pragma unroll
    for(int d=0;d<4;d++) accO[d]=(f32x4){0.f,0.f,0.f,0.f};
    #pragma unroll
    for(int kw=0;kw<8;kw++){
      union{unsigned u[4]; short8v v;} pk;
      #pragma unroll
      for(int wd=0;wd<4;wd++){
        int sl=c+16*(((g&1)<<1)+(wd>>1));
        unsigned va=(unsigned)__shfl((int)U[kw*2  ][wd&1],sl);
        unsigned vb=(unsigned)__shfl((int)U[kw*2+1][wd&1],sl);
        pk.u[wd]=(lane>=32)?vb:va;
      }
      #pragma unroll
      for(int d=0;d<4;d++){
        short8v vf=*(const short8v*)(w2S + (d*16+c)*264 + kw*32 + g*8);
        accO[d]=__builtin_amdgcn_mfma_f32_16x16x32_bf16(vf,pk.v,accO[d],0,0,0);
      }
    }
    int q=q0+n*16+c;
    #pragma unroll
    for(int d=0;d<4;d++){
      f32x4 o=accO[d];
      uint2 pk2;
      pk2.x=cvtpk(o[0]*inv, o[1]*inv);
      pk2.y=cvtpk(o[2]*inv, o[3]*inv);
      *(uint2*)(aohb + ((size_t)bh*NPAD+q)*HD + d*16 + g*4)=pk2;
    }
  }
}

// ---------------- depthwise 33-tap conv from vt; aoh bf16 += -----------------
__global__ __launch_bounds__(256) void k_resconv2(
    const unsigned short* __restrict__ vt, const float* __restrict__ rw,
    unsigned short* __restrict__ aohb){
  int bx=blockIdx.x, bh=blockIdx.y;
  int t=threadIdx.x, d=t&63, g=t>>6;
  int i0=bx*32+g*8;
  int hh=bh&7;
  const unsigned short* vr=vt + ((size_t)bh*HD + d)*NPAD;
  float wv[40];
  int start=i0-16;
  if(start>=0 && start+40<=NPAD){
    #pragma unroll
    for(int b=0;b<5;b++){
      short8v v8=*(const short8v*)(vr+start+b*8);
      #pragma unroll
      for(int j=0;j<8;j++) wv[b*8+j]=bf2f((unsigned short)v8[j]);
    }
  } else {
    #pragma unroll
    for(int t2=0;t2<40;t2++){
      int src=start+t2;
      wv[t2]=(src>=0&&src<NPAD)?bf2f(vr[src]):0.f;
    }
  }
  const float* wt=rw+hh*33;
  #pragma unroll
  for(int p=0;p<8;p++){
    float a=0.f;
    #pragma unroll
    for(int tk=0;tk<33;tk++) a+=wv[p+tk]*wt[tk];
    size_t o=((size_t)bh*NPAD+i0+p)*HD+d;
    aohb[o]=f2bf(bf2f(aohb[o])+a);
  }
}

// ---------------- PPEG weight prep: combined 7x7 tap table (bf16) -----------
__global__ void k_wprep(const float* __restrict__ w7, const float* __restrict__ b7,
                        const float* __restrict__ w5, const float* __restrict__ b5,
                        const float* __restrict__ w3, const float* __restrict__ b3,
                        unsigned short* __restrict__ wcat){
  int t=blockIdx.x*256+threadIdx.x;
  if(t>=50*512) return;
  int r=t>>9, c=t&511;
  float v;
  if(r<49){
    int ky=r/7, kx=r%7;
    v=w7[(size_t)c*49+r];
    if(ky>=1&&ky<=5&&kx>=1&&kx<=5) v+=w5[(size_t)c*25+(ky-1)*5+(kx-1)];
    if(ky>=2&&ky<=4&&kx>=2&&kx<=4) v+=w3[(size_t)c*9+(ky-2)*3+(kx-2)];
  } else {
    v=b7[c]+b5[c]+b3[c];
  }
  wcat[t]=f2bf(v);
}

// ---------------- PPEG: 8x8 tile x 32ch, f32 patch, sliding row window ------
__global__ __launch_bounds__(256,4) void k_ppeg4(
    const float* __restrict__ src, const unsigned short* __restrict__ wcat,
    float* __restrict__ dst)
{
  __shared__ float patch[196][32];   // 14x14 halo
  __shared__ float wsf[50][32];
  int bx=blockIdx.x;
  int cz=blockIdx.y, bb=blockIdx.z;
  int t=threadIdx.x, c=t&31, g=t>>5;   // 32ch x 8 groups
  int ty0=(bx>>4)*8, tx0=(bx&15)*8;
  const float* base=src+((size_t)bb*NTOK+1)*DM + cz*32 + c;
  #pragma unroll
  for(int i=0;i<25;i++){
    int p=g+8*i;
    if(p<196){
      int py=p/14, px=p%14;
      int yy=ty0-3+py, xx=tx0-3+px;
      float v=0.f;
      if(yy>=0&&yy<127&&xx>=0&&xx<127) v=base[(size_t)(yy*127+xx)*DM];
      patch[p][c]=v;
    }
  }
  #pragma unroll
  for(int i=0;i<7;i++){
    int r=g+8*i; if(r<50) wsf[r][c]=bf2f(wcat[(size_t)r*DM + cz*32 + c]);
  }
  __syncthreads();
  float acc[8];
  float bias=wsf[49][c];
  #pragma unroll
  for(int j=0;j<8;j++) acc[j]=patch[(g+3)*14+(j+3)][c]+bias;  // exact identity
  #pragma unroll
  for(int ky=0;ky<7;ky++){
    float win[14];
    #pragma unroll
    for(int x=0;x<14;x++) win[x]=patch[(g+ky)*14+x][c];
    #pragma unroll
    for(int kx=0;kx<7;kx++){
      float wv=wsf[ky*7+kx][c];
      #pragma unroll
      for(int j=0;j<8;j++) acc[j]+=win[j+kx]*wv;
    }
  }
  int y=ty0+g;
  if(y<127){
    #pragma unroll
    for(int j=0;j<8;j++){
      int x=tx0+j;
      if(x<127)
        dst[((size_t)bb*NTOK+1+(size_t)(y*127+x))*DM + cz*32 + c]=acc[j];
    }
  }
}

// copy cls row h -> dst
__global__ void k_cpcls(const float* __restrict__ h, float* __restrict__ dst){
  int t=blockIdx.x*256+threadIdx.x;
  if(t<2*DM) dst[(size_t)(t>>9)*NTOK*DM + (t&511)]=h[(size_t)(t>>9)*NTOK*DM + (t&511)];
}

// ---------------- final: LN(h[:,0]) @ fc2 + b ----------------
__global__ __launch_bounds__(256) void k_final(
    const float* __restrict__ h, const float* __restrict__ g, const float* __restrict__ bta,
    const float* __restrict__ w, const float* __restrict__ fb, float* __restrict__ out)
{
  int bb=blockIdx.x, t=threadIdx.x;
  const float* src=h+(size_t)bb*NTOK*DM;
  float x0=src[t], x1=src[t+256];
  __shared__ float s4[4];
  float mu=block_sum256(x0+x1,s4)*(1.f/512.f);
  float d0=x0-mu, d1=x1-mu;
  float var=block_sum256(d0*d0+d1*d1,s4)*(1.f/512.f);
  float rst=rsqrtf(var+1e-5f);
  float y0=d0*rst*g[t]+bta[t], y1=d1*rst*g[t+256]+bta[t+256];
  float dot=block_sum256(y0*w[t]+y1*w[t+256],s4);
  if(t==0) out[bb]=dot+fb[0];
}

// =======================================================================
extern "C" void kernel_launch(void* const* d_in, const int* in_sizes, int n_in,
                              void* d_out, int out_size, void* d_ws, size_t ws_size,
                              hipStream_t stream){
  (void)in_sizes; (void)n_in; (void)out_size; (void)ws_size;
  const float* features=(const float*)d_in[0];
  const float* fc1_w  =(const float*)d_in[1];
  const float* fc1_b  =(const float*)d_in[2];
  const float* cls_tok=(const float*)d_in[3];
  const float* fc2_w  =(const float*)d_in[24];
  const float* fc2_b  =(const float*)d_in[25];
  float* out=(float*)d_out;

  char* wp=(char*)d_ws;
  auto allocB=[&](size_t bytes)->char*{
    char* p=wp; wp+=((bytes+255)/256)*256; return p;
  };
  float* h    =(float*)allocB((size_t)NB*NTOK*DM*4);
  float* h2   =(float*)allocB((size_t)NB*NTOK*DM*4);
  unsigned short* vb  =(unsigned short*)allocB((size_t)NB*NPAD*DM*2);
  unsigned short* xlnb=(unsigned short*)allocB((size_t)NB*NPAD*DM*2);
  unsigned short* qb  =(unsigned short*)allocB((size_t)NB*NPAD*DM*2);
  unsigned short* kb  =(unsigned short*)allocB((size_t)NB*NPAD*DM*2);
  unsigned short* vtb =(unsigned short*)allocB((size_t)NB*NPAD*DM*2);
  unsigned short* aohb=(unsigned short*)allocB((size_t)NB*NPAD*DM*2);
  unsigned short* wtf=(unsigned short*)allocB((size_t)512*1024*2);
  unsigned short* wtq=(unsigned short*)allocB((size_t)1536*512*2);
  unsigned short* wtp=(unsigned short*)allocB((size_t)512*512*2);
  float* ql =(float*)allocB((size_t)16*LM*HD*4);
  float* kl =(float*)allocB((size_t)16*LM*HD*4);
  unsigned short* qlb=(unsigned short*)allocB((size_t)16*LM*HD*2);
  unsigned short* klb=(unsigned short*)allocB((size_t)16*LM*HD*2);
  float* attn2=(float*)allocB((size_t)16*LM*LM*4);
  unsigned short* a2h=(unsigned short*)allocB((size_t)16*LM*LM*2);
  unsigned short* a2l=(unsigned short*)allocB((size_t)16*LM*LM*2);
  unsigned short* zb[8];
  for(int i=0;i<8;i++) zb[i]=(unsigned short*)allocB((size_t)16*LM*LM*2);
  unsigned short* Abh=(unsigned short*)allocB((size_t)16*LM*LM*2);
  unsigned short* Abl=(unsigned short*)allocB((size_t)16*LM*LM*2);
  unsigned short* Abth=(unsigned short*)allocB((size_t)16*LM*LM*2);
  unsigned short* Abtl=(unsigned short*)allocB((size_t)16*LM*LM*2);
  unsigned short* Ubth=(unsigned short*)allocB((size_t)16*LM*LM*2);
  unsigned short* Ubtl=(unsigned short*)allocB((size_t)16*LM*LM*2);
  unsigned short* Tbth=(unsigned short*)allocB((size_t)16*LM*LM*2);
  unsigned short* Tbtl=(unsigned short*)allocB((size_t)16*LM*LM*2);
  unsigned short* a3vth=(unsigned short*)allocB((size_t)16*HD*LM*2);
  unsigned short* a3vtl=(unsigned short*)allocB((size_t)16*HD*LM*2);
  unsigned short* w2t=(unsigned short*)allocB((size_t)16*HD*LM*2);
  float* pacc=(float*)allocB((size_t)16*16*LM*HD*4);
  float* pms =(float*)allocB((size_t)16*16*LM*2*4);
  float* cs  =(float*)allocB(4096*4);
  float* scl =(float*)allocB(64*4);

  auto nystrom=[&](float* hbuf, const float* ng, const float* nbias, const float* qkvw,
                   const float* outw, const float* outb, const float* resw){
    k_lnpad<<<NB*NPAD,256,0,stream>>>(hbuf, ng, nbias, xlnb);
    k_wconv_t<<<(512*1536+255)/256,256,0,stream>>>(qkvw, wtq, 512, 1536);
    k_mfma_gemm<1,0><<<dim3(12,256),256,0,stream>>>(xlnb, wtq, 32768,1536,512,
                                                    nullptr, qb, kb, vb);
    k_lmean2<<<8192,64,0,stream>>>(qb, kb, ql, qlb, kl, klb);
    k_vtrans<<<dim3(256,16),256,0,stream>>>(vb, vtb);
    k_attn2<<<4096,256,0,stream>>>(ql, kl, attn2, a2h, a2l);
    k_colsum<<<16,256,0,stream>>>(attn2, cs);
    k_pinvscale<<<1,256,0,stream>>>(cs, scl);
    k_zinit_hl<<<4096,256,0,stream>>>(attn2, scl, zb[0],zb[1],zb[2],zb[3]);
    unsigned short *zch=zb[0],*zcl=zb[1],*zcth=zb[2],*zctl=zb[3];
    unsigned short *znh=zb[4],*znl=zb[5],*znth=zb[6],*zntl=zb[7];
    for(int it=0;it<6;it++){
      if(it<5){
        k_bmm3<0,0><<<dim3(4,4,16),256,0,stream>>>(a2h,a2l, zcth,zctl, nullptr,nullptr,
                                                   Abh,Abl, Abth,Abtl, 256);
        k_bmm3<1,0><<<dim3(4,4,16),256,0,stream>>>(Abh,Abl, Abth,Abtl, Abh,Abl,
                                                   nullptr,nullptr, Ubth,Ubtl, 256);
        k_bmm3<2,0><<<dim3(4,4,16),256,0,stream>>>(Abh,Abl, Ubth,Ubtl, nullptr,nullptr,
                                                   nullptr,nullptr, Tbth,Tbtl, 256);
        k_bmm3<3,0><<<dim3(4,4,16),256,0,stream>>>(zch,zcl, Tbth,Tbtl, nullptr,nullptr,
                                                   znh,znl, znth,zntl, 256);
      } else {
        k_bmm3<0,1><<<dim3(4,4,16),256,0,stream>>>(a2h,a2l, zcth,zctl, nullptr,nullptr,
                                                   Abh,Abl, Abth,Abtl, 256);
        k_bmm3<1,1><<<dim3(4,4,16),256,0,stream>>>(Abh,Abl, Abth,Abtl, Abh,Abl,
                                                   nullptr,nullptr, Ubth,Ubtl, 256);
        k_bmm3<2,1><<<dim3(4,4,16),256,0,stream>>>(Abh,Abl, Ubth,Ubtl, nullptr,nullptr,
                                                   nullptr,nullptr, Tbth,Tbtl, 256);
        k_bmm3<3,1><<<dim3(4,4,16),256,0,stream>>>(zch,zcl, Tbth,Tbtl, nullptr,nullptr,
                                                   znh,znl, znth,zntl, 256);
      }
      unsigned short* tp;
      tp=zch; zch=znh; znh=tp;  tp=zcl; zcl=znl; znl=tp;
      tp=zcth; zcth=znth; znth=tp;  tp=zctl; zctl=zntl; zntl=tp;
    }
    k_attn3m<<<dim3(16,16),512,0,stream>>>(qlb, kb, vtb, pacc, pms);
    k_attn3vc<<<1024,256,0,stream>>>(pacc, pms, a3vth, a3vtl);
    k_bmm3<4,1><<<dim3(1,4,16),256,0,stream>>>(zch,zcl, a3vth,a3vtl, nullptr,nullptr,
                                               nullptr,nullptr, w2t,nullptr, 64);
    k_attn1m<<<dim3(64,16),512,0,stream>>>(qb, klb, w2t, aohb);
    k_resconv2<<<dim3(512,16),256,0,stream>>>(vtb, resw, aohb);
    k_wconv_t<<<(512*512+255)/256,256,0,stream>>>(outw, wtp, 512, 512);
    k_mfma_gemm<2,3><<<dim3(4,256),256,0,stream>>>(aohb, wtp, 32768,512,512,
                                                   outb, hbuf, nullptr, nullptr);
  };

  // fc1: features -> bf16 (h2 overlay), then MFMA GEMM via global_load_lds
  unsigned short* featbf=(unsigned short*)h2;   // dead before PPEG
  k_f2bf4<<<32000,256,0,stream>>>(features, featbf, 32000*1024/4);
  k_wconv_t<<<(1024*512+255)/256,256,0,stream>>>(fc1_w, wtf, 1024, 512);
  k_mfma_gemm<0,0><<<dim3(4,250),256,0,stream>>>(featbf, wtf, 32000,512,1024,
                                                 fc1_b, h, nullptr, nullptr);
  k_cls<<<4,256,0,stream>>>(cls_tok, h);

  // layer 1 attention (on h)
  nystrom(h, (const float*)d_in[4],(const float*)d_in[5],(const float*)d_in[6],
          (const float*)d_in[7],(const float*)d_in[8],(const float*)d_in[9]);

  // PPEG: combined-tap stencil h -> h2 (no copy-back; layer 2 runs on h2)
  {
    unsigned short* wcat=(unsigned short*)attn2;  // free at this point
    k_wprep<<<100,256,0,stream>>>(
        (const float*)d_in[10],(const float*)d_in[11],
        (const float*)d_in[12],(const float*)d_in[13],
        (const float*)d_in[14],(const float*)d_in[15], wcat);
    k_cpcls<<<4,256,0,stream>>>(h, h2);
    k_ppeg4<<<dim3(256,16,2),256,0,stream>>>(h, wcat, h2);
  }

  // layer 2 attention (on h2)
  nystrom(h2, (const float*)d_in[16],(const float*)d_in[17],(const float*)d_in[18],
          (const float*)d_in[19],(const float*)d_in[20],(const float*)d_in[21]);

  // final LN(h2[:,0]) @ fc2
  k_final<<<2,256,0,stream>>>(h2,(const float*)d_in[22],(const float*)d_in[23],
                              fc2_w, fc2_b, out);
}

// Round 17
// 1268.585 us; speedup vs baseline: 1.2522x; 1.0483x over previous
//
#include <hip/hip_runtime.h>
#include <math.h>

#define NTOK 16130   // 1 + 127*127
#define NPAD 16384
#define PADF 254
#define NB   2
#define DM   512
#define NH   8
#define HD   64
#define LM   256
#define SEG  64

typedef __attribute__((ext_vector_type(8))) short short8v;
typedef __attribute__((ext_vector_type(4))) float f32x4;
typedef unsigned int u32;

// ---------------- helpers ----------------
__device__ __forceinline__ float wred_max(float v){
  #pragma unroll
  for(int o=32;o;o>>=1) v=fmaxf(v,__shfl_xor(v,o));
  return v;
}
__device__ __forceinline__ float wred_sum(float v){
  #pragma unroll
  for(int o=32;o;o>>=1) v+=__shfl_xor(v,o);
  return v;
}
__device__ __forceinline__ float block_max256(float v, float* s4){
  v=wred_max(v);
  if((threadIdx.x&63)==0) s4[threadIdx.x>>6]=v;
  __syncthreads();
  v=fmaxf(fmaxf(s4[0],s4[1]),fmaxf(s4[2],s4[3]));
  __syncthreads();
  return v;
}
__device__ __forceinline__ float block_sum256(float v, float* s4){
  v=wred_sum(v);
  if((threadIdx.x&63)==0) s4[threadIdx.x>>6]=v;
  __syncthreads();
  v=s4[0]+s4[1]+s4[2]+s4[3];
  __syncthreads();
  return v;
}
__device__ __forceinline__ unsigned short f2bf(float f){
  unsigned u=__float_as_uint(f);
  u = u + 0x7FFFu + ((u>>16)&1u);
  return (unsigned short)(u>>16);
}
__device__ __forceinline__ float bf2f(unsigned short u){
  return __uint_as_float(((unsigned)u)<<16);
}
__device__ __forceinline__ unsigned cvtpk(float a, float b){
  unsigned r;
  asm("v_cvt_pk_bf16_f32 %0, %1, %2" : "=v"(r) : "v"(a), "v"(b));
  return r;
}
// async global->LDS, 16B per lane
__device__ __forceinline__ void gl16(const unsigned short* g, unsigned short* l){
  __builtin_amdgcn_global_load_lds(
      (const __attribute__((address_space(1))) u32*)(g),
      (__attribute__((address_space(3))) u32*)(l), 16, 0, 0);
}

// ---------------- conversions ----------------
__global__ void k_f2bf4(const float* __restrict__ x, unsigned short* __restrict__ y, int n4){
  int i=blockIdx.x*256+threadIdx.x; if(i>=n4) return;
  float4 v=((const float4*)x)[i];
  ushort4 r; r.x=f2bf(v.x); r.y=f2bf(v.y); r.z=f2bf(v.z); r.w=f2bf(v.w);
  ((ushort4*)y)[i]=r;
}
// W[K][N] f32 -> Wt[N][K] bf16
__global__ void k_wconv_t(const float* __restrict__ W, unsigned short* __restrict__ Wt,
                          int K, int N){
  int idx=blockIdx.x*256+threadIdx.x; if(idx>=K*N) return;
  int k=idx/N, n=idx%N;
  Wt[(size_t)n*K+k]=f2bf(W[idx]);
}

// ---------------- MFMA bf16 GEMM: 128x128 tile, BK=32, XCD swizzle -----------
// ASRC 0: A bf16 row-major (global_load_lds staging)
// ASRC 3: A bf16 head-major [bb][8][NPAD][64] (global_load_lds staging)
template<int MODE, int ASRC>
__global__ __launch_bounds__(256) void k_mfma_gemm(
    const void* __restrict__ Ap, const unsigned short* __restrict__ Bt,
    int M, int N, int K,
    const float* __restrict__ bias,
    void* __restrict__ o0, void* __restrict__ o1, void* __restrict__ o2)
{
  __shared__ __align__(16) unsigned short Sh[128*64];   // As=Sh[0..4095], Bs=Sh[4096..]
  int t=threadIdx.x;
  int bx=blockIdx.x, by=blockIdx.y;
  { // bijective XCD swizzle (grid size divisible by 8)
    int gx=gridDim.x; int wg=by*gx+bx; int nwg=gx*gridDim.y;
    int cpx=nwg>>3; int x2=(wg&7)*cpx+(wg>>3);
    by=x2/gx; bx=x2-by*gx;
  }
  int row0=by*128, col0=bx*128;
  int lane=t&63, w=t>>6, wr=w>>1, wc=w&1, lr=lane&15, kg=lane>>4;
  f32x4 acc[4][4];
  #pragma unroll
  for(int m=0;m<4;m++)
    #pragma unroll
    for(int n=0;n<4;n++) acc[m][n]=(f32x4){0.f,0.f,0.f,0.f};

  for(int k0=0;k0<K;k0+=32){
    __syncthreads();   // previous tile fully consumed
    #pragma unroll
    for(int i=0;i<2;i++){
      int flat=i*256+t, r=flat>>2, k8=flat&3;
      int kofs=k0+k8*8;
      const unsigned short* asrc;
      if constexpr(ASRC==0){
        asrc=(const unsigned short*)Ap+(size_t)(row0+r)*K+kofs;
      } else {
        int rr2=row0+r; int bb=rr2>>14, ri=rr2&16383;
        int head=kofs>>6, dd=kofs&63;
        asrc=(const unsigned short*)Ap + (((size_t)bb*NH+head)*NPAD+ri)*HD + dd;
      }
      gl16(asrc, Sh+(size_t)flat*8);
      gl16(Bt+(size_t)(col0+r)*K+kofs, Sh+4096+(size_t)flat*8);
    }
    __syncthreads();   // data ready (vmcnt/lgkm drained before barrier)
    short8v af[4], bf[4];
    #pragma unroll
    for(int m=0;m<4;m++) af[m]=*(const short8v*)(Sh+(wr*64+m*16+lr)*32 + kg*8);
    #pragma unroll
    for(int n=0;n<4;n++) bf[n]=*(const short8v*)(Sh+4096+(wc*64+n*16+lr)*32 + kg*8);
    #pragma unroll
    for(int m=0;m<4;m++)
      #pragma unroll
      for(int n=0;n<4;n++)
        acc[m][n]=__builtin_amdgcn_mfma_f32_16x16x32_bf16(af[m],bf[n],acc[m][n],0,0,0);
  }
  // ---- epilogue ----
  if constexpr(MODE==1){
    // coalesced q/k/v store via LDS restage (2 passes of 64 rows x 128 cols bf16)
    #pragma unroll
    for(int p=0;p<2;p++){
      __syncthreads();
      #pragma unroll
      for(int mm=0;mm<2;mm++){
        int m=2*p+mm;
        #pragma unroll
        for(int n=0;n<4;n++){
          int cc=wc*64+n*16+lr;
          int c=col0+cc;
          float sc=((c>>9)==0)?0.125f:1.f;
          #pragma unroll
          for(int j=0;j<4;j++){
            int lrow=wr*32+mm*16+kg*4+j;
            Sh[lrow*128+cc]=f2bf(acc[m][n][j]*sc);
          }
        }
      }
      __syncthreads();
      #pragma unroll
      for(int i=0;i<4;i++){
        int p2=i*256+t;
        int r2=p2>>4, ck=p2&15;
        int grow=row0+(r2>>5)*64+(2*p+((r2>>4)&1))*16+(r2&15);
        int bb=grow>>14, rr=grow&16383;
        int c=col0+ck*8;
        int which=c>>9, hcol=c&511, head=hcol>>6, dd=hcol&63;
        unsigned short* dst=(which==0)?(unsigned short*)o0:
                            (which==1)?(unsigned short*)o1:(unsigned short*)o2;
        *(short8v*)(dst + (((size_t)bb*NH+head)*NPAD+rr)*HD+dd) =
            *(const short8v*)(Sh + r2*128 + ck*8);
      }
    }
  } else {
    #pragma unroll
    for(int m=0;m<4;m++){
      int rbase=row0 + wr*64 + m*16 + kg*4;
      #pragma unroll
      for(int j=0;j<4;j++){
        int r=rbase+j;
        #pragma unroll
        for(int n=0;n<4;n++){
          int c=col0 + wc*64 + n*16 + lr;
          float val=acc[m][n][j];
          if(MODE==0){
            float* h=(float*)o0;
            int bb=(r>=16000)?1:0, ii=r-bb*16000;
            float vv=fmaxf(val+bias[c],0.f);
            h[((size_t)bb*NTOK + 1 + ii)*DM + c]=vv;
            if(ii<129) h[((size_t)bb*NTOK + 16001 + ii)*DM + c]=vv;
          } else {
            float* h=(float*)o0;
            int bb=r>>14, rr=r&16383;
            if(rr>=PADF)
              h[((size_t)bb*NTOK + (rr-PADF))*DM + c]+=val+bias[c];
          }
        }
      }
    }
  }
}

__global__ void k_cls(const float* __restrict__ cls, float* __restrict__ h){
  int t=blockIdx.x*256+threadIdx.x;
  if(t<2*DM) h[(size_t)(t>>9)*NTOK*DM + (t&511)]=cls[t&511];
}

// ---------------- layernorm + front zero-pad -> bf16 ----------------
__global__ __launch_bounds__(256) void k_lnpad(
    const float* __restrict__ h, const float* __restrict__ g,
    const float* __restrict__ bta, unsigned short* __restrict__ xln)
{
  int r=blockIdx.x;
  int bb=r>>14, i=r&16383;
  int t=threadIdx.x;
  unsigned short* dst=xln+(size_t)r*DM;
  if(i<PADF){ dst[t]=0; dst[t+256]=0; return; }
  const float* src=h+((size_t)bb*NTOK + (i-PADF))*DM;
  float x0=src[t], x1=src[t+256];
  __shared__ float s4[4];
  float mu=block_sum256(x0+x1,s4)*(1.f/512.f);
  float d0=x0-mu, d1=x1-mu;
  float var=block_sum256(d0*d0+d1*d1,s4)*(1.f/512.f);
  float rst=rsqrtf(var+1e-5f);
  dst[t]    =f2bf(d0*rst*g[t]    +bta[t]);
  dst[t+256]=f2bf(d1*rst*g[t+256]+bta[t+256]);
}

// ---------------- landmark means, q and k in one launch ----------------
__global__ void k_lmean2(const unsigned short* __restrict__ qsrc,
                         const unsigned short* __restrict__ ksrc,
                         float* __restrict__ qlf, unsigned short* __restrict__ qlb_,
                         float* __restrict__ klf, unsigned short* __restrict__ klb_){
  int gid=blockIdx.x;
  const unsigned short* src; float* dstf; unsigned short* dstb;
  if(gid<4096){ src=qsrc; dstf=qlf; dstb=qlb_; }
  else        { src=ksrc; dstf=klf; dstb=klb_; gid-=4096; }
  int bh=gid>>8, s=gid&255, d=threadIdx.x;  // 64 threads
  const unsigned short* p=src + (((size_t)bh*NPAD)+s*SEG)*HD + d;
  float acc=0.f;
  #pragma unroll
  for(int l=0;l<SEG;l++) acc+=bf2f(p[(size_t)l*HD]);
  float m=acc*(1.f/64.f);
  dstf[((size_t)bh*LM+s)*HD+d]=m;
  dstb[((size_t)bh*LM+s)*HD+d]=f2bf(m);
}

// ---------------- v bf16 head-major -> vt bf16 [bh][64][NPAD] ----------------
__global__ __launch_bounds__(256) void k_vtrans(
    const unsigned short* __restrict__ v, unsigned short* __restrict__ vt)
{
  __shared__ unsigned short tile[64][72];
  int kt=blockIdx.x, bh=blockIdx.y;
  int t=threadIdx.x;
  int r=t>>2, sgq=t&3;
  const short8v* src=(const short8v*)(v + ((size_t)bh*NPAD + kt*64 + r)*HD + sgq*16);
  *(short8v*)(&tile[r][sgq*16])  =src[0];
  *(short8v*)(&tile[r][sgq*16+8])=src[1];
  __syncthreads();
  int d=t>>2;
  union{unsigned short u[16]; short8v v8[2];} pk;
  #pragma unroll
  for(int i=0;i<16;i++) pk.u[i]=tile[sgq*16+i][d];
  short8v* dst=(short8v*)(vt + ((size_t)bh*HD + d)*NPAD + kt*64 + sgq*16);
  dst[0]=pk.v8[0]; dst[1]=pk.v8[1];
}

// ---------------- attn2 = softmax(ql @ kl^T) f32 + fused hi/lo split --------
__global__ __launch_bounds__(256) void k_attn2(
    const float* __restrict__ ql, const float* __restrict__ kl,
    float* __restrict__ attn2,
    unsigned short* __restrict__ a2h, unsigned short* __restrict__ a2l)
{
  __shared__ float qrow[64]; __shared__ float s4[4];
  int bh=blockIdx.x>>8, i=blockIdx.x&255, j=threadIdx.x;
  if(j<64) qrow[j]=ql[((size_t)bh*LM+i)*HD+j];
  __syncthreads();
  const float* kp=kl+((size_t)bh*LM+j)*HD;
  float l=0.f;
  #pragma unroll
  for(int d=0;d<64;d++) l+=qrow[d]*kp[d];
  float m=block_max256(l,s4);
  float e=__expf(l-m);
  float s=block_sum256(e,s4);
  float pv=e/s;
  size_t o=((size_t)bh*LM+i)*LM+j;
  attn2[o]=pv;
  unsigned short hh=f2bf(pv);
  a2h[o]=hh; a2l[o]=f2bf(pv-bf2f(hh));
}

// ---------------- pinv helpers (rowsum of softmax == 1, skip it) ------------
__global__ void k_colsum(const float* __restrict__ x, float* __restrict__ cs){
  int bh=blockIdx.x, j=threadIdx.x;
  const float* p=x+(size_t)bh*65536;
  float s=0.f;
  for(int i=0;i<256;i++) s+=p[(size_t)i*256+j];
  cs[bh*256+j]=s;
}
__global__ void k_pinvscale(const float* __restrict__ cs, float* __restrict__ scale){
  __shared__ float s4[4];
  float mc=-1e30f;
  for(int i=threadIdx.x;i<4096;i+=256) mc=fmaxf(mc,cs[i]);
  mc=block_max256(mc,s4);
  if(threadIdx.x==0) scale[0]=1.f/mc;
}
__global__ void k_zinit_hl(const float* __restrict__ x, const float* __restrict__ scale,
    unsigned short* __restrict__ zh, unsigned short* __restrict__ zl,
    unsigned short* __restrict__ zth, unsigned short* __restrict__ ztl){
  int bh=blockIdx.x>>8, i=blockIdx.x&255, j=threadIdx.x;
  float s=scale[0];
  size_t base=(size_t)bh*65536;
  float vn=x[base+(size_t)j*256+i]*s;   // z0[i][j] = X^T * s
  float vt=x[base+(size_t)i*256+j]*s;   // z0^T[i][j]
  size_t o=base+(size_t)i*256+j;
  unsigned short h=f2bf(vn); zh[o]=h; zl[o]=f2bf(vn-bf2f(h));
  h=f2bf(vt); zth[o]=h; ztl[o]=f2bf(vt-bf2f(h));
}

// ---------------- hi/lo split bf16 MFMA batched GEMM (pinv chain) -----------
// Tile 32(M)x64(N), BK=64, 4 k-steps, grid 512 blocks (2/CU)
// MODE 0: C=A@B (emit normal+trans)    MODE 1: C=15I-7X+acc (trans only)
// MODE 2: C=13I-acc (trans only)       MODE 3: C=0.25*acc (normal+trans)
// MODE 4: C=acc (trans only, hi only; Ndim=64)
// PREC 0: single bf16 product; PREC 1: hi/lo 3-product (f32-equivalent)
template<int MODE, int PREC>
__global__ __launch_bounds__(256) void k_bmm3(
    const unsigned short* __restrict__ Ah, const unsigned short* __restrict__ Al,
    const unsigned short* __restrict__ Bth, const unsigned short* __restrict__ Btl,
    const unsigned short* __restrict__ Xh, const unsigned short* __restrict__ Xl,
    unsigned short* __restrict__ Cnh, unsigned short* __restrict__ Cnl,
    unsigned short* __restrict__ Cth, unsigned short* __restrict__ Ctl,
    int Ndim)
{
  __shared__ unsigned short AsH[32*72], BsH[64*72];
  __shared__ unsigned short AsL[PREC?32*72:8], BsL[PREC?64*72:8];
  int bh=blockIdx.z;
  int n0=blockIdx.x*64, m0=blockIdx.y*32;
  int t=threadIdx.x, lane=t&63, w=t>>6;
  int c=lane&15, g=lane>>4;
  int wr=(w>>1)*16, wc=(w&1)*32;
  f32x4 acc[2];
  acc[0]=(f32x4){0.f,0.f,0.f,0.f};
  acc[1]=(f32x4){0.f,0.f,0.f,0.f};
  size_t Abase=(size_t)bh*65536;
  size_t Bbase=(size_t)bh*(size_t)Ndim*256;
  int r=t>>3, k8=(t&7)*8;
  const unsigned short* ApH =Ah +Abase+(size_t)(m0+r)*256+k8;
  const unsigned short* BpH0=Bth+Bbase+(size_t)(n0+r)*256+k8;
  const unsigned short* BpH1=Bth+Bbase+(size_t)(n0+32+r)*256+k8;
  const unsigned short* ApL =Al +Abase+(size_t)(m0+r)*256+k8;
  const unsigned short* BpL0=Btl+Bbase+(size_t)(n0+r)*256+k8;
  const unsigned short* BpL1=Btl+Bbase+(size_t)(n0+32+r)*256+k8;
  short8v rah,rbh0,rbh1, ral,rbl0,rbl1;
  rah =*(const short8v*)(ApH);
  rbh0=*(const short8v*)(BpH0);
  rbh1=*(const short8v*)(BpH1);
  if constexpr(PREC==1){
    ral =*(const short8v*)(ApL);
    rbl0=*(const short8v*)(BpL0);
    rbl1=*(const short8v*)(BpL1);
  }
  int k0=0;
  for(;;){
    __syncthreads();
    *(short8v*)(AsH + r*72 + k8)=rah;
    *(short8v*)(BsH + r*72 + k8)=rbh0;
    *(short8v*)(BsH + (r+32)*72 + k8)=rbh1;
    if constexpr(PREC==1){
      *(short8v*)(AsL + r*72 + k8)=ral;
      *(short8v*)(BsL + r*72 + k8)=rbl0;
      *(short8v*)(BsL + (r+32)*72 + k8)=rbl1;
    }
    __syncthreads();
    int kn=k0+64;
    if(kn<256){
      rah =*(const short8v*)(ApH +kn);
      rbh0=*(const short8v*)(BpH0+kn);
      rbh1=*(const short8v*)(BpH1+kn);
      if constexpr(PREC==1){
        ral =*(const short8v*)(ApL +kn);
        rbl0=*(const short8v*)(BpL0+kn);
        rbl1=*(const short8v*)(BpL1+kn);
      }
    }
    #pragma unroll
    for(int ks=0;ks<2;ks++){
      short8v af=*(const short8v*)(AsH+(wr+c)*72 + ks*32 + g*8);
      short8v alf;
      if constexpr(PREC==1) alf=*(const short8v*)(AsL+(wr+c)*72 + ks*32 + g*8);
      #pragma unroll
      for(int nt=0;nt<2;nt++){
        short8v bf=*(const short8v*)(BsH+(wc+nt*16+c)*72 + ks*32 + g*8);
        acc[nt]=__builtin_amdgcn_mfma_f32_16x16x32_bf16(af,bf,acc[nt],0,0,0);
        if constexpr(PREC==1){
          short8v blf=*(const short8v*)(BsL+(wc+nt*16+c)*72 + ks*32 + g*8);
          acc[nt]=__builtin_amdgcn_mfma_f32_16x16x32_bf16(af,blf,acc[nt],0,0,0);
          acc[nt]=__builtin_amdgcn_mfma_f32_16x16x32_bf16(alf,bf,acc[nt],0,0,0);
        }
      }
    }
    if(kn>=256) break;
    k0=kn;
  }
  int rb=m0+wr+g*4;
  #pragma unroll
  for(int nt=0;nt<2;nt++){
    int cc=n0+wc+nt*16+c;
    float vv[4];
    #pragma unroll
    for(int j=0;j<4;j++){
      float a=acc[nt][j];
      int rr=rb+j;
      if(MODE==1){
        float xv=bf2f(Xh[Abase+(size_t)rr*256+cc])+bf2f(Xl[Abase+(size_t)rr*256+cc]);
        a=(rr==cc?15.f:0.f)-7.f*xv+a;
      } else if(MODE==2){
        a=(rr==cc?13.f:0.f)-a;
      } else if(MODE==3){
        a*=0.25f;
      }
      vv[j]=a;
    }
    if(MODE==0||MODE==3){
      #pragma unroll
      for(int j=0;j<4;j++){
        unsigned short hh=f2bf(vv[j]);
        Cnh[Abase+(size_t)(rb+j)*256+cc]=hh;
        Cnl[Abase+(size_t)(rb+j)*256+cc]=f2bf(vv[j]-bf2f(hh));
      }
    }
    {
      ushort4 hv, lv;
      hv.x=f2bf(vv[0]); hv.y=f2bf(vv[1]); hv.z=f2bf(vv[2]); hv.w=f2bf(vv[3]);
      lv.x=f2bf(vv[0]-bf2f(hv.x)); lv.y=f2bf(vv[1]-bf2f(hv.y));
      lv.z=f2bf(vv[2]-bf2f(hv.z)); lv.w=f2bf(vv[3]-bf2f(hv.w));
      size_t co=((size_t)bh*Ndim+cc)*256+rb;
      *(ushort4*)(Cth+co)=hv;
      if(MODE!=4) *(ushort4*)(Ctl+co)=lv;
    }
  }
}

// ---------------- attn3@v : MFMA flash, split-K 16 chunks --------------------
__global__ __launch_bounds__(512) void k_attn3m(
    const unsigned short* __restrict__ qlb,
    const unsigned short* __restrict__ kb,
    const unsigned short* __restrict__ vtb,
    float* __restrict__ pacc, float* __restrict__ pms)
{
  __shared__ unsigned short Ks[64*72];
  __shared__ unsigned short Vs[64*72];
  int ck=blockIdx.x, bh=blockIdx.y;
  int t=threadIdx.x, lane=t&63, w=t>>6;
  int c=lane&15, g=lane>>4;
  short8v Qf[2][2];
  #pragma unroll
  for(int n=0;n<2;n++)
    #pragma unroll
    for(int kw=0;kw<2;kw++)
      Qf[n][kw]=*(const short8v*)(qlb + ((size_t)bh*LM + w*32 + n*16 + c)*HD + kw*32 + g*8);
  f32x4 accO[4][2];
  float mrun[2], srun[2];
  #pragma unroll
  for(int n=0;n<2;n++){
    mrun[n]=-3e38f; srun[n]=0.f;
    #pragma unroll
    for(int d=0;d<4;d++) accO[d][n]=(f32x4){0.f,0.f,0.f,0.f};
  }
  int sr=t>>3, sgk=t&7;
  for(int sc=0;sc<16;++sc){
    int key0=ck*1024 + sc*64;
    __syncthreads();
    *(short8v*)(Ks + sr*72 + sgk*8) =
      *(const short8v*)(kb + ((size_t)bh*NPAD + key0 + sr)*HD + sgk*8);
    *(short8v*)(Vs + sr*72 + sgk*8) =
      *(const short8v*)(vtb + ((size_t)bh*HD + sr)*NPAD + key0 + sgk*8);
    __syncthreads();
    f32x4 s[4][2];
    #pragma unroll
    for(int mt=0;mt<4;mt++){
      short8v a0=*(const short8v*)(Ks + (mt*16+c)*72 + g*8);
      short8v a1=*(const short8v*)(Ks + (mt*16+c)*72 + 32 + g*8);
      #pragma unroll
      for(int n=0;n<2;n++){
        f32x4 z=(f32x4){0.f,0.f,0.f,0.f};
        z=__builtin_amdgcn_mfma_f32_16x16x32_bf16(a0,Qf[n][0],z,0,0,0);
        z=__builtin_amdgcn_mfma_f32_16x16x32_bf16(a1,Qf[n][1],z,0,0,0);
        s[mt][n]=z;
      }
    }
    unsigned U[2][4][2];
    #pragma unroll
    for(int n=0;n<2;n++){
      float cm=-3e38f;
      #pragma unroll
      for(int mt=0;mt<4;mt++)
        #pragma unroll
        for(int j=0;j<4;j++) cm=fmaxf(cm,s[mt][n][j]);
      cm=fmaxf(cm,__shfl_xor(cm,16));
      cm=fmaxf(cm,__shfl_xor(cm,32));
      float mnew=fmaxf(mrun[n],cm);
      float f=__expf(mrun[n]-mnew);
      mrun[n]=mnew;
      float ps=0.f;
      #pragma unroll
      for(int mt=0;mt<4;mt++){
        float p0=__expf(s[mt][n][0]-mnew);
        float p1=__expf(s[mt][n][1]-mnew);
        float p2=__expf(s[mt][n][2]-mnew);
        float p3=__expf(s[mt][n][3]-mnew);
        ps+=p0+p1+p2+p3;
        U[n][mt][0]=cvtpk(p0,p1);
        U[n][mt][1]=cvtpk(p2,p3);
      }
      ps+=__shfl_xor(ps,16); ps+=__shfl_xor(ps,32);
      srun[n]=srun[n]*f+ps;
      #pragma unroll
      for(int d=0;d<4;d++){
        accO[d][n][0]*=f; accO[d][n][1]*=f; accO[d][n][2]*=f; accO[d][n][3]*=f;
      }
    }
    #pragma unroll
    for(int kw=0;kw<2;kw++){
      short8v pf[2];
      #pragma unroll
      for(int n=0;n<2;n++){
        union{unsigned u[4]; short8v v;} pk;
        #pragma unroll
        for(int wd=0;wd<4;wd++){
          int sl=c+16*(((g&1)<<1)+(wd>>1));
          unsigned va=(unsigned)__shfl((int)U[n][kw*2  ][wd&1],sl);
          unsigned vb=(unsigned)__shfl((int)U[n][kw*2+1][wd&1],sl);
          pk.u[wd]=(lane>=32)?vb:va;
        }
        pf[n]=pk.v;
      }
      #pragma unroll
      for(int d=0;d<4;d++){
        short8v vf=*(const short8v*)(Vs + (d*16+c)*72 + kw*32 + g*8);
        accO[d][0]=__builtin_amdgcn_mfma_f32_16x16x32_bf16(vf,pf[0],accO[d][0],0,0,0);
        accO[d][1]=__builtin_amdgcn_mfma_f32_16x16x32_bf16(vf,pf[1],accO[d][1],0,0,0);
      }
    }
  }
  size_t pb=((size_t)bh*16+ck)*LM;
  #pragma unroll
  for(int n=0;n<2;n++){
    int q=w*32+n*16+c;
    #pragma unroll
    for(int d=0;d<4;d++)
      *(f32x4*)(pacc + (pb+q)*HD + d*16 + g*4)=accO[d][n];
    if(g==0){ pms[(pb+q)*2]=mrun[n]; pms[(pb+q)*2+1]=srun[n]; }
  }
}
__global__ __launch_bounds__(256) void k_attn3vc(
    const float* __restrict__ pacc, const float* __restrict__ pms,
    unsigned short* __restrict__ a3vth, unsigned short* __restrict__ a3vtl)
{
  int gid=blockIdx.x*4+(threadIdx.x>>6);
  int bh=gid>>8, row=gid&255, lane=threadIdx.x&63;
  float M=-3e38f;
  float ms[16], ss[16];
  #pragma unroll
  for(int c=0;c<16;c++){
    size_t pb=((size_t)bh*16+c)*LM+row;
    ms[c]=pms[pb*2]; ss[c]=pms[pb*2+1];
    M=fmaxf(M,ms[c]);
  }
  float S=0.f,a=0.f;
  #pragma unroll
  for(int c=0;c<16;c++){
    float f=__expf(ms[c]-M);
    S+=ss[c]*f;
    a+=pacc[(((size_t)bh*16+c)*LM+row)*HD+lane]*f;
  }
  float v=a/S;
  unsigned short hi=f2bf(v);
  a3vth[((size_t)bh*HD+lane)*LM+row]=hi;
  a3vtl[((size_t)bh*HD+lane)*LM+row]=f2bf(v-bf2f(hi));
}

// ---------------- attn1 @ W2 : MFMA, 256 landmarks one-shot; bf16 out --------
__global__ __launch_bounds__(512) void k_attn1m(
    const unsigned short* __restrict__ qb,
    const unsigned short* __restrict__ klb,
    const unsigned short* __restrict__ w2t,
    unsigned short* __restrict__ aohb)
{
  __shared__ unsigned short klS[256*72];
  __shared__ unsigned short w2S[64*264];
  int qt=blockIdx.x, bh=blockIdx.y;
  int t=threadIdx.x, lane=t&63, w=t>>6;
  int c=lane&15, g=lane>>4;
  {
    int r=t>>1, hf=t&1;
    const short8v* s=(const short8v*)(klb + ((size_t)bh*LM+r)*HD + hf*32);
    short8v* d=(short8v*)(klS + r*72 + hf*32);
    d[0]=s[0]; d[1]=s[1]; d[2]=s[2]; d[3]=s[3];
    int r2=t>>3, sg2=t&7;
    const short8v* s2=(const short8v*)(w2t + ((size_t)bh*HD+r2)*LM + sg2*32);
    short8v* d2=(short8v*)(w2S + r2*264 + sg2*32);
    d2[0]=s2[0]; d2[1]=s2[1]; d2[2]=s2[2]; d2[3]=s2[3];
  }
  __syncthreads();
  int q0=qt*256 + w*32;
  #pragma unroll
  for(int n=0;n<2;n++){
    const unsigned short* qrow=qb + ((size_t)bh*NPAD + q0 + n*16 + c)*HD;
    short8v qf0=*(const short8v*)(qrow + g*8);
    short8v qf1=*(const short8v*)(qrow + 32 + g*8);
    f32x4 s[16];
    #pragma unroll
    for(int mt=0;mt<16;mt++){
      short8v a0=*(const short8v*)(klS + (mt*16+c)*72 + g*8);
      short8v a1=*(const short8v*)(klS + (mt*16+c)*72 + 32 + g*8);
      f32x4 z=(f32x4){0.f,0.f,0.f,0.f};
      z=__builtin_amdgcn_mfma_f32_16x16x32_bf16(a0,qf0,z,0,0,0);
      z=__builtin_amdgcn_mfma_f32_16x16x32_bf16(a1,qf1,z,0,0,0);
      s[mt]=z;
    }
    float M=-3e38f;
    #pragma unroll
    for(int mt=0;mt<16;mt++)
      #pragma unroll
      for(int j=0;j<4;j++) M=fmaxf(M,s[mt][j]);
    M=fmaxf(M,__shfl_xor(M,16));
    M=fmaxf(M,__shfl_xor(M,32));
    float sum=0.f;
    unsigned U[16][2];
    #pragma unroll
    for(int mt=0;mt<16;mt++){
      float p0=__expf(s[mt][0]-M);
      float p1=__expf(s[mt][1]-M);
      float p2=__expf(s[mt][2]-M);
      float p3=__expf(s[mt][3]-M);
      sum+=p0+p1+p2+p3;
      U[mt][0]=cvtpk(p0,p1);
      U[mt][1]=cvtpk(p2,p3);
    }
    sum+=__shfl_xor(sum,16); sum+=__shfl_xor(sum,32);
    float inv=1.f/sum;
    f32x4 accO[4];
    #pragma unroll
    for(int d=0;d<4;d++) accO[d]=(f32x4){0.f,0.f,0.f,0.f};
    #pragma unroll
    for(int kw=0;kw<8;kw++){
      union{unsigned u[4]; short8v v;} pk;
      #pragma unroll
      for(int wd=0;wd<4;wd++){
        int sl=c+16*(((g&1)<<1)+(wd>>1));
        unsigned va=(unsigned)__shfl((int)U[kw*2  ][wd&1],sl);
        unsigned vb=(unsigned)__shfl((int)U[kw*2+1][wd&1],sl);
        pk.u[wd]=(lane>=32)?vb:va;
      }
      #pragma unroll
      for(int d=0;d<4;d++){
        short8v vf=*(const short8v*)(w2S + (d*16+c)*264 + kw*32 + g*8);
        accO[d]=__builtin_amdgcn_mfma_f32_16x16x32_bf16(vf,pk.v,accO[d],0,0,0);
      }
    }
    int q=q0+n*16+c;
    #pragma unroll
    for(int d=0;d<4;d++){
      f32x4 o=accO[d];
      uint2 pk2;
      pk2.x=cvtpk(o[0]*inv, o[1]*inv);
      pk2.y=cvtpk(o[2]*inv, o[3]*inv);
      *(uint2*)(aohb + ((size_t)bh*NPAD+q)*HD + d*16 + g*4)=pk2;
    }
  }
}

// ---------------- depthwise 33-tap conv from vt; aoh bf16 += -----------------
__global__ __launch_bounds__(256) void k_resconv2(
    const unsigned short* __restrict__ vt, const float* __restrict__ rw,
    unsigned short* __restrict__ aohb){
  int bx=blockIdx.x, bh=blockIdx.y;
  int t=threadIdx.x, d=t&63, g=t>>6;
  int i0=bx*32+g*8;
  int hh=bh&7;
  const unsigned short* vr=vt + ((size_t)bh*HD + d)*NPAD;
  float wv[40];
  int start=i0-16;
  if(start>=0 && start+40<=NPAD){
    #pragma unroll
    for(int b=0;b<5;b++){
      short8v v8=*(const short8v*)(vr+start+b*8);
      #pragma unroll
      for(int j=0;j<8;j++) wv[b*8+j]=bf2f((unsigned short)v8[j]);
    }
  } else {
    #pragma unroll
    for(int t2=0;t2<40;t2++){
      int src=start+t2;
      wv[t2]=(src>=0&&src<NPAD)?bf2f(vr[src]):0.f;
    }
  }
  const float* wt=rw+hh*33;
  #pragma unroll
  for(int p=0;p<8;p++){
    float a=0.f;
    #pragma unroll
    for(int tk=0;tk<33;tk++) a+=wv[p+tk]*wt[tk];
    size_t o=((size_t)bh*NPAD+i0+p)*HD+d;
    aohb[o]=f2bf(bf2f(aohb[o])+a);
  }
}

// ---------------- PPEG weight prep: combined 7x7 tap table (bf16) -----------
__global__ void k_wprep(const float* __restrict__ w7, const float* __restrict__ b7,
                        const float* __restrict__ w5, const float* __restrict__ b5,
                        const float* __restrict__ w3, const float* __restrict__ b3,
                        unsigned short* __restrict__ wcat){
  int t=blockIdx.x*256+threadIdx.x;
  if(t>=50*512) return;
  int r=t>>9, c=t&511;
  float v;
  if(r<49){
    int ky=r/7, kx=r%7;
    v=w7[(size_t)c*49+r];
    if(ky>=1&&ky<=5&&kx>=1&&kx<=5) v+=w5[(size_t)c*25+(ky-1)*5+(kx-1)];
    if(ky>=2&&ky<=4&&kx>=2&&kx<=4) v+=w3[(size_t)c*9+(ky-2)*3+(kx-2)];
  } else {
    v=b7[c]+b5[c]+b3[c];
  }
  wcat[t]=f2bf(v);
}

// ---------------- PPEG: 8x8 tile x 32ch, f32 patch, sliding row window ------
__global__ __launch_bounds__(256,4) void k_ppeg4(
    const float* __restrict__ src, const unsigned short* __restrict__ wcat,
    float* __restrict__ dst)
{
  __shared__ float patch[196][32];   // 14x14 halo
  __shared__ float wsf[50][32];
  int bx=blockIdx.x;
  int cz=blockIdx.y, bb=blockIdx.z;
  int t=threadIdx.x, c=t&31, g=t>>5;   // 32ch x 8 groups
  int ty0=(bx>>4)*8, tx0=(bx&15)*8;
  const float* base=src+((size_t)bb*NTOK+1)*DM + cz*32 + c;
  #pragma unroll
  for(int i=0;i<25;i++){
    int p=g+8*i;
    if(p<196){
      int py=p/14, px=p%14;
      int yy=ty0-3+py, xx=tx0-3+px;
      float v=0.f;
      if(yy>=0&&yy<127&&xx>=0&&xx<127) v=base[(size_t)(yy*127+xx)*DM];
      patch[p][c]=v;
    }
  }
  #pragma unroll
  for(int i=0;i<7;i++){
    int r=g+8*i; if(r<50) wsf[r][c]=bf2f(wcat[(size_t)r*DM + cz*32 + c]);
  }
  __syncthreads();
  float acc[8];
  float bias=wsf[49][c];
  #pragma unroll
  for(int j=0;j<8;j++) acc[j]=patch[(g+3)*14+(j+3)][c]+bias;  // exact identity
  #pragma unroll
  for(int ky=0;ky<7;ky++){
    float win[14];
    #pragma unroll
    for(int x=0;x<14;x++) win[x]=patch[(g+ky)*14+x][c];
    #pragma unroll
    for(int kx=0;kx<7;kx++){
      float wv=wsf[ky*7+kx][c];
      #pragma unroll
      for(int j=0;j<8;j++) acc[j]+=win[j+kx]*wv;
    }
  }
  int y=ty0+g;
  if(y<127){
    #pragma unroll
    for(int j=0;j<8;j++){
      int x=tx0+j;
      if(x<127)
        dst[((size_t)bb*NTOK+1+(size_t)(y*127+x))*DM + cz*32 + c]=acc[j];
    }
  }
}

// copy cls row h -> dst
__global__ void k_cpcls(const float* __restrict__ h, float* __restrict__ dst){
  int t=blockIdx.x*256+threadIdx.x;
  if(t<2*DM) dst[(size_t)(t>>9)*NTOK*DM + (t&511)]=h[(size_t)(t>>9)*NTOK*DM + (t&511)];
}

// ---------------- final: LN(h[:,0]) @ fc2 + b ----------------
__global__ __launch_bounds__(256) void k_final(
    const float* __restrict__ h, const float* __restrict__ g, const float* __restrict__ bta,
    const float* __restrict__ w, const float* __restrict__ fb, float* __restrict__ out)
{
  int bb=blockIdx.x, t=threadIdx.x;
  const float* src=h+(size_t)bb*NTOK*DM;
  float x0=src[t], x1=src[t+256];
  __shared__ float s4[4];
  float mu=block_sum256(x0+x1,s4)*(1.f/512.f);
  float d0=x0-mu, d1=x1-mu;
  float var=block_sum256(d0*d0+d1*d1,s4)*(1.f/512.f);
  float rst=rsqrtf(var+1e-5f);
  float y0=d0*rst*g[t]+bta[t], y1=d1*rst*g[t+256]+bta[t+256];
  float dot=block_sum256(y0*w[t]+y1*w[t+256],s4);
  if(t==0) out[bb]=dot+fb[0];
}

// =======================================================================
extern "C" void kernel_launch(void* const* d_in, const int* in_sizes, int n_in,
                              void* d_out, int out_size, void* d_ws, size_t ws_size,
                              hipStream_t stream){
  (void)in_sizes; (void)n_in; (void)out_size; (void)ws_size;
  const float* features=(const float*)d_in[0];
  const float* fc1_w  =(const float*)d_in[1];
  const float* fc1_b  =(const float*)d_in[2];
  const float* cls_tok=(const float*)d_in[3];
  const float* fc2_w  =(const float*)d_in[24];
  const float* fc2_b  =(const float*)d_in[25];
  float* out=(float*)d_out;

  char* wp=(char*)d_ws;
  auto allocB=[&](size_t bytes)->char*{
    char* p=wp; wp+=((bytes+255)/256)*256; return p;
  };
  float* h    =(float*)allocB((size_t)NB*NTOK*DM*4);
  float* h2   =(float*)allocB((size_t)NB*NTOK*DM*4);
  unsigned short* vb  =(unsigned short*)allocB((size_t)NB*NPAD*DM*2);
  unsigned short* xlnb=(unsigned short*)allocB((size_t)NB*NPAD*DM*2);
  unsigned short* qb  =(unsigned short*)allocB((size_t)NB*NPAD*DM*2);
  unsigned short* kb  =(unsigned short*)allocB((size_t)NB*NPAD*DM*2);
  unsigned short* vtb =(unsigned short*)allocB((size_t)NB*NPAD*DM*2);
  unsigned short* aohb=(unsigned short*)allocB((size_t)NB*NPAD*DM*2);
  unsigned short* wtf=(unsigned short*)allocB((size_t)512*1024*2);
  unsigned short* wtq=(unsigned short*)allocB((size_t)1536*512*2);
  unsigned short* wtp=(unsigned short*)allocB((size_t)512*512*2);
  float* ql =(float*)allocB((size_t)16*LM*HD*4);
  float* kl =(float*)allocB((size_t)16*LM*HD*4);
  unsigned short* qlb=(unsigned short*)allocB((size_t)16*LM*HD*2);
  unsigned short* klb=(unsigned short*)allocB((size_t)16*LM*HD*2);
  float* attn2=(float*)allocB((size_t)16*LM*LM*4);
  unsigned short* a2h=(unsigned short*)allocB((size_t)16*LM*LM*2);
  unsigned short* a2l=(unsigned short*)allocB((size_t)16*LM*LM*2);
  unsigned short* zb[8];
  for(int i=0;i<8;i++) zb[i]=(unsigned short*)allocB((size_t)16*LM*LM*2);
  unsigned short* Abh=(unsigned short*)allocB((size_t)16*LM*LM*2);
  unsigned short* Abl=(unsigned short*)allocB((size_t)16*LM*LM*2);
  unsigned short* Abth=(unsigned short*)allocB((size_t)16*LM*LM*2);
  unsigned short* Abtl=(unsigned short*)allocB((size_t)16*LM*LM*2);
  unsigned short* Ubth=(unsigned short*)allocB((size_t)16*LM*LM*2);
  unsigned short* Ubtl=(unsigned short*)allocB((size_t)16*LM*LM*2);
  unsigned short* Tbth=(unsigned short*)allocB((size_t)16*LM*LM*2);
  unsigned short* Tbtl=(unsigned short*)allocB((size_t)16*LM*LM*2);
  unsigned short* a3vth=(unsigned short*)allocB((size_t)16*HD*LM*2);
  unsigned short* a3vtl=(unsigned short*)allocB((size_t)16*HD*LM*2);
  unsigned short* w2t=(unsigned short*)allocB((size_t)16*HD*LM*2);
  float* pacc=(float*)allocB((size_t)16*16*LM*HD*4);
  float* pms =(float*)allocB((size_t)16*16*LM*2*4);
  float* cs  =(float*)allocB(4096*4);
  float* scl =(float*)allocB(64*4);

  auto nystrom=[&](float* hbuf, const float* ng, const float* nbias, const float* qkvw,
                   const float* outw, const float* outb, const float* resw){
    k_lnpad<<<NB*NPAD,256,0,stream>>>(hbuf, ng, nbias, xlnb);
    k_wconv_t<<<(512*1536+255)/256,256,0,stream>>>(qkvw, wtq, 512, 1536);
    k_mfma_gemm<1,0><<<dim3(12,256),256,0,stream>>>(xlnb, wtq, 32768,1536,512,
                                                    nullptr, qb, kb, vb);
    k_lmean2<<<8192,64,0,stream>>>(qb, kb, ql, qlb, kl, klb);
    k_vtrans<<<dim3(256,16),256,0,stream>>>(vb, vtb);
    k_attn2<<<4096,256,0,stream>>>(ql, kl, attn2, a2h, a2l);
    k_colsum<<<16,256,0,stream>>>(attn2, cs);
    k_pinvscale<<<1,256,0,stream>>>(cs, scl);
    k_zinit_hl<<<4096,256,0,stream>>>(attn2, scl, zb[0],zb[1],zb[2],zb[3]);
    unsigned short *zch=zb[0],*zcl=zb[1],*zcth=zb[2],*zctl=zb[3];
    unsigned short *znh=zb[4],*znl=zb[5],*znth=zb[6],*zntl=zb[7];
    for(int it=0;it<6;it++){
      if(it<5){
        k_bmm3<0,0><<<dim3(4,8,16),256,0,stream>>>(a2h,a2l, zcth,zctl, nullptr,nullptr,
                                                   Abh,Abl, Abth,Abtl, 256);
        k_bmm3<1,0><<<dim3(4,8,16),256,0,stream>>>(Abh,Abl, Abth,Abtl, Abh,Abl,
                                                   nullptr,nullptr, Ubth,Ubtl, 256);
        k_bmm3<2,0><<<dim3(4,8,16),256,0,stream>>>(Abh,Abl, Ubth,Ubtl, nullptr,nullptr,
                                                   nullptr,nullptr, Tbth,Tbtl, 256);
        k_bmm3<3,0><<<dim3(4,8,16),256,0,stream>>>(zch,zcl, Tbth,Tbtl, nullptr,nullptr,
                                                   znh,znl, znth,zntl, 256);
      } else {
        k_bmm3<0,1><<<dim3(4,8,16),256,0,stream>>>(a2h,a2l, zcth,zctl, nullptr,nullptr,
                                                   Abh,Abl, Abth,Abtl, 256);
        k_bmm3<1,1><<<dim3(4,8,16),256,0,stream>>>(Abh,Abl, Abth,Abtl, Abh,Abl,
                                                   nullptr,nullptr, Ubth,Ubtl, 256);
        k_bmm3<2,1><<<dim3(4,8,16),256,0,stream>>>(Abh,Abl, Ubth,Ubtl, nullptr,nullptr,
                                                   nullptr,nullptr, Tbth,Tbtl, 256);
        k_bmm3<3,1><<<dim3(4,8,16),256,0,stream>>>(zch,zcl, Tbth,Tbtl, nullptr,nullptr,
                                                   znh,znl, znth,zntl, 256);
      }
      unsigned short* tp;
      tp=zch; zch=znh; znh=tp;  tp=zcl; zcl=znl; znl=tp;
      tp=zcth; zcth=znth; znth=tp;  tp=zctl; zctl=zntl; zntl=tp;
    }
    k_attn3m<<<dim3(16,16),512,0,stream>>>(qlb, kb, vtb, pacc, pms);
    k_attn3vc<<<1024,256,0,stream>>>(pacc, pms, a3vth, a3vtl);
    k_bmm3<4,1><<<dim3(1,8,16),256,0,stream>>>(zch,zcl, a3vth,a3vtl, nullptr,nullptr,
                                               nullptr,nullptr, w2t,nullptr, 64);
    k_attn1m<<<dim3(64,16),512,0,stream>>>(qb, klb, w2t, aohb);
    k_resconv2<<<dim3(512,16),256,0,stream>>>(vtb, resw, aohb);
    k_wconv_t<<<(512*512+255)/256,256,0,stream>>>(outw, wtp, 512, 512);
    k_mfma_gemm<2,3><<<dim3(4,256),256,0,stream>>>(aohb, wtp, 32768,512,512,
                                                   outb, hbuf, nullptr, nullptr);
  };

  // fc1: features -> bf16 (h2 overlay), then MFMA GEMM via global_load_lds
  unsigned short* featbf=(unsigned short*)h2;   // dead before PPEG
  k_f2bf4<<<32000,256,0,stream>>>(features, featbf, 32000*1024/4);
  k_wconv_t<<<(1024*512+255)/256,256,0,stream>>>(fc1_w, wtf, 1024, 512);
  k_mfma_gemm<0,0><<<dim3(4,250),256,0,stream>>>(featbf, wtf, 32000,512,1024,
                                                 fc1_b, h, nullptr, nullptr);
  k_cls<<<4,256,0,stream>>>(cls_tok, h);

  // layer 1 attention (on h)
  nystrom(h, (const float*)d_in[4],(const float*)d_in[5],(const float*)d_in[6],
          (const float*)d_in[7],(const float*)d_in[8],(const float*)d_in[9]);

  // PPEG: combined-tap stencil h -> h2 (no copy-back; layer 2 runs on h2)
  {
    unsigned short* wcat=(unsigned short*)attn2;  // free at this point
    k_wprep<<<100,256,0,stream>>>(
        (const float*)d_in[10],(const float*)d_in[11],
        (const float*)d_in[12],(const float*)d_in[13],
        (const float*)d_in[14],(const float*)d_in[15], wcat);
    k_cpcls<<<4,256,0,stream>>>(h, h2);
    k_ppeg4<<<dim3(256,16,2),256,0,stream>>>(h, wcat, h2);
  }

  // layer 2 attention (on h2)
  nystrom(h2, (const float*)d_in[16],(const float*)d_in[17],(const float*)d_in[18],
          (const float*)d_in[19],(const float*)d_in[20],(const float*)d_in[21]);

  // final LN(h2[:,0]) @ fc2
  k_final<<<2,256,0,stream>>>(h2,(const float*)d_in[22],(const float*)d_in[23],
                              fc2_w, fc2_b, out);
}

// Round 18
// 1267.710 us; speedup vs baseline: 1.2530x; 1.0007x over previous
//
#include <hip/hip_runtime.h>
#include <math.h>

#define NTOK 16130   // 1 + 127*127
#define NPAD 16384
#define PADF 254
#define NB   2
#define DM   512
#define NH   8
#define HD   64
#define LM   256
#define SEG  64

typedef __attribute__((ext_vector_type(8))) short short8v;
typedef __attribute__((ext_vector_type(4))) float f32x4;
typedef unsigned int u32;

// ---------------- helpers ----------------
__device__ __forceinline__ float wred_max(float v){
  #pragma unroll
  for(int o=32;o;o>>=1) v=fmaxf(v,__shfl_xor(v,o));
  return v;
}
__device__ __forceinline__ float wred_sum(float v){
  #pragma unroll
  for(int o=32;o;o>>=1) v+=__shfl_xor(v,o);
  return v;
}
__device__ __forceinline__ float block_max256(float v, float* s4){
  v=wred_max(v);
  if((threadIdx.x&63)==0) s4[threadIdx.x>>6]=v;
  __syncthreads();
  v=fmaxf(fmaxf(s4[0],s4[1]),fmaxf(s4[2],s4[3]));
  __syncthreads();
  return v;
}
__device__ __forceinline__ float block_sum256(float v, float* s4){
  v=wred_sum(v);
  if((threadIdx.x&63)==0) s4[threadIdx.x>>6]=v;
  __syncthreads();
  v=s4[0]+s4[1]+s4[2]+s4[3];
  __syncthreads();
  return v;
}
__device__ __forceinline__ unsigned short f2bf(float f){
  unsigned u=__float_as_uint(f);
  u = u + 0x7FFFu + ((u>>16)&1u);
  return (unsigned short)(u>>16);
}
__device__ __forceinline__ float bf2f(unsigned short u){
  return __uint_as_float(((unsigned)u)<<16);
}
__device__ __forceinline__ unsigned cvtpk(float a, float b){
  unsigned r;
  asm("v_cvt_pk_bf16_f32 %0, %1, %2" : "=v"(r) : "v"(a), "v"(b));
  return r;
}
// async global->LDS, 16B per lane
__device__ __forceinline__ void gl16(const unsigned short* g, unsigned short* l){
  __builtin_amdgcn_global_load_lds(
      (const __attribute__((address_space(1))) u32*)(g),
      (__attribute__((address_space(3))) u32*)(l), 16, 0, 0);
}

// ---------------- conversions ----------------
__global__ void k_f2bf4(const float* __restrict__ x, unsigned short* __restrict__ y, int n4){
  int i=blockIdx.x*256+threadIdx.x; if(i>=n4) return;
  float4 v=((const float4*)x)[i];
  ushort4 r; r.x=f2bf(v.x); r.y=f2bf(v.y); r.z=f2bf(v.z); r.w=f2bf(v.w);
  ((ushort4*)y)[i]=r;
}
// W[K][N] f32 -> Wt[N][K] bf16
__global__ void k_wconv_t(const float* __restrict__ W, unsigned short* __restrict__ Wt,
                          int K, int N){
  int idx=blockIdx.x*256+threadIdx.x; if(idx>=K*N) return;
  int k=idx/N, n=idx%N;
  Wt[(size_t)n*K+k]=f2bf(W[idx]);
}

// ---------------- MFMA bf16 GEMM: 128x128 tile, BK=32, XCD swizzle -----------
// ASRC 0: A bf16 row-major (global_load_lds staging)
// ASRC 3: A bf16 head-major [bb][8][NPAD][64] (global_load_lds staging)
template<int MODE, int ASRC>
__global__ __launch_bounds__(256) void k_mfma_gemm(
    const void* __restrict__ Ap, const unsigned short* __restrict__ Bt,
    int M, int N, int K,
    const float* __restrict__ bias,
    void* __restrict__ o0, void* __restrict__ o1, void* __restrict__ o2)
{
  __shared__ __align__(16) unsigned short Sh[128*64];   // As=Sh[0..4095], Bs=Sh[4096..]
  int t=threadIdx.x;
  int bx=blockIdx.x, by=blockIdx.y;
  { // bijective XCD swizzle (grid size divisible by 8)
    int gx=gridDim.x; int wg=by*gx+bx; int nwg=gx*gridDim.y;
    int cpx=nwg>>3; int x2=(wg&7)*cpx+(wg>>3);
    by=x2/gx; bx=x2-by*gx;
  }
  int row0=by*128, col0=bx*128;
  int lane=t&63, w=t>>6, wr=w>>1, wc=w&1, lr=lane&15, kg=lane>>4;
  f32x4 acc[4][4];
  #pragma unroll
  for(int m=0;m<4;m++)
    #pragma unroll
    for(int n=0;n<4;n++) acc[m][n]=(f32x4){0.f,0.f,0.f,0.f};

  for(int k0=0;k0<K;k0+=32){
    __syncthreads();   // previous tile fully consumed
    #pragma unroll
    for(int i=0;i<2;i++){
      int flat=i*256+t, r=flat>>2, k8=flat&3;
      int kofs=k0+k8*8;
      const unsigned short* asrc;
      if constexpr(ASRC==0){
        asrc=(const unsigned short*)Ap+(size_t)(row0+r)*K+kofs;
      } else {
        int rr2=row0+r; int bb=rr2>>14, ri=rr2&16383;
        int head=kofs>>6, dd=kofs&63;
        asrc=(const unsigned short*)Ap + (((size_t)bb*NH+head)*NPAD+ri)*HD + dd;
      }
      gl16(asrc, Sh+(size_t)flat*8);
      gl16(Bt+(size_t)(col0+r)*K+kofs, Sh+4096+(size_t)flat*8);
    }
    __syncthreads();   // data ready (vmcnt/lgkm drained before barrier)
    short8v af[4], bf[4];
    #pragma unroll
    for(int m=0;m<4;m++) af[m]=*(const short8v*)(Sh+(wr*64+m*16+lr)*32 + kg*8);
    #pragma unroll
    for(int n=0;n<4;n++) bf[n]=*(const short8v*)(Sh+4096+(wc*64+n*16+lr)*32 + kg*8);
    #pragma unroll
    for(int m=0;m<4;m++)
      #pragma unroll
      for(int n=0;n<4;n++)
        acc[m][n]=__builtin_amdgcn_mfma_f32_16x16x32_bf16(af[m],bf[n],acc[m][n],0,0,0);
  }
  // ---- epilogue ----
  if constexpr(MODE==1){
    // coalesced q/k/v store via LDS restage (2 passes of 64 rows x 128 cols bf16)
    #pragma unroll
    for(int p=0;p<2;p++){
      __syncthreads();
      #pragma unroll
      for(int mm=0;mm<2;mm++){
        int m=2*p+mm;
        #pragma unroll
        for(int n=0;n<4;n++){
          int cc=wc*64+n*16+lr;
          int c=col0+cc;
          float sc=((c>>9)==0)?0.125f:1.f;
          #pragma unroll
          for(int j=0;j<4;j++){
            int lrow=wr*32+mm*16+kg*4+j;
            Sh[lrow*128+cc]=f2bf(acc[m][n][j]*sc);
          }
        }
      }
      __syncthreads();
      #pragma unroll
      for(int i=0;i<4;i++){
        int p2=i*256+t;
        int r2=p2>>4, ck=p2&15;
        int grow=row0+(r2>>5)*64+(2*p+((r2>>4)&1))*16+(r2&15);
        int bb=grow>>14, rr=grow&16383;
        int c=col0+ck*8;
        int which=c>>9, hcol=c&511, head=hcol>>6, dd=hcol&63;
        unsigned short* dst=(which==0)?(unsigned short*)o0:
                            (which==1)?(unsigned short*)o1:(unsigned short*)o2;
        *(short8v*)(dst + (((size_t)bb*NH+head)*NPAD+rr)*HD+dd) =
            *(const short8v*)(Sh + r2*128 + ck*8);
      }
    }
  } else {
    #pragma unroll
    for(int m=0;m<4;m++){
      int rbase=row0 + wr*64 + m*16 + kg*4;
      #pragma unroll
      for(int j=0;j<4;j++){
        int r=rbase+j;
        #pragma unroll
        for(int n=0;n<4;n++){
          int c=col0 + wc*64 + n*16 + lr;
          float val=acc[m][n][j];
          if(MODE==0){
            float* h=(float*)o0;
            int bb=(r>=16000)?1:0, ii=r-bb*16000;
            float vv=fmaxf(val+bias[c],0.f);
            h[((size_t)bb*NTOK + 1 + ii)*DM + c]=vv;
            if(ii<129) h[((size_t)bb*NTOK + 16001 + ii)*DM + c]=vv;
          } else {
            float* h=(float*)o0;
            int bb=r>>14, rr=r&16383;
            if(rr>=PADF)
              h[((size_t)bb*NTOK + (rr-PADF))*DM + c]+=val+bias[c];
          }
        }
      }
    }
  }
}

__global__ void k_cls(const float* __restrict__ cls, float* __restrict__ h){
  int t=blockIdx.x*256+threadIdx.x;
  if(t<2*DM) h[(size_t)(t>>9)*NTOK*DM + (t&511)]=cls[t&511];
}

// ---------------- layernorm + front zero-pad -> bf16 ----------------
__global__ __launch_bounds__(256) void k_lnpad(
    const float* __restrict__ h, const float* __restrict__ g,
    const float* __restrict__ bta, unsigned short* __restrict__ xln)
{
  int r=blockIdx.x;
  int bb=r>>14, i=r&16383;
  int t=threadIdx.x;
  unsigned short* dst=xln+(size_t)r*DM;
  if(i<PADF){ dst[t]=0; dst[t+256]=0; return; }
  const float* src=h+((size_t)bb*NTOK + (i-PADF))*DM;
  float x0=src[t], x1=src[t+256];
  __shared__ float s4[4];
  float mu=block_sum256(x0+x1,s4)*(1.f/512.f);
  float d0=x0-mu, d1=x1-mu;
  float var=block_sum256(d0*d0+d1*d1,s4)*(1.f/512.f);
  float rst=rsqrtf(var+1e-5f);
  dst[t]    =f2bf(d0*rst*g[t]    +bta[t]);
  dst[t+256]=f2bf(d1*rst*g[t+256]+bta[t+256]);
}

// ---------------- landmark means, q and k in one launch ----------------
__global__ void k_lmean2(const unsigned short* __restrict__ qsrc,
                         const unsigned short* __restrict__ ksrc,
                         float* __restrict__ qlf, unsigned short* __restrict__ qlb_,
                         float* __restrict__ klf, unsigned short* __restrict__ klb_){
  int gid=blockIdx.x;
  const unsigned short* src; float* dstf; unsigned short* dstb;
  if(gid<4096){ src=qsrc; dstf=qlf; dstb=qlb_; }
  else        { src=ksrc; dstf=klf; dstb=klb_; gid-=4096; }
  int bh=gid>>8, s=gid&255, d=threadIdx.x;  // 64 threads
  const unsigned short* p=src + (((size_t)bh*NPAD)+s*SEG)*HD + d;
  float acc=0.f;
  #pragma unroll
  for(int l=0;l<SEG;l++) acc+=bf2f(p[(size_t)l*HD]);
  float m=acc*(1.f/64.f);
  dstf[((size_t)bh*LM+s)*HD+d]=m;
  dstb[((size_t)bh*LM+s)*HD+d]=f2bf(m);
}

// ---------------- v bf16 head-major -> vt bf16 [bh][64][NPAD] ----------------
__global__ __launch_bounds__(256) void k_vtrans(
    const unsigned short* __restrict__ v, unsigned short* __restrict__ vt)
{
  __shared__ unsigned short tile[64][72];
  int kt=blockIdx.x, bh=blockIdx.y;
  int t=threadIdx.x;
  int r=t>>2, sgq=t&3;
  const short8v* src=(const short8v*)(v + ((size_t)bh*NPAD + kt*64 + r)*HD + sgq*16);
  *(short8v*)(&tile[r][sgq*16])  =src[0];
  *(short8v*)(&tile[r][sgq*16+8])=src[1];
  __syncthreads();
  int d=t>>2;
  union{unsigned short u[16]; short8v v8[2];} pk;
  #pragma unroll
  for(int i=0;i<16;i++) pk.u[i]=tile[sgq*16+i][d];
  short8v* dst=(short8v*)(vt + ((size_t)bh*HD + d)*NPAD + kt*64 + sgq*16);
  dst[0]=pk.v8[0]; dst[1]=pk.v8[1];
}

// ---------------- attn2 = softmax(ql @ kl^T) f32 + fused hi/lo split --------
__global__ __launch_bounds__(256) void k_attn2(
    const float* __restrict__ ql, const float* __restrict__ kl,
    float* __restrict__ attn2,
    unsigned short* __restrict__ a2h, unsigned short* __restrict__ a2l)
{
  __shared__ float qrow[64]; __shared__ float s4[4];
  int bh=blockIdx.x>>8, i=blockIdx.x&255, j=threadIdx.x;
  if(j<64) qrow[j]=ql[((size_t)bh*LM+i)*HD+j];
  __syncthreads();
  const float* kp=kl+((size_t)bh*LM+j)*HD;
  float l=0.f;
  #pragma unroll
  for(int d=0;d<64;d++) l+=qrow[d]*kp[d];
  float m=block_max256(l,s4);
  float e=__expf(l-m);
  float s=block_sum256(e,s4);
  float pv=e/s;
  size_t o=((size_t)bh*LM+i)*LM+j;
  attn2[o]=pv;
  unsigned short hh=f2bf(pv);
  a2h[o]=hh; a2l[o]=f2bf(pv-bf2f(hh));
}

// ---------------- pinv helpers (rowsum of softmax == 1, skip it) ------------
__global__ void k_colsum(const float* __restrict__ x, float* __restrict__ cs){
  int bh=blockIdx.x, j=threadIdx.x;
  const float* p=x+(size_t)bh*65536;
  float s=0.f;
  for(int i=0;i<256;i++) s+=p[(size_t)i*256+j];
  cs[bh*256+j]=s;
}
__global__ void k_pinvscale(const float* __restrict__ cs, float* __restrict__ scale){
  __shared__ float s4[4];
  float mc=-1e30f;
  for(int i=threadIdx.x;i<4096;i+=256) mc=fmaxf(mc,cs[i]);
  mc=block_max256(mc,s4);
  if(threadIdx.x==0) scale[0]=1.f/mc;
}
__global__ void k_zinit_hl(const float* __restrict__ x, const float* __restrict__ scale,
    unsigned short* __restrict__ zh, unsigned short* __restrict__ zl,
    unsigned short* __restrict__ zth, unsigned short* __restrict__ ztl){
  int bh=blockIdx.x>>8, i=blockIdx.x&255, j=threadIdx.x;
  float s=scale[0];
  size_t base=(size_t)bh*65536;
  float vn=x[base+(size_t)j*256+i]*s;   // z0[i][j] = X^T * s
  float vt=x[base+(size_t)i*256+j]*s;   // z0^T[i][j]
  size_t o=base+(size_t)i*256+j;
  unsigned short h=f2bf(vn); zh[o]=h; zl[o]=f2bf(vn-bf2f(h));
  h=f2bf(vt); zth[o]=h; ztl[o]=f2bf(vt-bf2f(h));
}

// ---------------- hi/lo split bf16 MFMA batched GEMM (pinv chain) -----------
// Tile 32(M)x64(N), BK=64, 4 k-steps, grid 512 blocks (2/CU)
// MODE 0: C=A@B (emit normal+trans)    MODE 1: C=15I-7X+acc (trans only)
// MODE 2: C=13I-acc (trans only)       MODE 3: C=0.25*acc (normal+trans)
// MODE 4: C=acc (trans only, hi only; Ndim=64)
// PREC 0: single bf16 product; PREC 1: hi/lo 3-product (f32-equivalent)
template<int MODE, int PREC>
__global__ __launch_bounds__(256) void k_bmm3(
    const unsigned short* __restrict__ Ah, const unsigned short* __restrict__ Al,
    const unsigned short* __restrict__ Bth, const unsigned short* __restrict__ Btl,
    const unsigned short* __restrict__ Xh, const unsigned short* __restrict__ Xl,
    unsigned short* __restrict__ Cnh, unsigned short* __restrict__ Cnl,
    unsigned short* __restrict__ Cth, unsigned short* __restrict__ Ctl,
    int Ndim)
{
  __shared__ unsigned short AsH[32*72], BsH[64*72];
  __shared__ unsigned short AsL[PREC?32*72:8], BsL[PREC?64*72:8];
  int bh=blockIdx.z;
  int n0=blockIdx.x*64, m0=blockIdx.y*32;
  int t=threadIdx.x, lane=t&63, w=t>>6;
  int c=lane&15, g=lane>>4;
  int wr=(w>>1)*16, wc=(w&1)*32;
  f32x4 acc[2];
  acc[0]=(f32x4){0.f,0.f,0.f,0.f};
  acc[1]=(f32x4){0.f,0.f,0.f,0.f};
  size_t Abase=(size_t)bh*65536;
  size_t Bbase=(size_t)bh*(size_t)Ndim*256;
  int r=t>>3, k8=(t&7)*8;
  const unsigned short* ApH =Ah +Abase+(size_t)(m0+r)*256+k8;
  const unsigned short* BpH0=Bth+Bbase+(size_t)(n0+r)*256+k8;
  const unsigned short* BpH1=Bth+Bbase+(size_t)(n0+32+r)*256+k8;
  const unsigned short* ApL =Al +Abase+(size_t)(m0+r)*256+k8;
  const unsigned short* BpL0=Btl+Bbase+(size_t)(n0+r)*256+k8;
  const unsigned short* BpL1=Btl+Bbase+(size_t)(n0+32+r)*256+k8;
  short8v rah,rbh0,rbh1, ral,rbl0,rbl1;
  rah =*(const short8v*)(ApH);
  rbh0=*(const short8v*)(BpH0);
  rbh1=*(const short8v*)(BpH1);
  if constexpr(PREC==1){
    ral =*(const short8v*)(ApL);
    rbl0=*(const short8v*)(BpL0);
    rbl1=*(const short8v*)(BpL1);
  }
  int k0=0;
  for(;;){
    __syncthreads();
    *(short8v*)(AsH + r*72 + k8)=rah;
    *(short8v*)(BsH + r*72 + k8)=rbh0;
    *(short8v*)(BsH + (r+32)*72 + k8)=rbh1;
    if constexpr(PREC==1){
      *(short8v*)(AsL + r*72 + k8)=ral;
      *(short8v*)(BsL + r*72 + k8)=rbl0;
      *(short8v*)(BsL + (r+32)*72 + k8)=rbl1;
    }
    __syncthreads();
    int kn=k0+64;
    if(kn<256){
      rah =*(const short8v*)(ApH +kn);
      rbh0=*(const short8v*)(BpH0+kn);
      rbh1=*(const short8v*)(BpH1+kn);
      if constexpr(PREC==1){
        ral =*(const short8v*)(ApL +kn);
        rbl0=*(const short8v*)(BpL0+kn);
        rbl1=*(const short8v*)(BpL1+kn);
      }
    }
    #pragma unroll
    for(int ks=0;ks<2;ks++){
      short8v af=*(const short8v*)(AsH+(wr+c)*72 + ks*32 + g*8);
      short8v alf;
      if constexpr(PREC==1) alf=*(const short8v*)(AsL+(wr+c)*72 + ks*32 + g*8);
      #pragma unroll
      for(int nt=0;nt<2;nt++){
        short8v bf=*(const short8v*)(BsH+(wc+nt*16+c)*72 + ks*32 + g*8);
        acc[nt]=__builtin_amdgcn_mfma_f32_16x16x32_bf16(af,bf,acc[nt],0,0,0);
        if constexpr(PREC==1){
          short8v blf=*(const short8v*)(BsL+(wc+nt*16+c)*72 + ks*32 + g*8);
          acc[nt]=__builtin_amdgcn_mfma_f32_16x16x32_bf16(af,blf,acc[nt],0,0,0);
          acc[nt]=__builtin_amdgcn_mfma_f32_16x16x32_bf16(alf,bf,acc[nt],0,0,0);
        }
      }
    }
    if(kn>=256) break;
    k0=kn;
  }
  int rb=m0+wr+g*4;
  #pragma unroll
  for(int nt=0;nt<2;nt++){
    int cc=n0+wc+nt*16+c;
    float vv[4];
    #pragma unroll
    for(int j=0;j<4;j++){
      float a=acc[nt][j];
      int rr=rb+j;
      if(MODE==1){
        float xv=bf2f(Xh[Abase+(size_t)rr*256+cc])+bf2f(Xl[Abase+(size_t)rr*256+cc]);
        a=(rr==cc?15.f:0.f)-7.f*xv+a;
      } else if(MODE==2){
        a=(rr==cc?13.f:0.f)-a;
      } else if(MODE==3){
        a*=0.25f;
      }
      vv[j]=a;
    }
    if(MODE==0||MODE==3){
      #pragma unroll
      for(int j=0;j<4;j++){
        unsigned short hh=f2bf(vv[j]);
        Cnh[Abase+(size_t)(rb+j)*256+cc]=hh;
        Cnl[Abase+(size_t)(rb+j)*256+cc]=f2bf(vv[j]-bf2f(hh));
      }
    }
    {
      ushort4 hv, lv;
      hv.x=f2bf(vv[0]); hv.y=f2bf(vv[1]); hv.z=f2bf(vv[2]); hv.w=f2bf(vv[3]);
      lv.x=f2bf(vv[0]-bf2f(hv.x)); lv.y=f2bf(vv[1]-bf2f(hv.y));
      lv.z=f2bf(vv[2]-bf2f(hv.z)); lv.w=f2bf(vv[3]-bf2f(hv.w));
      size_t co=((size_t)bh*Ndim+cc)*256+rb;
      *(ushort4*)(Cth+co)=hv;
      if(MODE!=4) *(ushort4*)(Ctl+co)=lv;
    }
  }
}

// ---------------- attn3@v : MFMA flash, split-K 16 chunks x 2 row-halves -----
__global__ __launch_bounds__(512) void k_attn3m(
    const unsigned short* __restrict__ qlb,
    const unsigned short* __restrict__ kb,
    const unsigned short* __restrict__ vtb,
    float* __restrict__ pacc, float* __restrict__ pms)
{
  __shared__ unsigned short Ks[64*72];
  __shared__ unsigned short Vs[64*72];
  int ck=blockIdx.x, rh=blockIdx.y, bh=blockIdx.z;
  int t=threadIdx.x, lane=t&63, w=t>>6;
  int c=lane&15, g=lane>>4;
  int qrow0=rh*128 + w*16;          // this wave's 16 q-rows: qrow0 + c
  short8v Qf[2];
  #pragma unroll
  for(int kw=0;kw<2;kw++)
    Qf[kw]=*(const short8v*)(qlb + ((size_t)bh*LM + qrow0 + c)*HD + kw*32 + g*8);
  f32x4 accO[4];
  float mrun=-3e38f, srun=0.f;
  #pragma unroll
  for(int d=0;d<4;d++) accO[d]=(f32x4){0.f,0.f,0.f,0.f};
  int sr=t>>3, sgk=t&7;
  for(int sc=0;sc<16;++sc){
    int key0=ck*1024 + sc*64;
    __syncthreads();
    *(short8v*)(Ks + sr*72 + sgk*8) =
      *(const short8v*)(kb + ((size_t)bh*NPAD + key0 + sr)*HD + sgk*8);
    *(short8v*)(Vs + sr*72 + sgk*8) =
      *(const short8v*)(vtb + ((size_t)bh*HD + sr)*NPAD + key0 + sgk*8);
    __syncthreads();
    f32x4 s[4];
    #pragma unroll
    for(int mt=0;mt<4;mt++){
      short8v a0=*(const short8v*)(Ks + (mt*16+c)*72 + g*8);
      short8v a1=*(const short8v*)(Ks + (mt*16+c)*72 + 32 + g*8);
      f32x4 z=(f32x4){0.f,0.f,0.f,0.f};
      z=__builtin_amdgcn_mfma_f32_16x16x32_bf16(a0,Qf[0],z,0,0,0);
      z=__builtin_amdgcn_mfma_f32_16x16x32_bf16(a1,Qf[1],z,0,0,0);
      s[mt]=z;
    }
    unsigned U[4][2];
    {
      float cm=-3e38f;
      #pragma unroll
      for(int mt=0;mt<4;mt++)
        #pragma unroll
        for(int j=0;j<4;j++) cm=fmaxf(cm,s[mt][j]);
      cm=fmaxf(cm,__shfl_xor(cm,16));
      cm=fmaxf(cm,__shfl_xor(cm,32));
      float mnew=fmaxf(mrun,cm);
      float f=__expf(mrun-mnew);
      mrun=mnew;
      float ps=0.f;
      #pragma unroll
      for(int mt=0;mt<4;mt++){
        float p0=__expf(s[mt][0]-mnew);
        float p1=__expf(s[mt][1]-mnew);
        float p2=__expf(s[mt][2]-mnew);
        float p3=__expf(s[mt][3]-mnew);
        ps+=p0+p1+p2+p3;
        U[mt][0]=cvtpk(p0,p1);
        U[mt][1]=cvtpk(p2,p3);
      }
      ps+=__shfl_xor(ps,16); ps+=__shfl_xor(ps,32);
      srun=srun*f+ps;
      #pragma unroll
      for(int d=0;d<4;d++){
        accO[d][0]*=f; accO[d][1]*=f; accO[d][2]*=f; accO[d][3]*=f;
      }
    }
    #pragma unroll
    for(int kw=0;kw<2;kw++){
      union{unsigned u[4]; short8v v;} pk;
      #pragma unroll
      for(int wd=0;wd<4;wd++){
        int sl=c+16*(((g&1)<<1)+(wd>>1));
        unsigned va=(unsigned)__shfl((int)U[kw*2  ][wd&1],sl);
        unsigned vb=(unsigned)__shfl((int)U[kw*2+1][wd&1],sl);
        pk.u[wd]=(lane>=32)?vb:va;
      }
      #pragma unroll
      for(int d=0;d<4;d++){
        short8v vf=*(const short8v*)(Vs + (d*16+c)*72 + kw*32 + g*8);
        accO[d]=__builtin_amdgcn_mfma_f32_16x16x32_bf16(vf,pk.v,accO[d],0,0,0);
      }
    }
  }
  size_t pb=((size_t)bh*16+ck)*LM;
  int q=qrow0+c;
  #pragma unroll
  for(int d=0;d<4;d++)
    *(f32x4*)(pacc + (pb+q)*HD + d*16 + g*4)=accO[d];
  if(g==0){ pms[(pb+q)*2]=mrun; pms[(pb+q)*2+1]=srun; }
}
__global__ __launch_bounds__(256) void k_attn3vc(
    const float* __restrict__ pacc, const float* __restrict__ pms,
    unsigned short* __restrict__ a3vth, unsigned short* __restrict__ a3vtl)
{
  int gid=blockIdx.x*4+(threadIdx.x>>6);
  int bh=gid>>8, row=gid&255, lane=threadIdx.x&63;
  float M=-3e38f;
  float ms[16], ss[16];
  #pragma unroll
  for(int c=0;c<16;c++){
    size_t pb=((size_t)bh*16+c)*LM+row;
    ms[c]=pms[pb*2]; ss[c]=pms[pb*2+1];
    M=fmaxf(M,ms[c]);
  }
  float S=0.f,a=0.f;
  #pragma unroll
  for(int c=0;c<16;c++){
    float f=__expf(ms[c]-M);
    S+=ss[c]*f;
    a+=pacc[(((size_t)bh*16+c)*LM+row)*HD+lane]*f;
  }
  float v=a/S;
  unsigned short hi=f2bf(v);
  a3vth[((size_t)bh*HD+lane)*LM+row]=hi;
  a3vtl[((size_t)bh*HD+lane)*LM+row]=f2bf(v-bf2f(hi));
}

// ---------------- attn1 @ W2 : MFMA, 256 landmarks one-shot; bf16 out --------
__global__ __launch_bounds__(512) void k_attn1m(
    const unsigned short* __restrict__ qb,
    const unsigned short* __restrict__ klb,
    const unsigned short* __restrict__ w2t,
    unsigned short* __restrict__ aohb)
{
  __shared__ unsigned short klS[256*72];
  __shared__ unsigned short w2S[64*264];
  int qt=blockIdx.x, bh=blockIdx.y;
  int t=threadIdx.x, lane=t&63, w=t>>6;
  int c=lane&15, g=lane>>4;
  {
    int r=t>>1, hf=t&1;
    const short8v* s=(const short8v*)(klb + ((size_t)bh*LM+r)*HD + hf*32);
    short8v* d=(short8v*)(klS + r*72 + hf*32);
    d[0]=s[0]; d[1]=s[1]; d[2]=s[2]; d[3]=s[3];
    int r2=t>>3, sg2=t&7;
    const short8v* s2=(const short8v*)(w2t + ((size_t)bh*HD+r2)*LM + sg2*32);
    short8v* d2=(short8v*)(w2S + r2*264 + sg2*32);
    d2[0]=s2[0]; d2[1]=s2[1]; d2[2]=s2[2]; d2[3]=s2[3];
  }
  __syncthreads();
  int q0=qt*256 + w*32;
  #pragma unroll
  for(int n=0;n<2;n++){
    const unsigned short* qrow=qb + ((size_t)bh*NPAD + q0 + n*16 + c)*HD;
    short8v qf0=*(const short8v*)(qrow + g*8);
    short8v qf1=*(const short8v*)(qrow + 32 + g*8);
    f32x4 s[16];
    #pragma unroll
    for(int mt=0;mt<16;mt++){
      short8v a0=*(const short8v*)(klS + (mt*16+c)*72 + g*8);
      short8v a1=*(const short8v*)(klS + (mt*16+c)*72 + 32 + g*8);
      f32x4 z=(f32x4){0.f,0.f,0.f,0.f};
      z=__builtin_amdgcn_mfma_f32_16x16x32_bf16(a0,qf0,z,0,0,0);
      z=__builtin_amdgcn_mfma_f32_16x16x32_bf16(a1,qf1,z,0,0,0);
      s[mt]=z;
    }
    float M=-3e38f;
    #pragma unroll
    for(int mt=0;mt<16;mt++)
      #pragma unroll
      for(int j=0;j<4;j++) M=fmaxf(M,s[mt][j]);
    M=fmaxf(M,__shfl_xor(M,16));
    M=fmaxf(M,__shfl_xor(M,32));
    float sum=0.f;
    unsigned U[16][2];
    #pragma unroll
    for(int mt=0;mt<16;mt++){
      float p0=__expf(s[mt][0]-M);
      float p1=__expf(s[mt][1]-M);
      float p2=__expf(s[mt][2]-M);
      float p3=__expf(s[mt][3]-M);
      sum+=p0+p1+p2+p3;
      U[mt][0]=cvtpk(p0,p1);
      U[mt][1]=cvtpk(p2,p3);
    }
    sum+=__shfl_xor(sum,16); sum+=__shfl_xor(sum,32);
    float inv=1.f/sum;
    f32x4 accO[4];
    #pragma unroll
    for(int d=0;d<4;d++) accO[d]=(f32x4){0.f,0.f,0.f,0.f};
    #pragma unroll
    for(int kw=0;kw<8;kw++){
      union{unsigned u[4]; short8v v;} pk;
      #pragma unroll
      for(int wd=0;wd<4;wd++){
        int sl=c+16*(((g&1)<<1)+(wd>>1));
        unsigned va=(unsigned)__shfl((int)U[kw*2  ][wd&1],sl);
        unsigned vb=(unsigned)__shfl((int)U[kw*2+1][wd&1],sl);
        pk.u[wd]=(lane>=32)?vb:va;
      }
      #pragma unroll
      for(int d=0;d<4;d++){
        short8v vf=*(const short8v*)(w2S + (d*16+c)*264 + kw*32 + g*8);
        accO[d]=__builtin_amdgcn_mfma_f32_16x16x32_bf16(vf,pk.v,accO[d],0,0,0);
      }
    }
    int q=q0+n*16+c;
    #pragma unroll
    for(int d=0;d<4;d++){
      f32x4 o=accO[d];
      uint2 pk2;
      pk2.x=cvtpk(o[0]*inv, o[1]*inv);
      pk2.y=cvtpk(o[2]*inv, o[3]*inv);
      *(uint2*)(aohb + ((size_t)bh*NPAD+q)*HD + d*16 + g*4)=pk2;
    }
  }
}

// ---------------- depthwise 33-tap conv from vt; aoh bf16 += -----------------
__global__ __launch_bounds__(256) void k_resconv2(
    const unsigned short* __restrict__ vt, const float* __restrict__ rw,
    unsigned short* __restrict__ aohb){
  int bx=blockIdx.x, bh=blockIdx.y;
  int t=threadIdx.x, d=t&63, g=t>>6;
  int i0=bx*32+g*8;
  int hh=bh&7;
  const unsigned short* vr=vt + ((size_t)bh*HD + d)*NPAD;
  float wv[40];
  int start=i0-16;
  if(start>=0 && start+40<=NPAD){
    #pragma unroll
    for(int b=0;b<5;b++){
      short8v v8=*(const short8v*)(vr+start+b*8);
      #pragma unroll
      for(int j=0;j<8;j++) wv[b*8+j]=bf2f((unsigned short)v8[j]);
    }
  } else {
    #pragma unroll
    for(int t2=0;t2<40;t2++){
      int src=start+t2;
      wv[t2]=(src>=0&&src<NPAD)?bf2f(vr[src]):0.f;
    }
  }
  const float* wt=rw+hh*33;
  #pragma unroll
  for(int p=0;p<8;p++){
    float a=0.f;
    #pragma unroll
    for(int tk=0;tk<33;tk++) a+=wv[p+tk]*wt[tk];
    size_t o=((size_t)bh*NPAD+i0+p)*HD+d;
    aohb[o]=f2bf(bf2f(aohb[o])+a);
  }
}

// ---------------- PPEG weight prep: combined 7x7 tap table (bf16) -----------
__global__ void k_wprep(const float* __restrict__ w7, const float* __restrict__ b7,
                        const float* __restrict__ w5, const float* __restrict__ b5,
                        const float* __restrict__ w3, const float* __restrict__ b3,
                        unsigned short* __restrict__ wcat){
  int t=blockIdx.x*256+threadIdx.x;
  if(t>=50*512) return;
  int r=t>>9, c=t&511;
  float v;
  if(r<49){
    int ky=r/7, kx=r%7;
    v=w7[(size_t)c*49+r];
    if(ky>=1&&ky<=5&&kx>=1&&kx<=5) v+=w5[(size_t)c*25+(ky-1)*5+(kx-1)];
    if(ky>=2&&ky<=4&&kx>=2&&kx<=4) v+=w3[(size_t)c*9+(ky-2)*3+(kx-2)];
  } else {
    v=b7[c]+b5[c]+b3[c];
  }
  wcat[t]=f2bf(v);
}

// ---------------- PPEG: 8x8 tile x 16ch, f32 patch (padded), high occupancy --
__global__ __launch_bounds__(256) void k_ppeg5(
    const float* __restrict__ src, const unsigned short* __restrict__ wcat,
    float* __restrict__ dst)
{
  __shared__ float patch[196][17];   // 14x14 halo, +1 pad breaks bank conflicts
  __shared__ float wsf[50][16];
  int bx=blockIdx.x;
  int cz=blockIdx.y, bb=blockIdx.z;
  int t=threadIdx.x, c=t&15, g=t>>4;   // 16ch x 16 groups
  int ty0=(bx>>4)*8, tx0=(bx&15)*8;
  const float* base=src+((size_t)bb*NTOK+1)*DM + cz*16 + c;
  #pragma unroll
  for(int i=0;i<13;i++){
    int p=g+16*i;
    if(p<196){
      int py=p/14, px=p%14;
      int yy=ty0-3+py, xx=tx0-3+px;
      float v=0.f;
      if(yy>=0&&yy<127&&xx>=0&&xx<127) v=base[(size_t)(yy*127+xx)*DM];
      patch[p][c]=v;
    }
  }
  #pragma unroll
  for(int i=0;i<4;i++){
    int r=g+16*i; if(r<50) wsf[r][c]=bf2f(wcat[(size_t)r*DM + cz*16 + c]);
  }
  __syncthreads();
  int row=g>>1, ox0=(g&1)*4;       // group owns output row `row`, cols ox0..ox0+3
  float acc[4];
  float bias=wsf[49][c];
  #pragma unroll
  for(int j=0;j<4;j++) acc[j]=patch[(row+3)*14+(ox0+j+3)][c]+bias;  // exact identity
  #pragma unroll
  for(int ky=0;ky<7;ky++){
    float win[10];
    #pragma unroll
    for(int x=0;x<10;x++) win[x]=patch[(row+ky)*14+ox0+x][c];
    #pragma unroll
    for(int kx=0;kx<7;kx++){
      float wv=wsf[ky*7+kx][c];
      #pragma unroll
      for(int j=0;j<4;j++) acc[j]+=win[j+kx]*wv;
    }
  }
  int y=ty0+row;
  if(y<127){
    #pragma unroll
    for(int j=0;j<4;j++){
      int x=tx0+ox0+j;
      if(x<127)
        dst[((size_t)bb*NTOK+1+(size_t)(y*127+x))*DM + cz*16 + c]=acc[j];
    }
  }
}

// copy cls row h -> dst
__global__ void k_cpcls(const float* __restrict__ h, float* __restrict__ dst){
  int t=blockIdx.x*256+threadIdx.x;
  if(t<2*DM) dst[(size_t)(t>>9)*NTOK*DM + (t&511)]=h[(size_t)(t>>9)*NTOK*DM + (t&511)];
}

// ---------------- final: LN(h[:,0]) @ fc2 + b ----------------
__global__ __launch_bounds__(256) void k_final(
    const float* __restrict__ h, const float* __restrict__ g, const float* __restrict__ bta,
    const float* __restrict__ w, const float* __restrict__ fb, float* __restrict__ out)
{
  int bb=blockIdx.x, t=threadIdx.x;
  const float* src=h+(size_t)bb*NTOK*DM;
  float x0=src[t], x1=src[t+256];
  __shared__ float s4[4];
  float mu=block_sum256(x0+x1,s4)*(1.f/512.f);
  float d0=x0-mu, d1=x1-mu;
  float var=block_sum256(d0*d0+d1*d1,s4)*(1.f/512.f);
  float rst=rsqrtf(var+1e-5f);
  float y0=d0*rst*g[t]+bta[t], y1=d1*rst*g[t+256]+bta[t+256];
  float dot=block_sum256(y0*w[t]+y1*w[t+256],s4);
  if(t==0) out[bb]=dot+fb[0];
}

// =======================================================================
extern "C" void kernel_launch(void* const* d_in, const int* in_sizes, int n_in,
                              void* d_out, int out_size, void* d_ws, size_t ws_size,
                              hipStream_t stream){
  (void)in_sizes; (void)n_in; (void)out_size; (void)ws_size;
  const float* features=(const float*)d_in[0];
  const float* fc1_w  =(const float*)d_in[1];
  const float* fc1_b  =(const float*)d_in[2];
  const float* cls_tok=(const float*)d_in[3];
  const float* fc2_w  =(const float*)d_in[24];
  const float* fc2_b  =(const float*)d_in[25];
  float* out=(float*)d_out;

  char* wp=(char*)d_ws;
  auto allocB=[&](size_t bytes)->char*{
    char* p=wp; wp+=((bytes+255)/256)*256; return p;
  };
  float* h    =(float*)allocB((size_t)NB*NTOK*DM*4);
  float* h2   =(float*)allocB((size_t)NB*NTOK*DM*4);
  unsigned short* vb  =(unsigned short*)allocB((size_t)NB*NPAD*DM*2);
  unsigned short* xlnb=(unsigned short*)allocB((size_t)NB*NPAD*DM*2);
  unsigned short* qb  =(unsigned short*)allocB((size_t)NB*NPAD*DM*2);
  unsigned short* kb  =(unsigned short*)allocB((size_t)NB*NPAD*DM*2);
  unsigned short* vtb =(unsigned short*)allocB((size_t)NB*NPAD*DM*2);
  unsigned short* aohb=(unsigned short*)allocB((size_t)NB*NPAD*DM*2);
  unsigned short* wtf=(unsigned short*)allocB((size_t)512*1024*2);
  unsigned short* wtq=(unsigned short*)allocB((size_t)1536*512*2);
  unsigned short* wtp=(unsigned short*)allocB((size_t)512*512*2);
  float* ql =(float*)allocB((size_t)16*LM*HD*4);
  float* kl =(float*)allocB((size_t)16*LM*HD*4);
  unsigned short* qlb=(unsigned short*)allocB((size_t)16*LM*HD*2);
  unsigned short* klb=(unsigned short*)allocB((size_t)16*LM*HD*2);
  float* attn2=(float*)allocB((size_t)16*LM*LM*4);
  unsigned short* a2h=(unsigned short*)allocB((size_t)16*LM*LM*2);
  unsigned short* a2l=(unsigned short*)allocB((size_t)16*LM*LM*2);
  unsigned short* zb[8];
  for(int i=0;i<8;i++) zb[i]=(unsigned short*)allocB((size_t)16*LM*LM*2);
  unsigned short* Abh=(unsigned short*)allocB((size_t)16*LM*LM*2);
  unsigned short* Abl=(unsigned short*)allocB((size_t)16*LM*LM*2);
  unsigned short* Abth=(unsigned short*)allocB((size_t)16*LM*LM*2);
  unsigned short* Abtl=(unsigned short*)allocB((size_t)16*LM*LM*2);
  unsigned short* Ubth=(unsigned short*)allocB((size_t)16*LM*LM*2);
  unsigned short* Ubtl=(unsigned short*)allocB((size_t)16*LM*LM*2);
  unsigned short* Tbth=(unsigned short*)allocB((size_t)16*LM*LM*2);
  unsigned short* Tbtl=(unsigned short*)allocB((size_t)16*LM*LM*2);
  unsigned short* a3vth=(unsigned short*)allocB((size_t)16*HD*LM*2);
  unsigned short* a3vtl=(unsigned short*)allocB((size_t)16*HD*LM*2);
  unsigned short* w2t=(unsigned short*)allocB((size_t)16*HD*LM*2);
  float* pacc=(float*)allocB((size_t)16*16*LM*HD*4);
  float* pms =(float*)allocB((size_t)16*16*LM*2*4);
  float* cs  =(float*)allocB(4096*4);
  float* scl =(float*)allocB(64*4);

  auto nystrom=[&](float* hbuf, const float* ng, const float* nbias, const float* qkvw,
                   const float* outw, const float* outb, const float* resw){
    k_lnpad<<<NB*NPAD,256,0,stream>>>(hbuf, ng, nbias, xlnb);
    k_wconv_t<<<(512*1536+255)/256,256,0,stream>>>(qkvw, wtq, 512, 1536);
    k_mfma_gemm<1,0><<<dim3(12,256),256,0,stream>>>(xlnb, wtq, 32768,1536,512,
                                                    nullptr, qb, kb, vb);
    k_lmean2<<<8192,64,0,stream>>>(qb, kb, ql, qlb, kl, klb);
    k_vtrans<<<dim3(256,16),256,0,stream>>>(vb, vtb);
    k_attn2<<<4096,256,0,stream>>>(ql, kl, attn2, a2h, a2l);
    k_colsum<<<16,256,0,stream>>>(attn2, cs);
    k_pinvscale<<<1,256,0,stream>>>(cs, scl);
    k_zinit_hl<<<4096,256,0,stream>>>(attn2, scl, zb[0],zb[1],zb[2],zb[3]);
    unsigned short *zch=zb[0],*zcl=zb[1],*zcth=zb[2],*zctl=zb[3];
    unsigned short *znh=zb[4],*znl=zb[5],*znth=zb[6],*zntl=zb[7];
    for(int it=0;it<6;it++){
      if(it<5){
        k_bmm3<0,0><<<dim3(4,8,16),256,0,stream>>>(a2h,a2l, zcth,zctl, nullptr,nullptr,
                                                   Abh,Abl, Abth,Abtl, 256);
        k_bmm3<1,0><<<dim3(4,8,16),256,0,stream>>>(Abh,Abl, Abth,Abtl, Abh,Abl,
                                                   nullptr,nullptr, Ubth,Ubtl, 256);
        k_bmm3<2,0><<<dim3(4,8,16),256,0,stream>>>(Abh,Abl, Ubth,Ubtl, nullptr,nullptr,
                                                   nullptr,nullptr, Tbth,Tbtl, 256);
        k_bmm3<3,0><<<dim3(4,8,16),256,0,stream>>>(zch,zcl, Tbth,Tbtl, nullptr,nullptr,
                                                   znh,znl, znth,zntl, 256);
      } else {
        k_bmm3<0,1><<<dim3(4,8,16),256,0,stream>>>(a2h,a2l, zcth,zctl, nullptr,nullptr,
                                                   Abh,Abl, Abth,Abtl, 256);
        k_bmm3<1,1><<<dim3(4,8,16),256,0,stream>>>(Abh,Abl, Abth,Abtl, Abh,Abl,
                                                   nullptr,nullptr, Ubth,Ubtl, 256);
        k_bmm3<2,1><<<dim3(4,8,16),256,0,stream>>>(Abh,Abl, Ubth,Ubtl, nullptr,nullptr,
                                                   nullptr,nullptr, Tbth,Tbtl, 256);
        k_bmm3<3,1><<<dim3(4,8,16),256,0,stream>>>(zch,zcl, Tbth,Tbtl, nullptr,nullptr,
                                                   znh,znl, znth,zntl, 256);
      }
      unsigned short* tp;
      tp=zch; zch=znh; znh=tp;  tp=zcl; zcl=znl; znl=tp;
      tp=zcth; zcth=znth; znth=tp;  tp=zctl; zctl=zntl; zntl=tp;
    }
    k_attn3m<<<dim3(16,2,16),512,0,stream>>>(qlb, kb, vtb, pacc, pms);
    k_attn3vc<<<1024,256,0,stream>>>(pacc, pms, a3vth, a3vtl);
    k_bmm3<4,1><<<dim3(1,8,16),256,0,stream>>>(zch,zcl, a3vth,a3vtl, nullptr,nullptr,
                                               nullptr,nullptr, w2t,nullptr, 64);
    k_attn1m<<<dim3(64,16),512,0,stream>>>(qb, klb, w2t, aohb);
    k_resconv2<<<dim3(512,16),256,0,stream>>>(vtb, resw, aohb);
    k_wconv_t<<<(512*512+255)/256,256,0,stream>>>(outw, wtp, 512, 512);
    k_mfma_gemm<2,3><<<dim3(4,256),256,0,stream>>>(aohb, wtp, 32768,512,512,
                                                   outb, hbuf, nullptr, nullptr);
  };

  // fc1: features -> bf16 (h2 overlay), then MFMA GEMM via global_load_lds
  unsigned short* featbf=(unsigned short*)h2;   // dead before PPEG
  k_f2bf4<<<32000,256,0,stream>>>(features, featbf, 32000*1024/4);
  k_wconv_t<<<(1024*512+255)/256,256,0,stream>>>(fc1_w, wtf, 1024, 512);
  k_mfma_gemm<0,0><<<dim3(4,250),256,0,stream>>>(featbf, wtf, 32000,512,1024,
                                                 fc1_b, h, nullptr, nullptr);
  k_cls<<<4,256,0,stream>>>(cls_tok, h);

  // layer 1 attention (on h)
  nystrom(h, (const float*)d_in[4],(const float*)d_in[5],(const float*)d_in[6],
          (const float*)d_in[7],(const float*)d_in[8],(const float*)d_in[9]);

  // PPEG: combined-tap stencil h -> h2 (no copy-back; layer 2 runs on h2)
  {
    unsigned short* wcat=(unsigned short*)attn2;  // free at this point
    k_wprep<<<100,256,0,stream>>>(
        (const float*)d_in[10],(const float*)d_in[11],
        (const float*)d_in[12],(const float*)d_in[13],
        (const float*)d_in[14],(const float*)d_in[15], wcat);
    k_cpcls<<<4,256,0,stream>>>(h, h2);
    k_ppeg5<<<dim3(256,32,2),256,0,stream>>>(h, wcat, h2);
  }

  // layer 2 attention (on h2)
  nystrom(h2, (const float*)d_in[16],(const float*)d_in[17],(const float*)d_in[18],
          (const float*)d_in[19],(const float*)d_in[20],(const float*)d_in[21]);

  // final LN(h2[:,0]) @ fc2
  k_final<<<2,256,0,stream>>>(h2,(const float*)d_in[22],(const float*)d_in[23],
                              fc2_w, fc2_b, out);
}

// Round 19
// 1263.609 us; speedup vs baseline: 1.2571x; 1.0032x over previous
//
#include <hip/hip_runtime.h>
#include <math.h>

#define NTOK 16130   // 1 + 127*127
#define NPAD 16384
#define PADF 254
#define NB   2
#define DM   512
#define NH   8
#define HD   64
#define LM   256
#define SEG  64

typedef __attribute__((ext_vector_type(8))) short short8v;
typedef __attribute__((ext_vector_type(4))) float f32x4;
typedef unsigned int u32;

// ---------------- helpers ----------------
__device__ __forceinline__ float wred_max(float v){
  #pragma unroll
  for(int o=32;o;o>>=1) v=fmaxf(v,__shfl_xor(v,o));
  return v;
}
__device__ __forceinline__ float wred_sum(float v){
  #pragma unroll
  for(int o=32;o;o>>=1) v+=__shfl_xor(v,o);
  return v;
}
__device__ __forceinline__ float block_max256(float v, float* s4){
  v=wred_max(v);
  if((threadIdx.x&63)==0) s4[threadIdx.x>>6]=v;
  __syncthreads();
  v=fmaxf(fmaxf(s4[0],s4[1]),fmaxf(s4[2],s4[3]));
  __syncthreads();
  return v;
}
__device__ __forceinline__ float block_sum256(float v, float* s4){
  v=wred_sum(v);
  if((threadIdx.x&63)==0) s4[threadIdx.x>>6]=v;
  __syncthreads();
  v=s4[0]+s4[1]+s4[2]+s4[3];
  __syncthreads();
  return v;
}
__device__ __forceinline__ unsigned short f2bf(float f){
  unsigned u=__float_as_uint(f);
  u = u + 0x7FFFu + ((u>>16)&1u);
  return (unsigned short)(u>>16);
}
__device__ __forceinline__ float bf2f(unsigned short u){
  return __uint_as_float(((unsigned)u)<<16);
}
__device__ __forceinline__ unsigned cvtpk(float a, float b){
  unsigned r;
  asm("v_cvt_pk_bf16_f32 %0, %1, %2" : "=v"(r) : "v"(a), "v"(b));
  return r;
}
// async global->LDS, 16B per lane
__device__ __forceinline__ void gl16(const unsigned short* g, unsigned short* l){
  __builtin_amdgcn_global_load_lds(
      (const __attribute__((address_space(1))) u32*)(g),
      (__attribute__((address_space(3))) u32*)(l), 16, 0, 0);
}

// ---------------- conversions ----------------
__global__ void k_f2bf4(const float* __restrict__ x, unsigned short* __restrict__ y, int n4){
  int i=blockIdx.x*256+threadIdx.x; if(i>=n4) return;
  float4 v=((const float4*)x)[i];
  ushort4 r; r.x=f2bf(v.x); r.y=f2bf(v.y); r.z=f2bf(v.z); r.w=f2bf(v.w);
  ((ushort4*)y)[i]=r;
}
// W[K][N] f32 -> Wt[N][K] bf16
__global__ void k_wconv_t(const float* __restrict__ W, unsigned short* __restrict__ Wt,
                          int K, int N){
  int idx=blockIdx.x*256+threadIdx.x; if(idx>=K*N) return;
  int k=idx/N, n=idx%N;
  Wt[(size_t)n*K+k]=f2bf(W[idx]);
}

// ---------------- MFMA bf16 GEMM: 128x128 tile, BK=32, XCD swizzle -----------
// ASRC 0: A bf16 row-major (global_load_lds staging)
// ASRC 3: A bf16 head-major [bb][8][NPAD][64] (global_load_lds staging)
template<int MODE, int ASRC>
__global__ __launch_bounds__(256) void k_mfma_gemm(
    const void* __restrict__ Ap, const unsigned short* __restrict__ Bt,
    int M, int N, int K,
    const float* __restrict__ bias,
    void* __restrict__ o0, void* __restrict__ o1, void* __restrict__ o2)
{
  __shared__ __align__(16) unsigned short Sh[128*64];   // As=Sh[0..4095], Bs=Sh[4096..]
  int t=threadIdx.x;
  int bx=blockIdx.x, by=blockIdx.y;
  { // bijective XCD swizzle (grid size divisible by 8)
    int gx=gridDim.x; int wg=by*gx+bx; int nwg=gx*gridDim.y;
    int cpx=nwg>>3; int x2=(wg&7)*cpx+(wg>>3);
    by=x2/gx; bx=x2-by*gx;
  }
  int row0=by*128, col0=bx*128;
  int lane=t&63, w=t>>6, wr=w>>1, wc=w&1, lr=lane&15, kg=lane>>4;
  f32x4 acc[4][4];
  #pragma unroll
  for(int m=0;m<4;m++)
    #pragma unroll
    for(int n=0;n<4;n++) acc[m][n]=(f32x4){0.f,0.f,0.f,0.f};

  for(int k0=0;k0<K;k0+=32){
    __syncthreads();   // previous tile fully consumed
    #pragma unroll
    for(int i=0;i<2;i++){
      int flat=i*256+t, r=flat>>2, k8=flat&3;
      int kofs=k0+k8*8;
      const unsigned short* asrc;
      if constexpr(ASRC==0){
        asrc=(const unsigned short*)Ap+(size_t)(row0+r)*K+kofs;
      } else {
        int rr2=row0+r; int bb=rr2>>14, ri=rr2&16383;
        int head=kofs>>6, dd=kofs&63;
        asrc=(const unsigned short*)Ap + (((size_t)bb*NH+head)*NPAD+ri)*HD + dd;
      }
      gl16(asrc, Sh+(size_t)flat*8);
      gl16(Bt+(size_t)(col0+r)*K+kofs, Sh+4096+(size_t)flat*8);
    }
    __syncthreads();   // data ready (vmcnt/lgkm drained before barrier)
    short8v af[4], bf[4];
    #pragma unroll
    for(int m=0;m<4;m++) af[m]=*(const short8v*)(Sh+(wr*64+m*16+lr)*32 + kg*8);
    #pragma unroll
    for(int n=0;n<4;n++) bf[n]=*(const short8v*)(Sh+4096+(wc*64+n*16+lr)*32 + kg*8);
    #pragma unroll
    for(int m=0;m<4;m++)
      #pragma unroll
      for(int n=0;n<4;n++)
        acc[m][n]=__builtin_amdgcn_mfma_f32_16x16x32_bf16(af[m],bf[n],acc[m][n],0,0,0);
  }
  // ---- epilogue ----
  if constexpr(MODE==1){
    // coalesced q/k/v store via LDS restage (2 passes of 64 rows x 128 cols bf16)
    #pragma unroll
    for(int p=0;p<2;p++){
      __syncthreads();
      #pragma unroll
      for(int mm=0;mm<2;mm++){
        int m=2*p+mm;
        #pragma unroll
        for(int n=0;n<4;n++){
          int cc=wc*64+n*16+lr;
          int c=col0+cc;
          float sc=((c>>9)==0)?0.125f:1.f;
          #pragma unroll
          for(int j=0;j<4;j++){
            int lrow=wr*32+mm*16+kg*4+j;
            Sh[lrow*128+cc]=f2bf(acc[m][n][j]*sc);
          }
        }
      }
      __syncthreads();
      #pragma unroll
      for(int i=0;i<4;i++){
        int p2=i*256+t;
        int r2=p2>>4, ck=p2&15;
        int grow=row0+(r2>>5)*64+(2*p+((r2>>4)&1))*16+(r2&15);
        int bb=grow>>14, rr=grow&16383;
        int c=col0+ck*8;
        int which=c>>9, hcol=c&511, head=hcol>>6, dd=hcol&63;
        unsigned short* dst=(which==0)?(unsigned short*)o0:
                            (which==1)?(unsigned short*)o1:(unsigned short*)o2;
        *(short8v*)(dst + (((size_t)bb*NH+head)*NPAD+rr)*HD+dd) =
            *(const short8v*)(Sh + r2*128 + ck*8);
      }
    }
  } else {
    #pragma unroll
    for(int m=0;m<4;m++){
      int rbase=row0 + wr*64 + m*16 + kg*4;
      #pragma unroll
      for(int j=0;j<4;j++){
        int r=rbase+j;
        #pragma unroll
        for(int n=0;n<4;n++){
          int c=col0 + wc*64 + n*16 + lr;
          float val=acc[m][n][j];
          if(MODE==0){
            float* h=(float*)o0;
            int bb=(r>=16000)?1:0, ii=r-bb*16000;
            float vv=fmaxf(val+bias[c],0.f);
            h[((size_t)bb*NTOK + 1 + ii)*DM + c]=vv;
            if(ii<129) h[((size_t)bb*NTOK + 16001 + ii)*DM + c]=vv;
          } else {
            float* h=(float*)o0;
            int bb=r>>14, rr=r&16383;
            if(rr>=PADF)
              h[((size_t)bb*NTOK + (rr-PADF))*DM + c]+=val+bias[c];
          }
        }
      }
    }
  }
}

__global__ void k_cls(const float* __restrict__ cls, float* __restrict__ h){
  int t=blockIdx.x*256+threadIdx.x;
  if(t<2*DM) h[(size_t)(t>>9)*NTOK*DM + (t&511)]=cls[t&511];
}

// ---------------- layernorm + front zero-pad -> bf16 ----------------
__global__ __launch_bounds__(256) void k_lnpad(
    const float* __restrict__ h, const float* __restrict__ g,
    const float* __restrict__ bta, unsigned short* __restrict__ xln)
{
  int r=blockIdx.x;
  int bb=r>>14, i=r&16383;
  int t=threadIdx.x;
  unsigned short* dst=xln+(size_t)r*DM;
  if(i<PADF){ dst[t]=0; dst[t+256]=0; return; }
  const float* src=h+((size_t)bb*NTOK + (i-PADF))*DM;
  float x0=src[t], x1=src[t+256];
  __shared__ float s4[4];
  float mu=block_sum256(x0+x1,s4)*(1.f/512.f);
  float d0=x0-mu, d1=x1-mu;
  float var=block_sum256(d0*d0+d1*d1,s4)*(1.f/512.f);
  float rst=rsqrtf(var+1e-5f);
  dst[t]    =f2bf(d0*rst*g[t]    +bta[t]);
  dst[t+256]=f2bf(d1*rst*g[t+256]+bta[t+256]);
}

// ---------------- landmark means, q and k in one launch ----------------
__global__ void k_lmean2(const unsigned short* __restrict__ qsrc,
                         const unsigned short* __restrict__ ksrc,
                         float* __restrict__ qlf, unsigned short* __restrict__ qlb_,
                         float* __restrict__ klf, unsigned short* __restrict__ klb_){
  int gid=blockIdx.x;
  const unsigned short* src; float* dstf; unsigned short* dstb;
  if(gid<4096){ src=qsrc; dstf=qlf; dstb=qlb_; }
  else        { src=ksrc; dstf=klf; dstb=klb_; gid-=4096; }
  int bh=gid>>8, s=gid&255, d=threadIdx.x;  // 64 threads
  const unsigned short* p=src + (((size_t)bh*NPAD)+s*SEG)*HD + d;
  float acc=0.f;
  #pragma unroll
  for(int l=0;l<SEG;l++) acc+=bf2f(p[(size_t)l*HD]);
  float m=acc*(1.f/64.f);
  dstf[((size_t)bh*LM+s)*HD+d]=m;
  dstb[((size_t)bh*LM+s)*HD+d]=f2bf(m);
}

// ---------------- v bf16 head-major -> vt bf16 [bh][64][NPAD] ----------------
__global__ __launch_bounds__(256) void k_vtrans(
    const unsigned short* __restrict__ v, unsigned short* __restrict__ vt)
{
  __shared__ unsigned short tile[64][72];
  int kt=blockIdx.x, bh=blockIdx.y;
  int t=threadIdx.x;
  int r=t>>2, sgq=t&3;
  const short8v* src=(const short8v*)(v + ((size_t)bh*NPAD + kt*64 + r)*HD + sgq*16);
  *(short8v*)(&tile[r][sgq*16])  =src[0];
  *(short8v*)(&tile[r][sgq*16+8])=src[1];
  __syncthreads();
  int d=t>>2;
  union{unsigned short u[16]; short8v v8[2];} pk;
  #pragma unroll
  for(int i=0;i<16;i++) pk.u[i]=tile[sgq*16+i][d];
  short8v* dst=(short8v*)(vt + ((size_t)bh*HD + d)*NPAD + kt*64 + sgq*16);
  dst[0]=pk.v8[0]; dst[1]=pk.v8[1];
}

// ---------------- attn2 = softmax(ql @ kl^T) f32 + fused hi/lo split --------
__global__ __launch_bounds__(256) void k_attn2(
    const float* __restrict__ ql, const float* __restrict__ kl,
    float* __restrict__ attn2,
    unsigned short* __restrict__ a2h, unsigned short* __restrict__ a2l)
{
  __shared__ float qrow[64]; __shared__ float s4[4];
  int bh=blockIdx.x>>8, i=blockIdx.x&255, j=threadIdx.x;
  if(j<64) qrow[j]=ql[((size_t)bh*LM+i)*HD+j];
  __syncthreads();
  const float* kp=kl+((size_t)bh*LM+j)*HD;
  float l=0.f;
  #pragma unroll
  for(int d=0;d<64;d++) l+=qrow[d]*kp[d];
  float m=block_max256(l,s4);
  float e=__expf(l-m);
  float s=block_sum256(e,s4);
  float pv=e/s;
  size_t o=((size_t)bh*LM+i)*LM+j;
  attn2[o]=pv;
  unsigned short hh=f2bf(pv);
  a2h[o]=hh; a2l[o]=f2bf(pv-bf2f(hh));
}

// ---------------- pinv helpers (rowsum of softmax == 1, skip it) ------------
__global__ void k_colsum(const float* __restrict__ x, float* __restrict__ cs){
  int bh=blockIdx.x, j=threadIdx.x;
  const float* p=x+(size_t)bh*65536;
  float s=0.f;
  for(int i=0;i<256;i++) s+=p[(size_t)i*256+j];
  cs[bh*256+j]=s;
}
__global__ void k_pinvscale(const float* __restrict__ cs, float* __restrict__ scale){
  __shared__ float s4[4];
  float mc=-1e30f;
  for(int i=threadIdx.x;i<4096;i+=256) mc=fmaxf(mc,cs[i]);
  mc=block_max256(mc,s4);
  if(threadIdx.x==0) scale[0]=1.f/mc;
}
__global__ void k_zinit_hl(const float* __restrict__ x, const float* __restrict__ scale,
    unsigned short* __restrict__ zh, unsigned short* __restrict__ zl,
    unsigned short* __restrict__ zth, unsigned short* __restrict__ ztl){
  int bh=blockIdx.x>>8, i=blockIdx.x&255, j=threadIdx.x;
  float s=scale[0];
  size_t base=(size_t)bh*65536;
  float vn=x[base+(size_t)j*256+i]*s;   // z0[i][j] = X^T * s
  float vt=x[base+(size_t)i*256+j]*s;   // z0^T[i][j]
  size_t o=base+(size_t)i*256+j;
  unsigned short h=f2bf(vn); zh[o]=h; zl[o]=f2bf(vn-bf2f(h));
  h=f2bf(vt); zth[o]=h; ztl[o]=f2bf(vt-bf2f(h));
}

// ---------------- hi/lo split bf16 MFMA batched GEMM (pinv chain) -----------
// Tile 32(M)x64(N), BK=64, 4 k-steps, grid 512 blocks (2/CU)
// MODE 0: C=A@B (emit normal+trans)    MODE 1: C=15I-7X+acc (trans only)
// MODE 2: C=13I-acc (trans only)       MODE 3: C=0.25*acc (normal+trans)
// MODE 4: C=acc (trans only, hi only; Ndim=64)
// PREC 0: single bf16 product; PREC 1: hi/lo 3-product (f32-equivalent)
template<int MODE, int PREC>
__global__ __launch_bounds__(256) void k_bmm3(
    const unsigned short* __restrict__ Ah, const unsigned short* __restrict__ Al,
    const unsigned short* __restrict__ Bth, const unsigned short* __restrict__ Btl,
    const unsigned short* __restrict__ Xh, const unsigned short* __restrict__ Xl,
    unsigned short* __restrict__ Cnh, unsigned short* __restrict__ Cnl,
    unsigned short* __restrict__ Cth, unsigned short* __restrict__ Ctl,
    int Ndim)
{
  __shared__ unsigned short AsH[32*72], BsH[64*72];
  __shared__ unsigned short AsL[PREC?32*72:8], BsL[PREC?64*72:8];
  int bh=blockIdx.z;
  int n0=blockIdx.x*64, m0=blockIdx.y*32;
  int t=threadIdx.x, lane=t&63, w=t>>6;
  int c=lane&15, g=lane>>4;
  int wr=(w>>1)*16, wc=(w&1)*32;
  f32x4 acc[2];
  acc[0]=(f32x4){0.f,0.f,0.f,0.f};
  acc[1]=(f32x4){0.f,0.f,0.f,0.f};
  size_t Abase=(size_t)bh*65536;
  size_t Bbase=(size_t)bh*(size_t)Ndim*256;
  int r=t>>3, k8=(t&7)*8;
  const unsigned short* ApH =Ah +Abase+(size_t)(m0+r)*256+k8;
  const unsigned short* BpH0=Bth+Bbase+(size_t)(n0+r)*256+k8;
  const unsigned short* BpH1=Bth+Bbase+(size_t)(n0+32+r)*256+k8;
  const unsigned short* ApL =Al +Abase+(size_t)(m0+r)*256+k8;
  const unsigned short* BpL0=Btl+Bbase+(size_t)(n0+r)*256+k8;
  const unsigned short* BpL1=Btl+Bbase+(size_t)(n0+32+r)*256+k8;
  short8v rah,rbh0,rbh1, ral,rbl0,rbl1;
  rah =*(const short8v*)(ApH);
  rbh0=*(const short8v*)(BpH0);
  rbh1=*(const short8v*)(BpH1);
  if constexpr(PREC==1){
    ral =*(const short8v*)(ApL);
    rbl0=*(const short8v*)(BpL0);
    rbl1=*(const short8v*)(BpL1);
  }
  int k0=0;
  for(;;){
    __syncthreads();
    *(short8v*)(AsH + r*72 + k8)=rah;
    *(short8v*)(BsH + r*72 + k8)=rbh0;
    *(short8v*)(BsH + (r+32)*72 + k8)=rbh1;
    if constexpr(PREC==1){
      *(short8v*)(AsL + r*72 + k8)=ral;
      *(short8v*)(BsL + r*72 + k8)=rbl0;
      *(short8v*)(BsL + (r+32)*72 + k8)=rbl1;
    }
    __syncthreads();
    int kn=k0+64;
    if(kn<256){
      rah =*(const short8v*)(ApH +kn);
      rbh0=*(const short8v*)(BpH0+kn);
      rbh1=*(const short8v*)(BpH1+kn);
      if constexpr(PREC==1){
        ral =*(const short8v*)(ApL +kn);
        rbl0=*(const short8v*)(BpL0+kn);
        rbl1=*(const short8v*)(BpL1+kn);
      }
    }
    #pragma unroll
    for(int ks=0;ks<2;ks++){
      short8v af=*(const short8v*)(AsH+(wr+c)*72 + ks*32 + g*8);
      short8v alf;
      if constexpr(PREC==1) alf=*(const short8v*)(AsL+(wr+c)*72 + ks*32 + g*8);
      #pragma unroll
      for(int nt=0;nt<2;nt++){
        short8v bf=*(const short8v*)(BsH+(wc+nt*16+c)*72 + ks*32 + g*8);
        acc[nt]=__builtin_amdgcn_mfma_f32_16x16x32_bf16(af,bf,acc[nt],0,0,0);
        if constexpr(PREC==1){
          short8v blf=*(const short8v*)(BsL+(wc+nt*16+c)*72 + ks*32 + g*8);
          acc[nt]=__builtin_amdgcn_mfma_f32_16x16x32_bf16(af,blf,acc[nt],0,0,0);
          acc[nt]=__builtin_amdgcn_mfma_f32_16x16x32_bf16(alf,bf,acc[nt],0,0,0);
        }
      }
    }
    if(kn>=256) break;
    k0=kn;
  }
  int rb=m0+wr+g*4;
  #pragma unroll
  for(int nt=0;nt<2;nt++){
    int cc=n0+wc+nt*16+c;
    float vv[4];
    #pragma unroll
    for(int j=0;j<4;j++){
      float a=acc[nt][j];
      int rr=rb+j;
      if(MODE==1){
        float xv=bf2f(Xh[Abase+(size_t)rr*256+cc])+bf2f(Xl[Abase+(size_t)rr*256+cc]);
        a=(rr==cc?15.f:0.f)-7.f*xv+a;
      } else if(MODE==2){
        a=(rr==cc?13.f:0.f)-a;
      } else if(MODE==3){
        a*=0.25f;
      }
      vv[j]=a;
    }
    if(MODE==0||MODE==3){
      #pragma unroll
      for(int j=0;j<4;j++){
        unsigned short hh=f2bf(vv[j]);
        Cnh[Abase+(size_t)(rb+j)*256+cc]=hh;
        Cnl[Abase+(size_t)(rb+j)*256+cc]=f2bf(vv[j]-bf2f(hh));
      }
    }
    {
      ushort4 hv, lv;
      hv.x=f2bf(vv[0]); hv.y=f2bf(vv[1]); hv.z=f2bf(vv[2]); hv.w=f2bf(vv[3]);
      lv.x=f2bf(vv[0]-bf2f(hv.x)); lv.y=f2bf(vv[1]-bf2f(hv.y));
      lv.z=f2bf(vv[2]-bf2f(hv.z)); lv.w=f2bf(vv[3]-bf2f(hv.w));
      size_t co=((size_t)bh*Ndim+cc)*256+rb;
      *(ushort4*)(Cth+co)=hv;
      if(MODE!=4) *(ushort4*)(Ctl+co)=lv;
    }
  }
}

// ---------------- attn3@v : MFMA flash, split-K 16 chunks x 2 row-halves -----
__global__ __launch_bounds__(512) void k_attn3m(
    const unsigned short* __restrict__ qlb,
    const unsigned short* __restrict__ kb,
    const unsigned short* __restrict__ vtb,
    float* __restrict__ pacc, float* __restrict__ pms)
{
  __shared__ unsigned short Ks[64*72];
  __shared__ unsigned short Vs[64*72];
  int ck=blockIdx.x, rh=blockIdx.y, bh=blockIdx.z;
  int t=threadIdx.x, lane=t&63, w=t>>6;
  int c=lane&15, g=lane>>4;
  int qrow0=rh*128 + w*16;          // this wave's 16 q-rows: qrow0 + c
  short8v Qf[2];
  #pragma unroll
  for(int kw=0;kw<2;kw++)
    Qf[kw]=*(const short8v*)(qlb + ((size_t)bh*LM + qrow0 + c)*HD + kw*32 + g*8);
  f32x4 accO[4];
  float mrun=-3e38f, srun=0.f;
  #pragma unroll
  for(int d=0;d<4;d++) accO[d]=(f32x4){0.f,0.f,0.f,0.f};
  int sr=t>>3, sgk=t&7;
  for(int sc=0;sc<16;++sc){
    int key0=ck*1024 + sc*64;
    __syncthreads();
    *(short8v*)(Ks + sr*72 + sgk*8) =
      *(const short8v*)(kb + ((size_t)bh*NPAD + key0 + sr)*HD + sgk*8);
    *(short8v*)(Vs + sr*72 + sgk*8) =
      *(const short8v*)(vtb + ((size_t)bh*HD + sr)*NPAD + key0 + sgk*8);
    __syncthreads();
    f32x4 s[4];
    #pragma unroll
    for(int mt=0;mt<4;mt++){
      short8v a0=*(const short8v*)(Ks + (mt*16+c)*72 + g*8);
      short8v a1=*(const short8v*)(Ks + (mt*16+c)*72 + 32 + g*8);
      f32x4 z=(f32x4){0.f,0.f,0.f,0.f};
      z=__builtin_amdgcn_mfma_f32_16x16x32_bf16(a0,Qf[0],z,0,0,0);
      z=__builtin_amdgcn_mfma_f32_16x16x32_bf16(a1,Qf[1],z,0,0,0);
      s[mt]=z;
    }
    unsigned U[4][2];
    {
      float cm=-3e38f;
      #pragma unroll
      for(int mt=0;mt<4;mt++)
        #pragma unroll
        for(int j=0;j<4;j++) cm=fmaxf(cm,s[mt][j]);
      cm=fmaxf(cm,__shfl_xor(cm,16));
      cm=fmaxf(cm,__shfl_xor(cm,32));
      float mnew=fmaxf(mrun,cm);
      float f=__expf(mrun-mnew);
      mrun=mnew;
      float ps=0.f;
      #pragma unroll
      for(int mt=0;mt<4;mt++){
        float p0=__expf(s[mt][0]-mnew);
        float p1=__expf(s[mt][1]-mnew);
        float p2=__expf(s[mt][2]-mnew);
        float p3=__expf(s[mt][3]-mnew);
        ps+=p0+p1+p2+p3;
        U[mt][0]=cvtpk(p0,p1);
        U[mt][1]=cvtpk(p2,p3);
      }
      ps+=__shfl_xor(ps,16); ps+=__shfl_xor(ps,32);
      srun=srun*f+ps;
      #pragma unroll
      for(int d=0;d<4;d++){
        accO[d][0]*=f; accO[d][1]*=f; accO[d][2]*=f; accO[d][3]*=f;
      }
    }
    #pragma unroll
    for(int kw=0;kw<2;kw++){
      union{unsigned u[4]; short8v v;} pk;
      #pragma unroll
      for(int wd=0;wd<4;wd++){
        int sl=c+16*(((g&1)<<1)+(wd>>1));
        unsigned va=(unsigned)__shfl((int)U[kw*2  ][wd&1],sl);
        unsigned vb=(unsigned)__shfl((int)U[kw*2+1][wd&1],sl);
        pk.u[wd]=(lane>=32)?vb:va;
      }
      #pragma unroll
      for(int d=0;d<4;d++){
        short8v vf=*(const short8v*)(Vs + (d*16+c)*72 + kw*32 + g*8);
        accO[d]=__builtin_amdgcn_mfma_f32_16x16x32_bf16(vf,pk.v,accO[d],0,0,0);
      }
    }
  }
  size_t pb=((size_t)bh*16+ck)*LM;
  int q=qrow0+c;
  #pragma unroll
  for(int d=0;d<4;d++)
    *(f32x4*)(pacc + (pb+q)*HD + d*16 + g*4)=accO[d];
  if(g==0){ pms[(pb+q)*2]=mrun; pms[(pb+q)*2+1]=srun; }
}
__global__ __launch_bounds__(256) void k_attn3vc(
    const float* __restrict__ pacc, const float* __restrict__ pms,
    unsigned short* __restrict__ a3vth, unsigned short* __restrict__ a3vtl)
{
  int gid=blockIdx.x*4+(threadIdx.x>>6);
  int bh=gid>>8, row=gid&255, lane=threadIdx.x&63;
  float M=-3e38f;
  float ms[16], ss[16];
  #pragma unroll
  for(int c=0;c<16;c++){
    size_t pb=((size_t)bh*16+c)*LM+row;
    ms[c]=pms[pb*2]; ss[c]=pms[pb*2+1];
    M=fmaxf(M,ms[c]);
  }
  float S=0.f,a=0.f;
  #pragma unroll
  for(int c=0;c<16;c++){
    float f=__expf(ms[c]-M);
    S+=ss[c]*f;
    a+=pacc[(((size_t)bh*16+c)*LM+row)*HD+lane]*f;
  }
  float v=a/S;
  unsigned short hi=f2bf(v);
  a3vth[((size_t)bh*HD+lane)*LM+row]=hi;
  a3vtl[((size_t)bh*HD+lane)*LM+row]=f2bf(v-bf2f(hi));
}

// ---------------- attn1 @ W2 : MFMA, 256 landmarks one-shot; bf16 out --------
__global__ __launch_bounds__(512) void k_attn1m(
    const unsigned short* __restrict__ qb,
    const unsigned short* __restrict__ klb,
    const unsigned short* __restrict__ w2t,
    unsigned short* __restrict__ aohb)
{
  __shared__ unsigned short klS[256*72];
  __shared__ unsigned short w2S[64*264];
  int qt=blockIdx.x, bh=blockIdx.y;
  int t=threadIdx.x, lane=t&63, w=t>>6;
  int c=lane&15, g=lane>>4;
  {
    int r=t>>1, hf=t&1;
    const short8v* s=(const short8v*)(klb + ((size_t)bh*LM+r)*HD + hf*32);
    short8v* d=(short8v*)(klS + r*72 + hf*32);
    d[0]=s[0]; d[1]=s[1]; d[2]=s[2]; d[3]=s[3];
    int r2=t>>3, sg2=t&7;
    const short8v* s2=(const short8v*)(w2t + ((size_t)bh*HD+r2)*LM + sg2*32);
    short8v* d2=(short8v*)(w2S + r2*264 + sg2*32);
    d2[0]=s2[0]; d2[1]=s2[1]; d2[2]=s2[2]; d2[3]=s2[3];
  }
  __syncthreads();
  int q0=qt*256 + w*32;
  #pragma unroll
  for(int n=0;n<2;n++){
    const unsigned short* qrow=qb + ((size_t)bh*NPAD + q0 + n*16 + c)*HD;
    short8v qf0=*(const short8v*)(qrow + g*8);
    short8v qf1=*(const short8v*)(qrow + 32 + g*8);
    f32x4 s[16];
    #pragma unroll
    for(int mt=0;mt<16;mt++){
      short8v a0=*(const short8v*)(klS + (mt*16+c)*72 + g*8);
      short8v a1=*(const short8v*)(klS + (mt*16+c)*72 + 32 + g*8);
      f32x4 z=(f32x4){0.f,0.f,0.f,0.f};
      z=__builtin_amdgcn_mfma_f32_16x16x32_bf16(a0,qf0,z,0,0,0);
      z=__builtin_amdgcn_mfma_f32_16x16x32_bf16(a1,qf1,z,0,0,0);
      s[mt]=z;
    }
    float M=-3e38f;
    #pragma unroll
    for(int mt=0;mt<16;mt++)
      #pragma unroll
      for(int j=0;j<4;j++) M=fmaxf(M,s[mt][j]);
    M=fmaxf(M,__shfl_xor(M,16));
    M=fmaxf(M,__shfl_xor(M,32));
    float sum=0.f;
    unsigned U[16][2];
    #pragma unroll
    for(int mt=0;mt<16;mt++){
      float p0=__expf(s[mt][0]-M);
      float p1=__expf(s[mt][1]-M);
      float p2=__expf(s[mt][2]-M);
      float p3=__expf(s[mt][3]-M);
      sum+=p0+p1+p2+p3;
      U[mt][0]=cvtpk(p0,p1);
      U[mt][1]=cvtpk(p2,p3);
    }
    sum+=__shfl_xor(sum,16); sum+=__shfl_xor(sum,32);
    float inv=1.f/sum;
    f32x4 accO[4];
    #pragma unroll
    for(int d=0;d<4;d++) accO[d]=(f32x4){0.f,0.f,0.f,0.f};
    #pragma unroll
    for(int kw=0;kw<8;kw++){
      union{unsigned u[4]; short8v v;} pk;
      #pragma unroll
      for(int wd=0;wd<4;wd++){
        int sl=c+16*(((g&1)<<1)+(wd>>1));
        unsigned va=(unsigned)__shfl((int)U[kw*2  ][wd&1],sl);
        unsigned vb=(unsigned)__shfl((int)U[kw*2+1][wd&1],sl);
        pk.u[wd]=(lane>=32)?vb:va;
      }
      #pragma unroll
      for(int d=0;d<4;d++){
        short8v vf=*(const short8v*)(w2S + (d*16+c)*264 + kw*32 + g*8);
        accO[d]=__builtin_amdgcn_mfma_f32_16x16x32_bf16(vf,pk.v,accO[d],0,0,0);
      }
    }
    int q=q0+n*16+c;
    #pragma unroll
    for(int d=0;d<4;d++){
      f32x4 o=accO[d];
      uint2 pk2;
      pk2.x=cvtpk(o[0]*inv, o[1]*inv);
      pk2.y=cvtpk(o[2]*inv, o[3]*inv);
      *(uint2*)(aohb + ((size_t)bh*NPAD+q)*HD + d*16 + g*4)=pk2;
    }
  }
}

// ---------------- depthwise 33-tap conv from vt; aoh bf16 += -----------------
__global__ __launch_bounds__(256) void k_resconv2(
    const unsigned short* __restrict__ vt, const float* __restrict__ rw,
    unsigned short* __restrict__ aohb){
  int bx=blockIdx.x, bh=blockIdx.y;
  int t=threadIdx.x, d=t&63, g=t>>6;
  int i0=bx*32+g*8;
  int hh=bh&7;
  const unsigned short* vr=vt + ((size_t)bh*HD + d)*NPAD;
  float wv[40];
  int start=i0-16;
  if(start>=0 && start+40<=NPAD){
    #pragma unroll
    for(int b=0;b<5;b++){
      short8v v8=*(const short8v*)(vr+start+b*8);
      #pragma unroll
      for(int j=0;j<8;j++) wv[b*8+j]=bf2f((unsigned short)v8[j]);
    }
  } else {
    #pragma unroll
    for(int t2=0;t2<40;t2++){
      int src=start+t2;
      wv[t2]=(src>=0&&src<NPAD)?bf2f(vr[src]):0.f;
    }
  }
  const float* wt=rw+hh*33;
  #pragma unroll
  for(int p=0;p<8;p++){
    float a=0.f;
    #pragma unroll
    for(int tk=0;tk<33;tk++) a+=wv[p+tk]*wt[tk];
    size_t o=((size_t)bh*NPAD+i0+p)*HD+d;
    aohb[o]=f2bf(bf2f(aohb[o])+a);
  }
}

// ---------------- PPEG weight prep: combined 7x7 tap table (bf16) -----------
__global__ void k_wprep(const float* __restrict__ w7, const float* __restrict__ b7,
                        const float* __restrict__ w5, const float* __restrict__ b5,
                        const float* __restrict__ w3, const float* __restrict__ b3,
                        unsigned short* __restrict__ wcat){
  int t=blockIdx.x*256+threadIdx.x;
  if(t>=50*512) return;
  int r=t>>9, c=t&511;
  float v;
  if(r<49){
    int ky=r/7, kx=r%7;
    v=w7[(size_t)c*49+r];
    if(ky>=1&&ky<=5&&kx>=1&&kx<=5) v+=w5[(size_t)c*25+(ky-1)*5+(kx-1)];
    if(ky>=2&&ky<=4&&kx>=2&&kx<=4) v+=w3[(size_t)c*9+(ky-2)*3+(kx-2)];
  } else {
    v=b7[c]+b5[c]+b3[c];
  }
  wcat[t]=f2bf(v);
}

// ---------------- PPEG: 8x8 tile x 32ch, f32 patch, sliding row window ------
__global__ __launch_bounds__(256,4) void k_ppeg4(
    const float* __restrict__ src, const unsigned short* __restrict__ wcat,
    float* __restrict__ dst)
{
  __shared__ float patch[196][32];   // 14x14 halo
  __shared__ float wsf[50][32];
  int bx=blockIdx.x;
  int cz=blockIdx.y, bb=blockIdx.z;
  int t=threadIdx.x, c=t&31, g=t>>5;   // 32ch x 8 groups
  int ty0=(bx>>4)*8, tx0=(bx&15)*8;
  const float* base=src+((size_t)bb*NTOK+1)*DM + cz*32 + c;
  #pragma unroll
  for(int i=0;i<25;i++){
    int p=g+8*i;
    if(p<196){
      int py=p/14, px=p%14;
      int yy=ty0-3+py, xx=tx0-3+px;
      float v=0.f;
      if(yy>=0&&yy<127&&xx>=0&&xx<127) v=base[(size_t)(yy*127+xx)*DM];
      patch[p][c]=v;
    }
  }
  #pragma unroll
  for(int i=0;i<7;i++){
    int r=g+8*i; if(r<50) wsf[r][c]=bf2f(wcat[(size_t)r*DM + cz*32 + c]);
  }
  __syncthreads();
  float acc[8];
  float bias=wsf[49][c];
  #pragma unroll
  for(int j=0;j<8;j++) acc[j]=patch[(g+3)*14+(j+3)][c]+bias;  // exact identity
  #pragma unroll
  for(int ky=0;ky<7;ky++){
    float win[14];
    #pragma unroll
    for(int x=0;x<14;x++) win[x]=patch[(g+ky)*14+x][c];
    #pragma unroll
    for(int kx=0;kx<7;kx++){
      float wv=wsf[ky*7+kx][c];
      #pragma unroll
      for(int j=0;j<8;j++) acc[j]+=win[j+kx]*wv;
    }
  }
  int y=ty0+g;
  if(y<127){
    #pragma unroll
    for(int j=0;j<8;j++){
      int x=tx0+j;
      if(x<127)
        dst[((size_t)bb*NTOK+1+(size_t)(y*127+x))*DM + cz*32 + c]=acc[j];
    }
  }
}

// copy cls row h -> dst
__global__ void k_cpcls(const float* __restrict__ h, float* __restrict__ dst){
  int t=blockIdx.x*256+threadIdx.x;
  if(t<2*DM) dst[(size_t)(t>>9)*NTOK*DM + (t&511)]=h[(size_t)(t>>9)*NTOK*DM + (t&511)];
}

// ---------------- final: LN(h[:,0]) @ fc2 + b ----------------
__global__ __launch_bounds__(256) void k_final(
    const float* __restrict__ h, const float* __restrict__ g, const float* __restrict__ bta,
    const float* __restrict__ w, const float* __restrict__ fb, float* __restrict__ out)
{
  int bb=blockIdx.x, t=threadIdx.x;
  const float* src=h+(size_t)bb*NTOK*DM;
  float x0=src[t], x1=src[t+256];
  __shared__ float s4[4];
  float mu=block_sum256(x0+x1,s4)*(1.f/512.f);
  float d0=x0-mu, d1=x1-mu;
  float var=block_sum256(d0*d0+d1*d1,s4)*(1.f/512.f);
  float rst=rsqrtf(var+1e-5f);
  float y0=d0*rst*g[t]+bta[t], y1=d1*rst*g[t+256]+bta[t+256];
  float dot=block_sum256(y0*w[t]+y1*w[t+256],s4);
  if(t==0) out[bb]=dot+fb[0];
}

// =======================================================================
extern "C" void kernel_launch(void* const* d_in, const int* in_sizes, int n_in,
                              void* d_out, int out_size, void* d_ws, size_t ws_size,
                              hipStream_t stream){
  (void)in_sizes; (void)n_in; (void)out_size; (void)ws_size;
  const float* features=(const float*)d_in[0];
  const float* fc1_w  =(const float*)d_in[1];
  const float* fc1_b  =(const float*)d_in[2];
  const float* cls_tok=(const float*)d_in[3];
  const float* fc2_w  =(const float*)d_in[24];
  const float* fc2_b  =(const float*)d_in[25];
  float* out=(float*)d_out;

  char* wp=(char*)d_ws;
  auto allocB=[&](size_t bytes)->char*{
    char* p=wp; wp+=((bytes+255)/256)*256; return p;
  };
  float* h    =(float*)allocB((size_t)NB*NTOK*DM*4);
  float* h2   =(float*)allocB((size_t)NB*NTOK*DM*4);
  unsigned short* vb  =(unsigned short*)allocB((size_t)NB*NPAD*DM*2);
  unsigned short* xlnb=(unsigned short*)allocB((size_t)NB*NPAD*DM*2);
  unsigned short* qb  =(unsigned short*)allocB((size_t)NB*NPAD*DM*2);
  unsigned short* kb  =(unsigned short*)allocB((size_t)NB*NPAD*DM*2);
  unsigned short* vtb =(unsigned short*)allocB((size_t)NB*NPAD*DM*2);
  unsigned short* aohb=(unsigned short*)allocB((size_t)NB*NPAD*DM*2);
  unsigned short* wtf=(unsigned short*)allocB((size_t)512*1024*2);
  unsigned short* wtq=(unsigned short*)allocB((size_t)1536*512*2);
  unsigned short* wtp=(unsigned short*)allocB((size_t)512*512*2);
  float* ql =(float*)allocB((size_t)16*LM*HD*4);
  float* kl =(float*)allocB((size_t)16*LM*HD*4);
  unsigned short* qlb=(unsigned short*)allocB((size_t)16*LM*HD*2);
  unsigned short* klb=(unsigned short*)allocB((size_t)16*LM*HD*2);
  float* attn2=(float*)allocB((size_t)16*LM*LM*4);
  unsigned short* a2h=(unsigned short*)allocB((size_t)16*LM*LM*2);
  unsigned short* a2l=(unsigned short*)allocB((size_t)16*LM*LM*2);
  unsigned short* zb[8];
  for(int i=0;i<8;i++) zb[i]=(unsigned short*)allocB((size_t)16*LM*LM*2);
  unsigned short* Abh=(unsigned short*)allocB((size_t)16*LM*LM*2);
  unsigned short* Abl=(unsigned short*)allocB((size_t)16*LM*LM*2);
  unsigned short* Abth=(unsigned short*)allocB((size_t)16*LM*LM*2);
  unsigned short* Abtl=(unsigned short*)allocB((size_t)16*LM*LM*2);
  unsigned short* Ubth=(unsigned short*)allocB((size_t)16*LM*LM*2);
  unsigned short* Ubtl=(unsigned short*)allocB((size_t)16*LM*LM*2);
  unsigned short* Tbth=(unsigned short*)allocB((size_t)16*LM*LM*2);
  unsigned short* Tbtl=(unsigned short*)allocB((size_t)16*LM*LM*2);
  unsigned short* a3vth=(unsigned short*)allocB((size_t)16*HD*LM*2);
  unsigned short* a3vtl=(unsigned short*)allocB((size_t)16*HD*LM*2);
  unsigned short* w2t=(unsigned short*)allocB((size_t)16*HD*LM*2);
  float* pacc=(float*)allocB((size_t)16*16*LM*HD*4);
  float* pms =(float*)allocB((size_t)16*16*LM*2*4);
  float* cs  =(float*)allocB(4096*4);
  float* scl =(float*)allocB(64*4);

  auto nystrom=[&](float* hbuf, const float* ng, const float* nbias, const float* qkvw,
                   const float* outw, const float* outb, const float* resw){
    k_lnpad<<<NB*NPAD,256,0,stream>>>(hbuf, ng, nbias, xlnb);
    k_wconv_t<<<(512*1536+255)/256,256,0,stream>>>(qkvw, wtq, 512, 1536);
    k_mfma_gemm<1,0><<<dim3(12,256),256,0,stream>>>(xlnb, wtq, 32768,1536,512,
                                                    nullptr, qb, kb, vb);
    k_lmean2<<<8192,64,0,stream>>>(qb, kb, ql, qlb, kl, klb);
    k_vtrans<<<dim3(256,16),256,0,stream>>>(vb, vtb);
    k_attn2<<<4096,256,0,stream>>>(ql, kl, attn2, a2h, a2l);
    k_colsum<<<16,256,0,stream>>>(attn2, cs);
    k_pinvscale<<<1,256,0,stream>>>(cs, scl);
    k_zinit_hl<<<4096,256,0,stream>>>(attn2, scl, zb[0],zb[1],zb[2],zb[3]);
    unsigned short *zch=zb[0],*zcl=zb[1],*zcth=zb[2],*zctl=zb[3];
    unsigned short *znh=zb[4],*znl=zb[5],*znth=zb[6],*zntl=zb[7];
    for(int it=0;it<6;it++){
      if(it<5){
        k_bmm3<0,0><<<dim3(4,8,16),256,0,stream>>>(a2h,a2l, zcth,zctl, nullptr,nullptr,
                                                   Abh,Abl, Abth,Abtl, 256);
        k_bmm3<1,0><<<dim3(4,8,16),256,0,stream>>>(Abh,Abl, Abth,Abtl, Abh,Abl,
                                                   nullptr,nullptr, Ubth,Ubtl, 256);
        k_bmm3<2,0><<<dim3(4,8,16),256,0,stream>>>(Abh,Abl, Ubth,Ubtl, nullptr,nullptr,
                                                   nullptr,nullptr, Tbth,Tbtl, 256);
        k_bmm3<3,0><<<dim3(4,8,16),256,0,stream>>>(zch,zcl, Tbth,Tbtl, nullptr,nullptr,
                                                   znh,znl, znth,zntl, 256);
      } else {
        k_bmm3<0,1><<<dim3(4,8,16),256,0,stream>>>(a2h,a2l, zcth,zctl, nullptr,nullptr,
                                                   Abh,Abl, Abth,Abtl, 256);
        k_bmm3<1,1><<<dim3(4,8,16),256,0,stream>>>(Abh,Abl, Abth,Abtl, Abh,Abl,
                                                   nullptr,nullptr, Ubth,Ubtl, 256);
        k_bmm3<2,1><<<dim3(4,8,16),256,0,stream>>>(Abh,Abl, Ubth,Ubtl, nullptr,nullptr,
                                                   nullptr,nullptr, Tbth,Tbtl, 256);
        k_bmm3<3,1><<<dim3(4,8,16),256,0,stream>>>(zch,zcl, Tbth,Tbtl, nullptr,nullptr,
                                                   znh,znl, znth,zntl, 256);
      }
      unsigned short* tp;
      tp=zch; zch=znh; znh=tp;  tp=zcl; zcl=znl; znl=tp;
      tp=zcth; zcth=znth; znth=tp;  tp=zctl; zctl=zntl; zntl=tp;
    }
    k_attn3m<<<dim3(16,2,16),512,0,stream>>>(qlb, kb, vtb, pacc, pms);
    k_attn3vc<<<1024,256,0,stream>>>(pacc, pms, a3vth, a3vtl);
    k_bmm3<4,1><<<dim3(1,8,16),256,0,stream>>>(zch,zcl, a3vth,a3vtl, nullptr,nullptr,
                                               nullptr,nullptr, w2t,nullptr, 64);
    k_attn1m<<<dim3(64,16),512,0,stream>>>(qb, klb, w2t, aohb);
    k_resconv2<<<dim3(512,16),256,0,stream>>>(vtb, resw, aohb);
    k_wconv_t<<<(512*512+255)/256,256,0,stream>>>(outw, wtp, 512, 512);
    k_mfma_gemm<2,3><<<dim3(4,256),256,0,stream>>>(aohb, wtp, 32768,512,512,
                                                   outb, hbuf, nullptr, nullptr);
  };

  // fc1: features -> bf16 (h2 overlay), then MFMA GEMM via global_load_lds
  unsigned short* featbf=(unsigned short*)h2;   // dead before PPEG
  k_f2bf4<<<32000,256,0,stream>>>(features, featbf, 32000*1024/4);
  k_wconv_t<<<(1024*512+255)/256,256,0,stream>>>(fc1_w, wtf, 1024, 512);
  k_mfma_gemm<0,0><<<dim3(4,250),256,0,stream>>>(featbf, wtf, 32000,512,1024,
                                                 fc1_b, h, nullptr, nullptr);
  k_cls<<<4,256,0,stream>>>(cls_tok, h);

  // layer 1 attention (on h)
  nystrom(h, (const float*)d_in[4],(const float*)d_in[5],(const float*)d_in[6],
          (const float*)d_in[7],(const float*)d_in[8],(const float*)d_in[9]);

  // PPEG: combined-tap stencil h -> h2 (no copy-back; layer 2 runs on h2)
  {
    unsigned short* wcat=(unsigned short*)attn2;  // free at this point
    k_wprep<<<100,256,0,stream>>>(
        (const float*)d_in[10],(const float*)d_in[11],
        (const float*)d_in[12],(const float*)d_in[13],
        (const float*)d_in[14],(const float*)d_in[15], wcat);
    k_cpcls<<<4,256,0,stream>>>(h, h2);
    k_ppeg4<<<dim3(256,16,2),256,0,stream>>>(h, wcat, h2);
  }

  // layer 2 attention (on h2)
  nystrom(h2, (const float*)d_in[16],(const float*)d_in[17],(const float*)d_in[18],
          (const float*)d_in[19],(const float*)d_in[20],(const float*)d_in[21]);

  // final LN(h2[:,0]) @ fc2
  k_final<<<2,256,0,stream>>>(h2,(const float*)d_in[22],(const float*)d_in[23],
                              fc2_w, fc2_b, out);
}

// Round 20
// 1206.937 us; speedup vs baseline: 1.3161x; 1.0470x over previous
//
#include <hip/hip_runtime.h>
#include <math.h>

#define NTOK 16130   // 1 + 127*127
#define NPAD 16384
#define PADF 254
#define NB   2
#define DM   512
#define NH   8
#define HD   64
#define LM   256
#define SEG  64

typedef __attribute__((ext_vector_type(8))) short short8v;
typedef __attribute__((ext_vector_type(4))) float f32x4;
typedef unsigned int u32;

// ---------------- helpers ----------------
__device__ __forceinline__ float wred_max(float v){
  #pragma unroll
  for(int o=32;o;o>>=1) v=fmaxf(v,__shfl_xor(v,o));
  return v;
}
__device__ __forceinline__ float wred_sum(float v){
  #pragma unroll
  for(int o=32;o;o>>=1) v+=__shfl_xor(v,o);
  return v;
}
__device__ __forceinline__ float block_max256(float v, float* s4){
  v=wred_max(v);
  if((threadIdx.x&63)==0) s4[threadIdx.x>>6]=v;
  __syncthreads();
  v=fmaxf(fmaxf(s4[0],s4[1]),fmaxf(s4[2],s4[3]));
  __syncthreads();
  return v;
}
__device__ __forceinline__ float block_sum256(float v, float* s4){
  v=wred_sum(v);
  if((threadIdx.x&63)==0) s4[threadIdx.x>>6]=v;
  __syncthreads();
  v=s4[0]+s4[1]+s4[2]+s4[3];
  __syncthreads();
  return v;
}
__device__ __forceinline__ unsigned short f2bf(float f){
  unsigned u=__float_as_uint(f);
  u = u + 0x7FFFu + ((u>>16)&1u);
  return (unsigned short)(u>>16);
}
__device__ __forceinline__ float bf2f(unsigned short u){
  return __uint_as_float(((unsigned)u)<<16);
}
__device__ __forceinline__ unsigned cvtpk(float a, float b){
  unsigned r;
  asm("v_cvt_pk_bf16_f32 %0, %1, %2" : "=v"(r) : "v"(a), "v"(b));
  return r;
}
// async global->LDS, 16B per lane
__device__ __forceinline__ void gl16(const unsigned short* g, unsigned short* l){
  __builtin_amdgcn_global_load_lds(
      (const __attribute__((address_space(1))) u32*)(g),
      (__attribute__((address_space(3))) u32*)(l), 16, 0, 0);
}

// ---------------- conversions ----------------
__global__ void k_f2bf4(const float* __restrict__ x, unsigned short* __restrict__ y, int n4){
  int i=blockIdx.x*256+threadIdx.x; if(i>=n4) return;
  float4 v=((const float4*)x)[i];
  ushort4 r; r.x=f2bf(v.x); r.y=f2bf(v.y); r.z=f2bf(v.z); r.w=f2bf(v.w);
  ((ushort4*)y)[i]=r;
}
// W[K][N] f32 -> Wt[N][K] bf16, LDS 32x32 tile transpose (coalesced both sides)
__global__ __launch_bounds__(256) void k_wconv_t(
    const float* __restrict__ W, unsigned short* __restrict__ Wt, int K, int N){
  __shared__ float T[32][33];
  int k0=blockIdx.x*32, n0=blockIdx.y*32;
  int t=threadIdx.x, r=t>>3, c4=(t&7)*4;
  float4 a=*(const float4*)(W+(size_t)(k0+r)*N + n0+c4);
  T[r][c4]=a.x; T[r][c4+1]=a.y; T[r][c4+2]=a.z; T[r][c4+3]=a.w;
  __syncthreads();
  ushort4 w;
  w.x=f2bf(T[c4+0][r]); w.y=f2bf(T[c4+1][r]);
  w.z=f2bf(T[c4+2][r]); w.w=f2bf(T[c4+3][r]);
  *(ushort4*)(Wt+(size_t)(n0+r)*K + k0+c4)=w;
}

// ---------------- MFMA bf16 GEMM: 128x128 tile, BK=32, XCD swizzle -----------
// ASRC 0: A bf16 row-major (global_load_lds staging)
// ASRC 3: A bf16 head-major [bb][8][NPAD][64] (global_load_lds staging)
template<int MODE, int ASRC>
__global__ __launch_bounds__(256) void k_mfma_gemm(
    const void* __restrict__ Ap, const unsigned short* __restrict__ Bt,
    int M, int N, int K,
    const float* __restrict__ bias,
    void* __restrict__ o0, void* __restrict__ o1, void* __restrict__ o2)
{
  __shared__ __align__(16) unsigned short Sh[128*64];   // As=Sh[0..4095], Bs=Sh[4096..]
  int t=threadIdx.x;
  int bx=blockIdx.x, by=blockIdx.y;
  { // bijective XCD swizzle (grid size divisible by 8)
    int gx=gridDim.x; int wg=by*gx+bx; int nwg=gx*gridDim.y;
    int cpx=nwg>>3; int x2=(wg&7)*cpx+(wg>>3);
    by=x2/gx; bx=x2-by*gx;
  }
  int row0=by*128, col0=bx*128;
  int lane=t&63, w=t>>6, wr=w>>1, wc=w&1, lr=lane&15, kg=lane>>4;
  f32x4 acc[4][4];
  #pragma unroll
  for(int m=0;m<4;m++)
    #pragma unroll
    for(int n=0;n<4;n++) acc[m][n]=(f32x4){0.f,0.f,0.f,0.f};

  for(int k0=0;k0<K;k0+=32){
    __syncthreads();   // previous tile fully consumed
    #pragma unroll
    for(int i=0;i<2;i++){
      int flat=i*256+t, r=flat>>2, k8=flat&3;
      int kofs=k0+k8*8;
      const unsigned short* asrc;
      if constexpr(ASRC==0){
        asrc=(const unsigned short*)Ap+(size_t)(row0+r)*K+kofs;
      } else {
        int rr2=row0+r; int bb=rr2>>14, ri=rr2&16383;
        int head=kofs>>6, dd=kofs&63;
        asrc=(const unsigned short*)Ap + (((size_t)bb*NH+head)*NPAD+ri)*HD + dd;
      }
      gl16(asrc, Sh+(size_t)flat*8);
      gl16(Bt+(size_t)(col0+r)*K+kofs, Sh+4096+(size_t)flat*8);
    }
    __syncthreads();   // data ready (vmcnt/lgkm drained before barrier)
    short8v af[4], bf[4];
    #pragma unroll
    for(int m=0;m<4;m++) af[m]=*(const short8v*)(Sh+(wr*64+m*16+lr)*32 + kg*8);
    #pragma unroll
    for(int n=0;n<4;n++) bf[n]=*(const short8v*)(Sh+4096+(wc*64+n*16+lr)*32 + kg*8);
    #pragma unroll
    for(int m=0;m<4;m++)
      #pragma unroll
      for(int n=0;n<4;n++)
        acc[m][n]=__builtin_amdgcn_mfma_f32_16x16x32_bf16(af[m],bf[n],acc[m][n],0,0,0);
  }
  // ---- epilogue ----
  if constexpr(MODE==1){
    // coalesced q/k/v store via LDS restage (2 passes of 64 rows x 128 cols bf16)
    #pragma unroll
    for(int p=0;p<2;p++){
      __syncthreads();
      #pragma unroll
      for(int mm=0;mm<2;mm++){
        int m=2*p+mm;
        #pragma unroll
        for(int n=0;n<4;n++){
          int cc=wc*64+n*16+lr;
          int c=col0+cc;
          float sc=((c>>9)==0)?0.125f:1.f;
          #pragma unroll
          for(int j=0;j<4;j++){
            int lrow=wr*32+mm*16+kg*4+j;
            Sh[lrow*128+cc]=f2bf(acc[m][n][j]*sc);
          }
        }
      }
      __syncthreads();
      #pragma unroll
      for(int i=0;i<4;i++){
        int p2=i*256+t;
        int r2=p2>>4, ck=p2&15;
        int grow=row0+(r2>>5)*64+(2*p+((r2>>4)&1))*16+(r2&15);
        int bb=grow>>14, rr=grow&16383;
        int c=col0+ck*8;
        int which=c>>9, hcol=c&511, head=hcol>>6, dd=hcol&63;
        unsigned short* dst=(which==0)?(unsigned short*)o0:
                            (which==1)?(unsigned short*)o1:(unsigned short*)o2;
        *(short8v*)(dst + (((size_t)bb*NH+head)*NPAD+rr)*HD+dd) =
            *(const short8v*)(Sh + r2*128 + ck*8);
      }
    }
  } else {
    #pragma unroll
    for(int m=0;m<4;m++){
      int rbase=row0 + wr*64 + m*16 + kg*4;
      #pragma unroll
      for(int j=0;j<4;j++){
        int r=rbase+j;
        #pragma unroll
        for(int n=0;n<4;n++){
          int c=col0 + wc*64 + n*16 + lr;
          float val=acc[m][n][j];
          if(MODE==0){
            float* h=(float*)o0;
            int bb=(r>=16000)?1:0, ii=r-bb*16000;
            float vv=fmaxf(val+bias[c],0.f);
            h[((size_t)bb*NTOK + 1 + ii)*DM + c]=vv;
            if(ii<129) h[((size_t)bb*NTOK + 16001 + ii)*DM + c]=vv;
          } else {
            float* h=(float*)o0;
            int bb=r>>14, rr=r&16383;
            if(rr>=PADF)
              h[((size_t)bb*NTOK + (rr-PADF))*DM + c]+=val+bias[c];
          }
        }
      }
    }
  }
}

__global__ void k_cls(const float* __restrict__ cls, float* __restrict__ h){
  int t=blockIdx.x*256+threadIdx.x;
  if(t<2*DM) h[(size_t)(t>>9)*NTOK*DM + (t&511)]=cls[t&511];
}

// ---------------- layernorm + front zero-pad -> bf16, one wave per row ------
__global__ __launch_bounds__(256) void k_lnpad(
    const float* __restrict__ h, const float* __restrict__ g,
    const float* __restrict__ bta, unsigned short* __restrict__ xln)
{
  int wid=blockIdx.x*4+(threadIdx.x>>6);
  int lane=threadIdx.x&63;
  int bb=wid>>14, i=wid&16383;
  unsigned short* dst=xln+(size_t)wid*DM+lane*8;
  if(i<PADF){
    ushort4 z=(ushort4){0,0,0,0};
    *(ushort4*)dst=z; *(ushort4*)(dst+4)=z;
    return;
  }
  const float* src=h+((size_t)bb*NTOK + (i-PADF))*DM + lane*8;
  float4 v0=*(const float4*)src;
  float4 v1=*(const float4*)(src+4);
  float x[8]={v0.x,v0.y,v0.z,v0.w,v1.x,v1.y,v1.z,v1.w};
  float s=0.f;
  #pragma unroll
  for(int k=0;k<8;k++) s+=x[k];
  float mu=wred_sum(s)*(1.f/512.f);
  float d[8]; float vs=0.f;
  #pragma unroll
  for(int k=0;k<8;k++){ d[k]=x[k]-mu; vs+=d[k]*d[k]; }
  float rst=rsqrtf(wred_sum(vs)*(1.f/512.f)+1e-5f);
  float4 g0=*(const float4*)(g+lane*8),   g1=*(const float4*)(g+lane*8+4);
  float4 b0=*(const float4*)(bta+lane*8), b1=*(const float4*)(bta+lane*8+4);
  float gg[8]={g0.x,g0.y,g0.z,g0.w,g1.x,g1.y,g1.z,g1.w};
  float bb8[8]={b0.x,b0.y,b0.z,b0.w,b1.x,b1.y,b1.z,b1.w};
  ushort4 w0,w1;
  w0.x=f2bf(d[0]*rst*gg[0]+bb8[0]); w0.y=f2bf(d[1]*rst*gg[1]+bb8[1]);
  w0.z=f2bf(d[2]*rst*gg[2]+bb8[2]); w0.w=f2bf(d[3]*rst*gg[3]+bb8[3]);
  w1.x=f2bf(d[4]*rst*gg[4]+bb8[4]); w1.y=f2bf(d[5]*rst*gg[5]+bb8[5]);
  w1.z=f2bf(d[6]*rst*gg[6]+bb8[6]); w1.w=f2bf(d[7]*rst*gg[7]+bb8[7]);
  *(ushort4*)dst=w0; *(ushort4*)(dst+4)=w1;
}

// ---------------- landmark means, q and k in one launch ----------------
__global__ void k_lmean2(const unsigned short* __restrict__ qsrc,
                         const unsigned short* __restrict__ ksrc,
                         float* __restrict__ qlf, unsigned short* __restrict__ qlb_,
                         float* __restrict__ klf, unsigned short* __restrict__ klb_){
  int gid=blockIdx.x;
  const unsigned short* src; float* dstf; unsigned short* dstb;
  if(gid<4096){ src=qsrc; dstf=qlf; dstb=qlb_; }
  else        { src=ksrc; dstf=klf; dstb=klb_; gid-=4096; }
  int bh=gid>>8, s=gid&255, d=threadIdx.x;  // 64 threads
  const unsigned short* p=src + (((size_t)bh*NPAD)+s*SEG)*HD + d;
  float acc=0.f;
  #pragma unroll
  for(int l=0;l<SEG;l++) acc+=bf2f(p[(size_t)l*HD]);
  float m=acc*(1.f/64.f);
  dstf[((size_t)bh*LM+s)*HD+d]=m;
  dstb[((size_t)bh*LM+s)*HD+d]=f2bf(m);
}

// ---------------- v bf16 head-major -> vt bf16 [bh][64][NPAD] ----------------
__global__ __launch_bounds__(256) void k_vtrans(
    const unsigned short* __restrict__ v, unsigned short* __restrict__ vt)
{
  __shared__ unsigned short tile[64][72];
  int kt=blockIdx.x, bh=blockIdx.y;
  int t=threadIdx.x;
  int r=t>>2, sgq=t&3;
  const short8v* src=(const short8v*)(v + ((size_t)bh*NPAD + kt*64 + r)*HD + sgq*16);
  *(short8v*)(&tile[r][sgq*16])  =src[0];
  *(short8v*)(&tile[r][sgq*16+8])=src[1];
  __syncthreads();
  int d=t>>2;
  union{unsigned short u[16]; short8v v8[2];} pk;
  #pragma unroll
  for(int i=0;i<16;i++) pk.u[i]=tile[sgq*16+i][d];
  short8v* dst=(short8v*)(vt + ((size_t)bh*HD + d)*NPAD + kt*64 + sgq*16);
  dst[0]=pk.v8[0]; dst[1]=pk.v8[1];
}

// ---------------- attn2 = softmax(ql @ kl^T) f32 + fused hi/lo split --------
__global__ __launch_bounds__(256) void k_attn2(
    const float* __restrict__ ql, const float* __restrict__ kl,
    float* __restrict__ attn2,
    unsigned short* __restrict__ a2h, unsigned short* __restrict__ a2l)
{
  __shared__ float qrow[64]; __shared__ float s4[4];
  int bh=blockIdx.x>>8, i=blockIdx.x&255, j=threadIdx.x;
  if(j<64) qrow[j]=ql[((size_t)bh*LM+i)*HD+j];
  __syncthreads();
  const float* kp=kl+((size_t)bh*LM+j)*HD;
  float l=0.f;
  #pragma unroll
  for(int d=0;d<64;d++) l+=qrow[d]*kp[d];
  float m=block_max256(l,s4);
  float e=__expf(l-m);
  float s=block_sum256(e,s4);
  float pv=e/s;
  size_t o=((size_t)bh*LM+i)*LM+j;
  attn2[o]=pv;
  unsigned short hh=f2bf(pv);
  a2h[o]=hh; a2l[o]=f2bf(pv-bf2f(hh));
}

// ---------------- pinv helpers (rowsum of softmax == 1, skip it) ------------
// two-stage colsum: partials into scratch (pacc), then combine
__global__ void k_colsumA(const float* __restrict__ x, float* __restrict__ partial){
  int bh=blockIdx.y, ic=blockIdx.x, j=threadIdx.x;
  const float* p=x+(size_t)bh*65536+(size_t)ic*16*256;
  float s=0.f;
  #pragma unroll
  for(int i=0;i<16;i++) s+=p[(size_t)i*256+j];
  partial[((size_t)bh*16+ic)*256+j]=s;
}
__global__ void k_colsumB(const float* __restrict__ partial, float* __restrict__ cs){
  int bh=blockIdx.x, j=threadIdx.x;
  float s=0.f;
  #pragma unroll
  for(int ic=0;ic<16;ic++) s+=partial[((size_t)bh*16+ic)*256+j];
  cs[bh*256+j]=s;
}
__global__ void k_pinvscale(const float* __restrict__ cs, float* __restrict__ scale){
  __shared__ float s4[4];
  float mc=-1e30f;
  for(int i=threadIdx.x;i<4096;i+=256) mc=fmaxf(mc,cs[i]);
  mc=block_max256(mc,s4);
  if(threadIdx.x==0) scale[0]=1.f/mc;
}
// z0 init via dual 32x32 LDS tile transpose (all reads/writes coalesced)
__global__ __launch_bounds__(256) void k_zinit_hl(
    const float* __restrict__ x, const float* __restrict__ scale,
    unsigned short* __restrict__ zh, unsigned short* __restrict__ zl,
    unsigned short* __restrict__ zth, unsigned short* __restrict__ ztl){
  __shared__ float T1[32][33], T2[32][33];
  int bh=blockIdx.x>>6, tile=blockIdx.x&63;
  int i0=(tile>>3)*32, j0=(tile&7)*32;
  int t=threadIdx.x, r=t>>3, c4=(t&7)*4;
  size_t base=(size_t)bh*65536;
  float4 a=*(const float4*)(x+base+(size_t)(i0+r)*256+j0+c4);
  float4 b=*(const float4*)(x+base+(size_t)(j0+r)*256+i0+c4);
  T1[r][c4]=a.x; T1[r][c4+1]=a.y; T1[r][c4+2]=a.z; T1[r][c4+3]=a.w;
  T2[r][c4]=b.x; T2[r][c4+1]=b.y; T2[r][c4+2]=b.z; T2[r][c4+3]=b.w;
  __syncthreads();
  float s=scale[0];
  size_t o=base+(size_t)(i0+r)*256+j0+c4;
  ushort4 nh,nl,th,tl;
  {
    float vn, vt; unsigned short hh;
    vn=T2[c4+0][r]*s; hh=f2bf(vn); nh.x=hh; nl.x=f2bf(vn-bf2f(hh));
    vn=T2[c4+1][r]*s; hh=f2bf(vn); nh.y=hh; nl.y=f2bf(vn-bf2f(hh));
    vn=T2[c4+2][r]*s; hh=f2bf(vn); nh.z=hh; nl.z=f2bf(vn-bf2f(hh));
    vn=T2[c4+3][r]*s; hh=f2bf(vn); nh.w=hh; nl.w=f2bf(vn-bf2f(hh));
    vt=T1[r][c4+0]*s; hh=f2bf(vt); th.x=hh; tl.x=f2bf(vt-bf2f(hh));
    vt=T1[r][c4+1]*s; hh=f2bf(vt); th.y=hh; tl.y=f2bf(vt-bf2f(hh));
    vt=T1[r][c4+2]*s; hh=f2bf(vt); th.z=hh; tl.z=f2bf(vt-bf2f(hh));
    vt=T1[r][c4+3]*s; hh=f2bf(vt); th.w=hh; tl.w=f2bf(vt-bf2f(hh));
  }
  *(ushort4*)(zh+o)=nh; *(ushort4*)(zl+o)=nl;
  *(ushort4*)(zth+o)=th; *(ushort4*)(ztl+o)=tl;
}

// ---------------- hi/lo split bf16 MFMA batched GEMM (pinv chain) -----------
// Tile 32(M)x64(N), BK=64, 4 k-steps, grid 512 blocks (2/CU)
// MODE 0: C=A@B (emit normal+trans)    MODE 1: C=15I-7X+acc (trans only)
// MODE 2: C=13I-acc (trans only)       MODE 3: C=0.25*acc (normal+trans)
// MODE 4: C=acc (trans only, hi only; Ndim=64)
// PREC 0: single bf16 product; PREC 1: hi/lo 3-product (f32-equivalent)
template<int MODE, int PREC>
__global__ __launch_bounds__(256) void k_bmm3(
    const unsigned short* __restrict__ Ah, const unsigned short* __restrict__ Al,
    const unsigned short* __restrict__ Bth, const unsigned short* __restrict__ Btl,
    const unsigned short* __restrict__ Xh, const unsigned short* __restrict__ Xl,
    unsigned short* __restrict__ Cnh, unsigned short* __restrict__ Cnl,
    unsigned short* __restrict__ Cth, unsigned short* __restrict__ Ctl,
    int Ndim)
{
  __shared__ unsigned short AsH[32*72], BsH[64*72];
  __shared__ unsigned short AsL[PREC?32*72:8], BsL[PREC?64*72:8];
  int bh=blockIdx.z;
  int n0=blockIdx.x*64, m0=blockIdx.y*32;
  int t=threadIdx.x, lane=t&63, w=t>>6;
  int c=lane&15, g=lane>>4;
  int wr=(w>>1)*16, wc=(w&1)*32;
  f32x4 acc[2];
  acc[0]=(f32x4){0.f,0.f,0.f,0.f};
  acc[1]=(f32x4){0.f,0.f,0.f,0.f};
  size_t Abase=(size_t)bh*65536;
  size_t Bbase=(size_t)bh*(size_t)Ndim*256;
  int r=t>>3, k8=(t&7)*8;
  const unsigned short* ApH =Ah +Abase+(size_t)(m0+r)*256+k8;
  const unsigned short* BpH0=Bth+Bbase+(size_t)(n0+r)*256+k8;
  const unsigned short* BpH1=Bth+Bbase+(size_t)(n0+32+r)*256+k8;
  const unsigned short* ApL =Al +Abase+(size_t)(m0+r)*256+k8;
  const unsigned short* BpL0=Btl+Bbase+(size_t)(n0+r)*256+k8;
  const unsigned short* BpL1=Btl+Bbase+(size_t)(n0+32+r)*256+k8;
  short8v rah,rbh0,rbh1, ral,rbl0,rbl1;
  rah =*(const short8v*)(ApH);
  rbh0=*(const short8v*)(BpH0);
  rbh1=*(const short8v*)(BpH1);
  if constexpr(PREC==1){
    ral =*(const short8v*)(ApL);
    rbl0=*(const short8v*)(BpL0);
    rbl1=*(const short8v*)(BpL1);
  }
  int k0=0;
  for(;;){
    __syncthreads();
    *(short8v*)(AsH + r*72 + k8)=rah;
    *(short8v*)(BsH + r*72 + k8)=rbh0;
    *(short8v*)(BsH + (r+32)*72 + k8)=rbh1;
    if constexpr(PREC==1){
      *(short8v*)(AsL + r*72 + k8)=ral;
      *(short8v*)(BsL + r*72 + k8)=rbl0;
      *(short8v*)(BsL + (r+32)*72 + k8)=rbl1;
    }
    __syncthreads();
    int kn=k0+64;
    if(kn<256){
      rah =*(const short8v*)(ApH +kn);
      rbh0=*(const short8v*)(BpH0+kn);
      rbh1=*(const short8v*)(BpH1+kn);
      if constexpr(PREC==1){
        ral =*(const short8v*)(ApL +kn);
        rbl0=*(const short8v*)(BpL0+kn);
        rbl1=*(const short8v*)(BpL1+kn);
      }
    }
    #pragma unroll
    for(int ks=0;ks<2;ks++){
      short8v af=*(const short8v*)(AsH+(wr+c)*72 + ks*32 + g*8);
      short8v alf;
      if constexpr(PREC==1) alf=*(const short8v*)(AsL+(wr+c)*72 + ks*32 + g*8);
      #pragma unroll
      for(int nt=0;nt<2;nt++){
        short8v bf=*(const short8v*)(BsH+(wc+nt*16+c)*72 + ks*32 + g*8);
        acc[nt]=__builtin_amdgcn_mfma_f32_16x16x32_bf16(af,bf,acc[nt],0,0,0);
        if constexpr(PREC==1){
          short8v blf=*(const short8v*)(BsL+(wc+nt*16+c)*72 + ks*32 + g*8);
          acc[nt]=__builtin_amdgcn_mfma_f32_16x16x32_bf16(af,blf,acc[nt],0,0,0);
          acc[nt]=__builtin_amdgcn_mfma_f32_16x16x32_bf16(alf,bf,acc[nt],0,0,0);
        }
      }
    }
    if(kn>=256) break;
    k0=kn;
  }
  int rb=m0+wr+g*4;
  #pragma unroll
  for(int nt=0;nt<2;nt++){
    int cc=n0+wc+nt*16+c;
    float vv[4];
    #pragma unroll
    for(int j=0;j<4;j++){
      float a=acc[nt][j];
      int rr=rb+j;
      if(MODE==1){
        float xv=bf2f(Xh[Abase+(size_t)rr*256+cc])+bf2f(Xl[Abase+(size_t)rr*256+cc]);
        a=(rr==cc?15.f:0.f)-7.f*xv+a;
      } else if(MODE==2){
        a=(rr==cc?13.f:0.f)-a;
      } else if(MODE==3){
        a*=0.25f;
      }
      vv[j]=a;
    }
    if(MODE==0||MODE==3){
      #pragma unroll
      for(int j=0;j<4;j++){
        unsigned short hh=f2bf(vv[j]);
        Cnh[Abase+(size_t)(rb+j)*256+cc]=hh;
        Cnl[Abase+(size_t)(rb+j)*256+cc]=f2bf(vv[j]-bf2f(hh));
      }
    }
    {
      ushort4 hv, lv;
      hv.x=f2bf(vv[0]); hv.y=f2bf(vv[1]); hv.z=f2bf(vv[2]); hv.w=f2bf(vv[3]);
      lv.x=f2bf(vv[0]-bf2f(hv.x)); lv.y=f2bf(vv[1]-bf2f(hv.y));
      lv.z=f2bf(vv[2]-bf2f(hv.z)); lv.w=f2bf(vv[3]-bf2f(hv.w));
      size_t co=((size_t)bh*Ndim+cc)*256+rb;
      *(ushort4*)(Cth+co)=hv;
      if(MODE!=4) *(ushort4*)(Ctl+co)=lv;
    }
  }
}

// ---------------- attn3@v : MFMA flash, split-K 16 chunks x 2 row-halves -----
__global__ __launch_bounds__(512) void k_attn3m(
    const unsigned short* __restrict__ qlb,
    const unsigned short* __restrict__ kb,
    const unsigned short* __restrict__ vtb,
    float* __restrict__ pacc, float* __restrict__ pms)
{
  __shared__ unsigned short Ks[64*72];
  __shared__ unsigned short Vs[64*72];
  int ck=blockIdx.x, rh=blockIdx.y, bh=blockIdx.z;
  int t=threadIdx.x, lane=t&63, w=t>>6;
  int c=lane&15, g=lane>>4;
  int qrow0=rh*128 + w*16;          // this wave's 16 q-rows: qrow0 + c
  short8v Qf[2];
  #pragma unroll
  for(int kw=0;kw<2;kw++)
    Qf[kw]=*(const short8v*)(qlb + ((size_t)bh*LM + qrow0 + c)*HD + kw*32 + g*8);
  f32x4 accO[4];
  float mrun=-3e38f, srun=0.f;
  #pragma unroll
  for(int d=0;d<4;d++) accO[d]=(f32x4){0.f,0.f,0.f,0.f};
  int sr=t>>3, sgk=t&7;
  for(int sc=0;sc<16;++sc){
    int key0=ck*1024 + sc*64;
    __syncthreads();
    *(short8v*)(Ks + sr*72 + sgk*8) =
      *(const short8v*)(kb + ((size_t)bh*NPAD + key0 + sr)*HD + sgk*8);
    *(short8v*)(Vs + sr*72 + sgk*8) =
      *(const short8v*)(vtb + ((size_t)bh*HD + sr)*NPAD + key0 + sgk*8);
    __syncthreads();
    f32x4 s[4];
    #pragma unroll
    for(int mt=0;mt<4;mt++){
      short8v a0=*(const short8v*)(Ks + (mt*16+c)*72 + g*8);
      short8v a1=*(const short8v*)(Ks + (mt*16+c)*72 + 32 + g*8);
      f32x4 z=(f32x4){0.f,0.f,0.f,0.f};
      z=__builtin_amdgcn_mfma_f32_16x16x32_bf16(a0,Qf[0],z,0,0,0);
      z=__builtin_amdgcn_mfma_f32_16x16x32_bf16(a1,Qf[1],z,0,0,0);
      s[mt]=z;
    }
    unsigned U[4][2];
    {
      float cm=-3e38f;
      #pragma unroll
      for(int mt=0;mt<4;mt++)
        #pragma unroll
        for(int j=0;j<4;j++) cm=fmaxf(cm,s[mt][j]);
      cm=fmaxf(cm,__shfl_xor(cm,16));
      cm=fmaxf(cm,__shfl_xor(cm,32));
      float mnew=fmaxf(mrun,cm);
      float f=__expf(mrun-mnew);
      mrun=mnew;
      float ps=0.f;
      #pragma unroll
      for(int mt=0;mt<4;mt++){
        float p0=__expf(s[mt][0]-mnew);
        float p1=__expf(s[mt][1]-mnew);
        float p2=__expf(s[mt][2]-mnew);
        float p3=__expf(s[mt][3]-mnew);
        ps+=p0+p1+p2+p3;
        U[mt][0]=cvtpk(p0,p1);
        U[mt][1]=cvtpk(p2,p3);
      }
      ps+=__shfl_xor(ps,16); ps+=__shfl_xor(ps,32);
      srun=srun*f+ps;
      #pragma unroll
      for(int d=0;d<4;d++){
        accO[d][0]*=f; accO[d][1]*=f; accO[d][2]*=f; accO[d][3]*=f;
      }
    }
    #pragma unroll
    for(int kw=0;kw<2;kw++){
      union{unsigned u[4]; short8v v;} pk;
      #pragma unroll
      for(int wd=0;wd<4;wd++){
        int sl=c+16*(((g&1)<<1)+(wd>>1));
        unsigned va=(unsigned)__shfl((int)U[kw*2  ][wd&1],sl);
        unsigned vb=(unsigned)__shfl((int)U[kw*2+1][wd&1],sl);
        pk.u[wd]=(lane>=32)?vb:va;
      }
      #pragma unroll
      for(int d=0;d<4;d++){
        short8v vf=*(const short8v*)(Vs + (d*16+c)*72 + kw*32 + g*8);
        accO[d]=__builtin_amdgcn_mfma_f32_16x16x32_bf16(vf,pk.v,accO[d],0,0,0);
      }
    }
  }
  size_t pb=((size_t)bh*16+ck)*LM;
  int q=qrow0+c;
  #pragma unroll
  for(int d=0;d<4;d++)
    *(f32x4*)(pacc + (pb+q)*HD + d*16 + g*4)=accO[d];
  if(g==0){ pms[(pb+q)*2]=mrun; pms[(pb+q)*2+1]=srun; }
}
__global__ __launch_bounds__(256) void k_attn3vc(
    const float* __restrict__ pacc, const float* __restrict__ pms,
    unsigned short* __restrict__ a3vth, unsigned short* __restrict__ a3vtl)
{
  int gid=blockIdx.x*4+(threadIdx.x>>6);
  int bh=gid>>8, row=gid&255, lane=threadIdx.x&63;
  float M=-3e38f;
  float ms[16], ss[16];
  #pragma unroll
  for(int c=0;c<16;c++){
    size_t pb=((size_t)bh*16+c)*LM+row;
    ms[c]=pms[pb*2]; ss[c]=pms[pb*2+1];
    M=fmaxf(M,ms[c]);
  }
  float S=0.f,a=0.f;
  #pragma unroll
  for(int c=0;c<16;c++){
    float f=__expf(ms[c]-M);
    S+=ss[c]*f;
    a+=pacc[(((size_t)bh*16+c)*LM+row)*HD+lane]*f;
  }
  float v=a/S;
  unsigned short hi=f2bf(v);
  a3vth[((size_t)bh*HD+lane)*LM+row]=hi;
  a3vtl[((size_t)bh*HD+lane)*LM+row]=f2bf(v-bf2f(hi));
}

// ---------------- attn1 @ W2 : MFMA, 256 landmarks one-shot; bf16 out --------
__global__ __launch_bounds__(512) void k_attn1m(
    const unsigned short* __restrict__ qb,
    const unsigned short* __restrict__ klb,
    const unsigned short* __restrict__ w2t,
    unsigned short* __restrict__ aohb)
{
  __shared__ unsigned short klS[256*72];
  __shared__ unsigned short w2S[64*264];
  int qt=blockIdx.x, bh=blockIdx.y;
  int t=threadIdx.x, lane=t&63, w=t>>6;
  int c=lane&15, g=lane>>4;
  {
    int r=t>>1, hf=t&1;
    const short8v* s=(const short8v*)(klb + ((size_t)bh*LM+r)*HD + hf*32);
    short8v* d=(short8v*)(klS + r*72 + hf*32);
    d[0]=s[0]; d[1]=s[1]; d[2]=s[2]; d[3]=s[3];
    int r2=t>>3, sg2=t&7;
    const short8v* s2=(const short8v*)(w2t + ((size_t)bh*HD+r2)*LM + sg2*32);
    short8v* d2=(short8v*)(w2S + r2*264 + sg2*32);
    d2[0]=s2[0]; d2[1]=s2[1]; d2[2]=s2[2]; d2[3]=s2[3];
  }
  __syncthreads();
  int q0=qt*256 + w*32;
  #pragma unroll
  for(int n=0;n<2;n++){
    const unsigned short* qrow=qb + ((size_t)bh*NPAD + q0 + n*16 + c)*HD;
    short8v qf0=*(const short8v*)(qrow + g*8);
    short8v qf1=*(const short8v*)(qrow + 32 + g*8);
    f32x4 s[16];
    #pragma unroll
    for(int mt=0;mt<16;mt++){
      short8v a0=*(const short8v*)(klS + (mt*16+c)*72 + g*8);
      short8v a1=*(const short8v*)(klS + (mt*16+c)*72 + 32 + g*8);
      f32x4 z=(f32x4){0.f,0.f,0.f,0.f};
      z=__builtin_amdgcn_mfma_f32_16x16x32_bf16(a0,qf0,z,0,0,0);
      z=__builtin_amdgcn_mfma_f32_16x16x32_bf16(a1,qf1,z,0,0,0);
      s[mt]=z;
    }
    float M=-3e38f;
    #pragma unroll
    for(int mt=0;mt<16;mt++)
      #pragma unroll
      for(int j=0;j<4;j++) M=fmaxf(M,s[mt][j]);
    M=fmaxf(M,__shfl_xor(M,16));
    M=fmaxf(M,__shfl_xor(M,32));
    float sum=0.f;
    unsigned U[16][2];
    #pragma unroll
    for(int mt=0;mt<16;mt++){
      float p0=__expf(s[mt][0]-M);
      float p1=__expf(s[mt][1]-M);
      float p2=__expf(s[mt][2]-M);
      float p3=__expf(s[mt][3]-M);
      sum+=p0+p1+p2+p3;
      U[mt][0]=cvtpk(p0,p1);
      U[mt][1]=cvtpk(p2,p3);
    }
    sum+=__shfl_xor(sum,16); sum+=__shfl_xor(sum,32);
    float inv=1.f/sum;
    f32x4 accO[4];
    #pragma unroll
    for(int d=0;d<4;d++) accO[d]=(f32x4){0.f,0.f,0.f,0.f};
    #pragma unroll
    for(int kw=0;kw<8;kw++){
      union{unsigned u[4]; short8v v;} pk;
      #pragma unroll
      for(int wd=0;wd<4;wd++){
        int sl=c+16*(((g&1)<<1)+(wd>>1));
        unsigned va=(unsigned)__shfl((int)U[kw*2  ][wd&1],sl);
        unsigned vb=(unsigned)__shfl((int)U[kw*2+1][wd&1],sl);
        pk.u[wd]=(lane>=32)?vb:va;
      }
      #pragma unroll
      for(int d=0;d<4;d++){
        short8v vf=*(const short8v*)(w2S + (d*16+c)*264 + kw*32 + g*8);
        accO[d]=__builtin_amdgcn_mfma_f32_16x16x32_bf16(vf,pk.v,accO[d],0,0,0);
      }
    }
    int q=q0+n*16+c;
    #pragma unroll
    for(int d=0;d<4;d++){
      f32x4 o=accO[d];
      uint2 pk2;
      pk2.x=cvtpk(o[0]*inv, o[1]*inv);
      pk2.y=cvtpk(o[2]*inv, o[3]*inv);
      *(uint2*)(aohb + ((size_t)bh*NPAD+q)*HD + d*16 + g*4)=pk2;
    }
  }
}

// ---------------- depthwise 33-tap conv from vt; aoh bf16 += -----------------
__global__ __launch_bounds__(256) void k_resconv2(
    const unsigned short* __restrict__ vt, const float* __restrict__ rw,
    unsigned short* __restrict__ aohb){
  int bx=blockIdx.x, bh=blockIdx.y;
  int t=threadIdx.x, d=t&63, g=t>>6;
  int i0=bx*32+g*8;
  int hh=bh&7;
  const unsigned short* vr=vt + ((size_t)bh*HD + d)*NPAD;
  float wv[40];
  int start=i0-16;
  if(start>=0 && start+40<=NPAD){
    #pragma unroll
    for(int b=0;b<5;b++){
      short8v v8=*(const short8v*)(vr+start+b*8);
      #pragma unroll
      for(int j=0;j<8;j++) wv[b*8+j]=bf2f((unsigned short)v8[j]);
    }
  } else {
    #pragma unroll
    for(int t2=0;t2<40;t2++){
      int src=start+t2;
      wv[t2]=(src>=0&&src<NPAD)?bf2f(vr[src]):0.f;
    }
  }
  const float* wt=rw+hh*33;
  #pragma unroll
  for(int p=0;p<8;p++){
    float a=0.f;
    #pragma unroll
    for(int tk=0;tk<33;tk++) a+=wv[p+tk]*wt[tk];
    size_t o=((size_t)bh*NPAD+i0+p)*HD+d;
    aohb[o]=f2bf(bf2f(aohb[o])+a);
  }
}

// ---------------- PPEG weight prep: combined 7x7 tap table (bf16) -----------
__global__ void k_wprep(const float* __restrict__ w7, const float* __restrict__ b7,
                        const float* __restrict__ w5, const float* __restrict__ b5,
                        const float* __restrict__ w3, const float* __restrict__ b3,
                        unsigned short* __restrict__ wcat){
  int t=blockIdx.x*256+threadIdx.x;
  if(t>=50*512) return;
  int r=t>>9, c=t&511;
  float v;
  if(r<49){
    int ky=r/7, kx=r%7;
    v=w7[(size_t)c*49+r];
    if(ky>=1&&ky<=5&&kx>=1&&kx<=5) v+=w5[(size_t)c*25+(ky-1)*5+(kx-1)];
    if(ky>=2&&ky<=4&&kx>=2&&kx<=4) v+=w3[(size_t)c*9+(ky-2)*3+(kx-2)];
  } else {
    v=b7[c]+b5[c]+b3[c];
  }
  wcat[t]=f2bf(v);
}

// ---------------- PPEG: 8x8 tile x 32ch, f32 patch, sliding row window ------
__global__ __launch_bounds__(256,4) void k_ppeg4(
    const float* __restrict__ src, const unsigned short* __restrict__ wcat,
    float* __restrict__ dst)
{
  __shared__ float patch[196][32];   // 14x14 halo
  __shared__ float wsf[50][32];
  int bx=blockIdx.x;
  int cz=blockIdx.y, bb=blockIdx.z;
  int t=threadIdx.x, c=t&31, g=t>>5;   // 32ch x 8 groups
  int ty0=(bx>>4)*8, tx0=(bx&15)*8;
  const float* base=src+((size_t)bb*NTOK+1)*DM + cz*32 + c;
  #pragma unroll
  for(int i=0;i<25;i++){
    int p=g+8*i;
    if(p<196){
      int py=p/14, px=p%14;
      int yy=ty0-3+py, xx=tx0-3+px;
      float v=0.f;
      if(yy>=0&&yy<127&&xx>=0&&xx<127) v=base[(size_t)(yy*127+xx)*DM];
      patch[p][c]=v;
    }
  }
  #pragma unroll
  for(int i=0;i<7;i++){
    int r=g+8*i; if(r<50) wsf[r][c]=bf2f(wcat[(size_t)r*DM + cz*32 + c]);
  }
  __syncthreads();
  float acc[8];
  float bias=wsf[49][c];
  #pragma unroll
  for(int j=0;j<8;j++) acc[j]=patch[(g+3)*14+(j+3)][c]+bias;  // exact identity
  #pragma unroll
  for(int ky=0;ky<7;ky++){
    float win[14];
    #pragma unroll
    for(int x=0;x<14;x++) win[x]=patch[(g+ky)*14+x][c];
    #pragma unroll
    for(int kx=0;kx<7;kx++){
      float wv=wsf[ky*7+kx][c];
      #pragma unroll
      for(int j=0;j<8;j++) acc[j]+=win[j+kx]*wv;
    }
  }
  int y=ty0+g;
  if(y<127){
    #pragma unroll
    for(int j=0;j<8;j++){
      int x=tx0+j;
      if(x<127)
        dst[((size_t)bb*NTOK+1+(size_t)(y*127+x))*DM + cz*32 + c]=acc[j];
    }
  }
}

// copy cls row h -> dst
__global__ void k_cpcls(const float* __restrict__ h, float* __restrict__ dst){
  int t=blockIdx.x*256+threadIdx.x;
  if(t<2*DM) dst[(size_t)(t>>9)*NTOK*DM + (t&511)]=h[(size_t)(t>>9)*NTOK*DM + (t&511)];
}

// ---------------- final: LN(h[:,0]) @ fc2 + b ----------------
__global__ __launch_bounds__(256) void k_final(
    const float* __restrict__ h, const float* __restrict__ g, const float* __restrict__ bta,
    const float* __restrict__ w, const float* __restrict__ fb, float* __restrict__ out)
{
  int bb=blockIdx.x, t=threadIdx.x;
  const float* src=h+(size_t)bb*NTOK*DM;
  float x0=src[t], x1=src[t+256];
  __shared__ float s4[4];
  float mu=block_sum256(x0+x1,s4)*(1.f/512.f);
  float d0=x0-mu, d1=x1-mu;
  float var=block_sum256(d0*d0+d1*d1,s4)*(1.f/512.f);
  float rst=rsqrtf(var+1e-5f);
  float y0=d0*rst*g[t]+bta[t], y1=d1*rst*g[t+256]+bta[t+256];
  float dot=block_sum256(y0*w[t]+y1*w[t+256],s4);
  if(t==0) out[bb]=dot+fb[0];
}

// =======================================================================
extern "C" void kernel_launch(void* const* d_in, const int* in_sizes, int n_in,
                              void* d_out, int out_size, void* d_ws, size_t ws_size,
                              hipStream_t stream){
  (void)in_sizes; (void)n_in; (void)out_size; (void)ws_size;
  const float* features=(const float*)d_in[0];
  const float* fc1_w  =(const float*)d_in[1];
  const float* fc1_b  =(const float*)d_in[2];
  const float* cls_tok=(const float*)d_in[3];
  const float* fc2_w  =(const float*)d_in[24];
  const float* fc2_b  =(const float*)d_in[25];
  float* out=(float*)d_out;

  char* wp=(char*)d_ws;
  auto allocB=[&](size_t bytes)->char*{
    char* p=wp; wp+=((bytes+255)/256)*256; return p;
  };
  float* h    =(float*)allocB((size_t)NB*NTOK*DM*4);
  float* h2   =(float*)allocB((size_t)NB*NTOK*DM*4);
  unsigned short* vb  =(unsigned short*)allocB((size_t)NB*NPAD*DM*2);
  unsigned short* xlnb=(unsigned short*)allocB((size_t)NB*NPAD*DM*2);
  unsigned short* qb  =(unsigned short*)allocB((size_t)NB*NPAD*DM*2);
  unsigned short* kb  =(unsigned short*)allocB((size_t)NB*NPAD*DM*2);
  unsigned short* vtb =(unsigned short*)allocB((size_t)NB*NPAD*DM*2);
  unsigned short* aohb=(unsigned short*)allocB((size_t)NB*NPAD*DM*2);
  unsigned short* wtf=(unsigned short*)allocB((size_t)512*1024*2);
  unsigned short* wtq=(unsigned short*)allocB((size_t)1536*512*2);
  unsigned short* wtp=(unsigned short*)allocB((size_t)512*512*2);
  float* ql =(float*)allocB((size_t)16*LM*HD*4);
  float* kl =(float*)allocB((size_t)16*LM*HD*4);
  unsigned short* qlb=(unsigned short*)allocB((size_t)16*LM*HD*2);
  unsigned short* klb=(unsigned short*)allocB((size_t)16*LM*HD*2);
  float* attn2=(float*)allocB((size_t)16*LM*LM*4);
  unsigned short* a2h=(unsigned short*)allocB((size_t)16*LM*LM*2);
  unsigned short* a2l=(unsigned short*)allocB((size_t)16*LM*LM*2);
  unsigned short* zb[8];
  for(int i=0;i<8;i++) zb[i]=(unsigned short*)allocB((size_t)16*LM*LM*2);
  unsigned short* Abh=(unsigned short*)allocB((size_t)16*LM*LM*2);
  unsigned short* Abl=(unsigned short*)allocB((size_t)16*LM*LM*2);
  unsigned short* Abth=(unsigned short*)allocB((size_t)16*LM*LM*2);
  unsigned short* Abtl=(unsigned short*)allocB((size_t)16*LM*LM*2);
  unsigned short* Ubth=(unsigned short*)allocB((size_t)16*LM*LM*2);
  unsigned short* Ubtl=(unsigned short*)allocB((size_t)16*LM*LM*2);
  unsigned short* Tbth=(unsigned short*)allocB((size_t)16*LM*LM*2);
  unsigned short* Tbtl=(unsigned short*)allocB((size_t)16*LM*LM*2);
  unsigned short* a3vth=(unsigned short*)allocB((size_t)16*HD*LM*2);
  unsigned short* a3vtl=(unsigned short*)allocB((size_t)16*HD*LM*2);
  unsigned short* w2t=(unsigned short*)allocB((size_t)16*HD*LM*2);
  float* pacc=(float*)allocB((size_t)16*16*LM*HD*4);
  float* pms =(float*)allocB((size_t)16*16*LM*2*4);
  float* cs  =(float*)allocB(4096*4);
  float* scl =(float*)allocB(64*4);

  auto nystrom=[&](float* hbuf, const float* ng, const float* nbias, const float* qkvw,
                   const float* outw, const float* outb, const float* resw){
    k_lnpad<<<NB*NPAD/4,256,0,stream>>>(hbuf, ng, nbias, xlnb);
    k_wconv_t<<<dim3(16,48),256,0,stream>>>(qkvw, wtq, 512, 1536);
    k_mfma_gemm<1,0><<<dim3(12,256),256,0,stream>>>(xlnb, wtq, 32768,1536,512,
                                                    nullptr, qb, kb, vb);
    k_lmean2<<<8192,64,0,stream>>>(qb, kb, ql, qlb, kl, klb);
    k_vtrans<<<dim3(256,16),256,0,stream>>>(vb, vtb);
    k_attn2<<<4096,256,0,stream>>>(ql, kl, attn2, a2h, a2l);
    k_colsumA<<<dim3(16,16),256,0,stream>>>(attn2, pacc);
    k_colsumB<<<16,256,0,stream>>>(pacc, cs);
    k_pinvscale<<<1,256,0,stream>>>(cs, scl);
    k_zinit_hl<<<1024,256,0,stream>>>(attn2, scl, zb[0],zb[1],zb[2],zb[3]);
    unsigned short *zch=zb[0],*zcl=zb[1],*zcth=zb[2],*zctl=zb[3];
    unsigned short *znh=zb[4],*znl=zb[5],*znth=zb[6],*zntl=zb[7];
    for(int it=0;it<6;it++){
      if(it<5){
        k_bmm3<0,0><<<dim3(4,8,16),256,0,stream>>>(a2h,a2l, zcth,zctl, nullptr,nullptr,
                                                   Abh,Abl, Abth,Abtl, 256);
        k_bmm3<1,0><<<dim3(4,8,16),256,0,stream>>>(Abh,Abl, Abth,Abtl, Abh,Abl,
                                                   nullptr,nullptr, Ubth,Ubtl, 256);
        k_bmm3<2,0><<<dim3(4,8,16),256,0,stream>>>(Abh,Abl, Ubth,Ubtl, nullptr,nullptr,
                                                   nullptr,nullptr, Tbth,Tbtl, 256);
        k_bmm3<3,0><<<dim3(4,8,16),256,0,stream>>>(zch,zcl, Tbth,Tbtl, nullptr,nullptr,
                                                   znh,znl, znth,zntl, 256);
      } else {
        k_bmm3<0,1><<<dim3(4,8,16),256,0,stream>>>(a2h,a2l, zcth,zctl, nullptr,nullptr,
                                                   Abh,Abl, Abth,Abtl, 256);
        k_bmm3<1,1><<<dim3(4,8,16),256,0,stream>>>(Abh,Abl, Abth,Abtl, Abh,Abl,
                                                   nullptr,nullptr, Ubth,Ubtl, 256);
        k_bmm3<2,1><<<dim3(4,8,16),256,0,stream>>>(Abh,Abl, Ubth,Ubtl, nullptr,nullptr,
                                                   nullptr,nullptr, Tbth,Tbtl, 256);
        k_bmm3<3,1><<<dim3(4,8,16),256,0,stream>>>(zch,zcl, Tbth,Tbtl, nullptr,nullptr,
                                                   znh,znl, znth,zntl, 256);
      }
      unsigned short* tp;
      tp=zch; zch=znh; znh=tp;  tp=zcl; zcl=znl; znl=tp;
      tp=zcth; zcth=znth; znth=tp;  tp=zctl; zctl=zntl; zntl=tp;
    }
    k_attn3m<<<dim3(16,2,16),512,0,stream>>>(qlb, kb, vtb, pacc, pms);
    k_attn3vc<<<1024,256,0,stream>>>(pacc, pms, a3vth, a3vtl);
    k_bmm3<4,1><<<dim3(1,8,16),256,0,stream>>>(zch,zcl, a3vth,a3vtl, nullptr,nullptr,
                                               nullptr,nullptr, w2t,nullptr, 64);
    k_attn1m<<<dim3(64,16),512,0,stream>>>(qb, klb, w2t, aohb);
    k_resconv2<<<dim3(512,16),256,0,stream>>>(vtb, resw, aohb);
    k_wconv_t<<<dim3(16,16),256,0,stream>>>(outw, wtp, 512, 512);
    k_mfma_gemm<2,3><<<dim3(4,256),256,0,stream>>>(aohb, wtp, 32768,512,512,
                                                   outb, hbuf, nullptr, nullptr);
  };

  // fc1: features -> bf16 (h2 overlay), then MFMA GEMM via global_load_lds
  unsigned short* featbf=(unsigned short*)h2;   // dead before PPEG
  k_f2bf4<<<32000,256,0,stream>>>(features, featbf, 32000*1024/4);
  k_wconv_t<<<dim3(32,16),256,0,stream>>>(fc1_w, wtf, 1024, 512);
  k_mfma_gemm<0,0><<<dim3(4,250),256,0,stream>>>(featbf, wtf, 32000,512,1024,
                                                 fc1_b, h, nullptr, nullptr);
  k_cls<<<4,256,0,stream>>>(cls_tok, h);

  // layer 1 attention (on h)
  nystrom(h, (const float*)d_in[4],(const float*)d_in[5],(const float*)d_in[6],
          (const float*)d_in[7],(const float*)d_in[8],(const float*)d_in[9]);

  // PPEG: combined-tap stencil h -> h2 (no copy-back; layer 2 runs on h2)
  {
    unsigned short* wcat=(unsigned short*)attn2;  // free at this point
    k_wprep<<<100,256,0,stream>>>(
        (const float*)d_in[10],(const float*)d_in[11],
        (const float*)d_in[12],(const float*)d_in[13],
        (const float*)d_in[14],(const float*)d_in[15], wcat);
    k_cpcls<<<4,256,0,stream>>>(h, h2);
    k_ppeg4<<<dim3(256,16,2),256,0,stream>>>(h, wcat, h2);
  }

  // layer 2 attention (on h2)
  nystrom(h2, (const float*)d_in[16],(const float*)d_in[17],(const float*)d_in[18],
          (const float*)d_in[19],(const float*)d_in[20],(const float*)d_in[21]);

  // final LN(h2[:,0]) @ fc2
  k_final<<<2,256,0,stream>>>(h2,(const float*)d_in[22],(const float*)d_in[23],
                              fc2_w, fc2_b, out);
}

// Round 21
// 1195.799 us; speedup vs baseline: 1.3284x; 1.0093x over previous
//
#include <hip/hip_runtime.h>
#include <math.h>

#define NTOK 16130   // 1 + 127*127
#define NPAD 16384
#define PADF 254
#define NB   2
#define DM   512
#define NH   8
#define HD   64
#define LM   256
#define SEG  64

typedef __attribute__((ext_vector_type(8))) short short8v;
typedef __attribute__((ext_vector_type(4))) float f32x4;
typedef __attribute__((ext_vector_type(2))) float f32x2;
typedef unsigned int u32;

// ---------------- helpers ----------------
__device__ __forceinline__ float wred_max(float v){
  #pragma unroll
  for(int o=32;o;o>>=1) v=fmaxf(v,__shfl_xor(v,o));
  return v;
}
__device__ __forceinline__ float wred_sum(float v){
  #pragma unroll
  for(int o=32;o;o>>=1) v+=__shfl_xor(v,o);
  return v;
}
__device__ __forceinline__ float block_max256(float v, float* s4){
  v=wred_max(v);
  if((threadIdx.x&63)==0) s4[threadIdx.x>>6]=v;
  __syncthreads();
  v=fmaxf(fmaxf(s4[0],s4[1]),fmaxf(s4[2],s4[3]));
  __syncthreads();
  return v;
}
__device__ __forceinline__ float block_sum256(float v, float* s4){
  v=wred_sum(v);
  if((threadIdx.x&63)==0) s4[threadIdx.x>>6]=v;
  __syncthreads();
  v=s4[0]+s4[1]+s4[2]+s4[3];
  __syncthreads();
  return v;
}
__device__ __forceinline__ unsigned short f2bf(float f){
  unsigned u=__float_as_uint(f);
  u = u + 0x7FFFu + ((u>>16)&1u);
  return (unsigned short)(u>>16);
}
__device__ __forceinline__ float bf2f(unsigned short u){
  return __uint_as_float(((unsigned)u)<<16);
}
__device__ __forceinline__ unsigned cvtpk(float a, float b){
  unsigned r;
  asm("v_cvt_pk_bf16_f32 %0, %1, %2" : "=v"(r) : "v"(a), "v"(b));
  return r;
}
// async global->LDS, 16B per lane
__device__ __forceinline__ void gl16(const unsigned short* g, unsigned short* l){
  __builtin_amdgcn_global_load_lds(
      (const __attribute__((address_space(1))) u32*)(g),
      (__attribute__((address_space(3))) u32*)(l), 16, 0, 0);
}

// ---------------- conversions ----------------
__global__ void k_f2bf4(const float* __restrict__ x, unsigned short* __restrict__ y, int n4){
  int i=blockIdx.x*256+threadIdx.x; if(i>=n4) return;
  float4 v=((const float4*)x)[i];
  ushort4 r; r.x=f2bf(v.x); r.y=f2bf(v.y); r.z=f2bf(v.z); r.w=f2bf(v.w);
  ((ushort4*)y)[i]=r;
}
// W[K][N] f32 -> Wt[N][K] bf16, LDS 32x32 tile transpose (coalesced both sides)
__global__ __launch_bounds__(256) void k_wconv_t(
    const float* __restrict__ W, unsigned short* __restrict__ Wt, int K, int N){
  __shared__ float T[32][33];
  int k0=blockIdx.x*32, n0=blockIdx.y*32;
  int t=threadIdx.x, r=t>>3, c4=(t&7)*4;
  float4 a=*(const float4*)(W+(size_t)(k0+r)*N + n0+c4);
  T[r][c4]=a.x; T[r][c4+1]=a.y; T[r][c4+2]=a.z; T[r][c4+3]=a.w;
  __syncthreads();
  ushort4 w;
  w.x=f2bf(T[c4+0][r]); w.y=f2bf(T[c4+1][r]);
  w.z=f2bf(T[c4+2][r]); w.w=f2bf(T[c4+3][r]);
  *(ushort4*)(Wt+(size_t)(n0+r)*K + k0+c4)=w;
}

// ---------------- MFMA bf16 GEMM: 128x128 tile, BK=32, XCD swizzle -----------
// ASRC 0: A bf16 row-major (global_load_lds staging)
// ASRC 3: A bf16 head-major [bb][8][NPAD][64] (global_load_lds staging)
template<int MODE, int ASRC>
__global__ __launch_bounds__(256) void k_mfma_gemm(
    const void* __restrict__ Ap, const unsigned short* __restrict__ Bt,
    int M, int N, int K,
    const float* __restrict__ bias,
    void* __restrict__ o0, void* __restrict__ o1, void* __restrict__ o2)
{
  __shared__ __align__(16) unsigned short Sh[128*64];   // As=Sh[0..4095], Bs=Sh[4096..]
  int t=threadIdx.x;
  int bx=blockIdx.x, by=blockIdx.y;
  { // bijective XCD swizzle (grid size divisible by 8)
    int gx=gridDim.x; int wg=by*gx+bx; int nwg=gx*gridDim.y;
    int cpx=nwg>>3; int x2=(wg&7)*cpx+(wg>>3);
    by=x2/gx; bx=x2-by*gx;
  }
  int row0=by*128, col0=bx*128;
  int lane=t&63, w=t>>6, wr=w>>1, wc=w&1, lr=lane&15, kg=lane>>4;
  f32x4 acc[4][4];
  #pragma unroll
  for(int m=0;m<4;m++)
    #pragma unroll
    for(int n=0;n<4;n++) acc[m][n]=(f32x4){0.f,0.f,0.f,0.f};

  for(int k0=0;k0<K;k0+=32){
    __syncthreads();   // previous tile fully consumed
    #pragma unroll
    for(int i=0;i<2;i++){
      int flat=i*256+t, r=flat>>2, k8=flat&3;
      int kofs=k0+k8*8;
      const unsigned short* asrc;
      if constexpr(ASRC==0){
        asrc=(const unsigned short*)Ap+(size_t)(row0+r)*K+kofs;
      } else {
        int rr2=row0+r; int bb=rr2>>14, ri=rr2&16383;
        int head=kofs>>6, dd=kofs&63;
        asrc=(const unsigned short*)Ap + (((size_t)bb*NH+head)*NPAD+ri)*HD + dd;
      }
      gl16(asrc, Sh+(size_t)flat*8);
      gl16(Bt+(size_t)(col0+r)*K+kofs, Sh+4096+(size_t)flat*8);
    }
    __syncthreads();   // data ready (vmcnt/lgkm drained before barrier)
    short8v af[4], bf[4];
    #pragma unroll
    for(int m=0;m<4;m++) af[m]=*(const short8v*)(Sh+(wr*64+m*16+lr)*32 + kg*8);
    #pragma unroll
    for(int n=0;n<4;n++) bf[n]=*(const short8v*)(Sh+4096+(wc*64+n*16+lr)*32 + kg*8);
    #pragma unroll
    for(int m=0;m<4;m++)
      #pragma unroll
      for(int n=0;n<4;n++)
        acc[m][n]=__builtin_amdgcn_mfma_f32_16x16x32_bf16(af[m],bf[n],acc[m][n],0,0,0);
  }
  // ---- epilogue ----
  if constexpr(MODE==1){
    // coalesced q/k/v store via LDS restage (2 passes of 64 rows x 128 cols bf16)
    #pragma unroll
    for(int p=0;p<2;p++){
      __syncthreads();
      #pragma unroll
      for(int mm=0;mm<2;mm++){
        int m=2*p+mm;
        #pragma unroll
        for(int n=0;n<4;n++){
          int cc=wc*64+n*16+lr;
          int c=col0+cc;
          float sc=((c>>9)==0)?0.125f:1.f;
          #pragma unroll
          for(int j=0;j<4;j++){
            int lrow=wr*32+mm*16+kg*4+j;
            Sh[lrow*128+cc]=f2bf(acc[m][n][j]*sc);
          }
        }
      }
      __syncthreads();
      #pragma unroll
      for(int i=0;i<4;i++){
        int p2=i*256+t;
        int r2=p2>>4, ck=p2&15;
        int grow=row0+(r2>>5)*64+(2*p+((r2>>4)&1))*16+(r2&15);
        int bb=grow>>14, rr=grow&16383;
        int c=col0+ck*8;
        int which=c>>9, hcol=c&511, head=hcol>>6, dd=hcol&63;
        unsigned short* dst=(which==0)?(unsigned short*)o0:
                            (which==1)?(unsigned short*)o1:(unsigned short*)o2;
        *(short8v*)(dst + (((size_t)bb*NH+head)*NPAD+rr)*HD+dd) =
            *(const short8v*)(Sh + r2*128 + ck*8);
      }
    }
  } else {
    #pragma unroll
    for(int m=0;m<4;m++){
      int rbase=row0 + wr*64 + m*16 + kg*4;
      #pragma unroll
      for(int j=0;j<4;j++){
        int r=rbase+j;
        #pragma unroll
        for(int n=0;n<4;n++){
          int c=col0 + wc*64 + n*16 + lr;
          float val=acc[m][n][j];
          if(MODE==0){
            float* h=(float*)o0;
            int bb=(r>=16000)?1:0, ii=r-bb*16000;
            float vv=fmaxf(val+bias[c],0.f);
            h[((size_t)bb*NTOK + 1 + ii)*DM + c]=vv;
            if(ii<129) h[((size_t)bb*NTOK + 16001 + ii)*DM + c]=vv;
          } else {
            float* h=(float*)o0;
            int bb=r>>14, rr=r&16383;
            if(rr>=PADF)
              h[((size_t)bb*NTOK + (rr-PADF))*DM + c]+=val+bias[c];
          }
        }
      }
    }
  }
}

__global__ void k_cls(const float* __restrict__ cls, float* __restrict__ h){
  int t=blockIdx.x*256+threadIdx.x;
  if(t<2*DM) h[(size_t)(t>>9)*NTOK*DM + (t&511)]=cls[t&511];
}

// ---------------- layernorm + front zero-pad -> bf16, one wave per row ------
__global__ __launch_bounds__(256) void k_lnpad(
    const float* __restrict__ h, const float* __restrict__ g,
    const float* __restrict__ bta, unsigned short* __restrict__ xln)
{
  int wid=blockIdx.x*4+(threadIdx.x>>6);
  int lane=threadIdx.x&63;
  int bb=wid>>14, i=wid&16383;
  unsigned short* dst=xln+(size_t)wid*DM+lane*8;
  if(i<PADF){
    ushort4 z=(ushort4){0,0,0,0};
    *(ushort4*)dst=z; *(ushort4*)(dst+4)=z;
    return;
  }
  const float* src=h+((size_t)bb*NTOK + (i-PADF))*DM + lane*8;
  float4 v0=*(const float4*)src;
  float4 v1=*(const float4*)(src+4);
  float x[8]={v0.x,v0.y,v0.z,v0.w,v1.x,v1.y,v1.z,v1.w};
  float s=0.f;
  #pragma unroll
  for(int k=0;k<8;k++) s+=x[k];
  float mu=wred_sum(s)*(1.f/512.f);
  float d[8]; float vs=0.f;
  #pragma unroll
  for(int k=0;k<8;k++){ d[k]=x[k]-mu; vs+=d[k]*d[k]; }
  float rst=rsqrtf(wred_sum(vs)*(1.f/512.f)+1e-5f);
  float4 g0=*(const float4*)(g+lane*8),   g1=*(const float4*)(g+lane*8+4);
  float4 b0=*(const float4*)(bta+lane*8), b1=*(const float4*)(bta+lane*8+4);
  float gg[8]={g0.x,g0.y,g0.z,g0.w,g1.x,g1.y,g1.z,g1.w};
  float bb8[8]={b0.x,b0.y,b0.z,b0.w,b1.x,b1.y,b1.z,b1.w};
  ushort4 w0,w1;
  w0.x=f2bf(d[0]*rst*gg[0]+bb8[0]); w0.y=f2bf(d[1]*rst*gg[1]+bb8[1]);
  w0.z=f2bf(d[2]*rst*gg[2]+bb8[2]); w0.w=f2bf(d[3]*rst*gg[3]+bb8[3]);
  w1.x=f2bf(d[4]*rst*gg[4]+bb8[4]); w1.y=f2bf(d[5]*rst*gg[5]+bb8[5]);
  w1.z=f2bf(d[6]*rst*gg[6]+bb8[6]); w1.w=f2bf(d[7]*rst*gg[7]+bb8[7]);
  *(ushort4*)dst=w0; *(ushort4*)(dst+4)=w1;
}

// ---------------- landmark means, q and k in one launch ----------------
__global__ void k_lmean2(const unsigned short* __restrict__ qsrc,
                         const unsigned short* __restrict__ ksrc,
                         float* __restrict__ qlf, unsigned short* __restrict__ qlb_,
                         float* __restrict__ klf, unsigned short* __restrict__ klb_){
  int gid=blockIdx.x;
  const unsigned short* src; float* dstf; unsigned short* dstb;
  if(gid<4096){ src=qsrc; dstf=qlf; dstb=qlb_; }
  else        { src=ksrc; dstf=klf; dstb=klb_; gid-=4096; }
  int bh=gid>>8, s=gid&255, d=threadIdx.x;  // 64 threads
  const unsigned short* p=src + (((size_t)bh*NPAD)+s*SEG)*HD + d;
  float acc=0.f;
  #pragma unroll
  for(int l=0;l<SEG;l++) acc+=bf2f(p[(size_t)l*HD]);
  float m=acc*(1.f/64.f);
  dstf[((size_t)bh*LM+s)*HD+d]=m;
  dstb[((size_t)bh*LM+s)*HD+d]=f2bf(m);
}

// ---------------- v bf16 head-major -> vt bf16 [bh][64][NPAD] ----------------
__global__ __launch_bounds__(256) void k_vtrans(
    const unsigned short* __restrict__ v, unsigned short* __restrict__ vt)
{
  __shared__ unsigned short tile[64][72];
  int kt=blockIdx.x, bh=blockIdx.y;
  int t=threadIdx.x;
  int r=t>>2, sgq=t&3;
  const short8v* src=(const short8v*)(v + ((size_t)bh*NPAD + kt*64 + r)*HD + sgq*16);
  *(short8v*)(&tile[r][sgq*16])  =src[0];
  *(short8v*)(&tile[r][sgq*16+8])=src[1];
  __syncthreads();
  int d=t>>2;
  union{unsigned short u[16]; short8v v8[2];} pk;
  #pragma unroll
  for(int i=0;i<16;i++) pk.u[i]=tile[sgq*16+i][d];
  short8v* dst=(short8v*)(vt + ((size_t)bh*HD + d)*NPAD + kt*64 + sgq*16);
  dst[0]=pk.v8[0]; dst[1]=pk.v8[1];
}

// ---------------- attn2 = softmax(ql @ kl^T) f32 + fused hi/lo split --------
__global__ __launch_bounds__(256) void k_attn2(
    const float* __restrict__ ql, const float* __restrict__ kl,
    float* __restrict__ attn2,
    unsigned short* __restrict__ a2h, unsigned short* __restrict__ a2l)
{
  __shared__ float qrow[64]; __shared__ float s4[4];
  int bh=blockIdx.x>>8, i=blockIdx.x&255, j=threadIdx.x;
  if(j<64) qrow[j]=ql[((size_t)bh*LM+i)*HD+j];
  __syncthreads();
  const float* kp=kl+((size_t)bh*LM+j)*HD;
  float l=0.f;
  #pragma unroll
  for(int d=0;d<64;d++) l+=qrow[d]*kp[d];
  float m=block_max256(l,s4);
  float e=__expf(l-m);
  float s=block_sum256(e,s4);
  float pv=e/s;
  size_t o=((size_t)bh*LM+i)*LM+j;
  attn2[o]=pv;
  unsigned short hh=f2bf(pv);
  a2h[o]=hh; a2l[o]=f2bf(pv-bf2f(hh));
}

// ---------------- pinv helpers (rowsum of softmax == 1, skip it) ------------
// two-stage colsum: partials into scratch (pacc), then combine
__global__ void k_colsumA(const float* __restrict__ x, float* __restrict__ partial){
  int bh=blockIdx.y, ic=blockIdx.x, j=threadIdx.x;
  const float* p=x+(size_t)bh*65536+(size_t)ic*16*256;
  float s=0.f;
  #pragma unroll
  for(int i=0;i<16;i++) s+=p[(size_t)i*256+j];
  partial[((size_t)bh*16+ic)*256+j]=s;
}
__global__ void k_colsumB(const float* __restrict__ partial, float* __restrict__ cs){
  int bh=blockIdx.x, j=threadIdx.x;
  float s=0.f;
  #pragma unroll
  for(int ic=0;ic<16;ic++) s+=partial[((size_t)bh*16+ic)*256+j];
  cs[bh*256+j]=s;
}
__global__ void k_pinvscale(const float* __restrict__ cs, float* __restrict__ scale){
  __shared__ float s4[4];
  float mc=-1e30f;
  for(int i=threadIdx.x;i<4096;i+=256) mc=fmaxf(mc,cs[i]);
  mc=block_max256(mc,s4);
  if(threadIdx.x==0) scale[0]=1.f/mc;
}
// z0 init via dual 32x32 LDS tile transpose (all reads/writes coalesced)
__global__ __launch_bounds__(256) void k_zinit_hl(
    const float* __restrict__ x, const float* __restrict__ scale,
    unsigned short* __restrict__ zh, unsigned short* __restrict__ zl,
    unsigned short* __restrict__ zth, unsigned short* __restrict__ ztl){
  __shared__ float T1[32][33], T2[32][33];
  int bh=blockIdx.x>>6, tile=blockIdx.x&63;
  int i0=(tile>>3)*32, j0=(tile&7)*32;
  int t=threadIdx.x, r=t>>3, c4=(t&7)*4;
  size_t base=(size_t)bh*65536;
  float4 a=*(const float4*)(x+base+(size_t)(i0+r)*256+j0+c4);
  float4 b=*(const float4*)(x+base+(size_t)(j0+r)*256+i0+c4);
  T1[r][c4]=a.x; T1[r][c4+1]=a.y; T1[r][c4+2]=a.z; T1[r][c4+3]=a.w;
  T2[r][c4]=b.x; T2[r][c4+1]=b.y; T2[r][c4+2]=b.z; T2[r][c4+3]=b.w;
  __syncthreads();
  float s=scale[0];
  size_t o=base+(size_t)(i0+r)*256+j0+c4;
  ushort4 nh,nl,th,tl;
  {
    float vn, vt; unsigned short hh;
    vn=T2[c4+0][r]*s; hh=f2bf(vn); nh.x=hh; nl.x=f2bf(vn-bf2f(hh));
    vn=T2[c4+1][r]*s; hh=f2bf(vn); nh.y=hh; nl.y=f2bf(vn-bf2f(hh));
    vn=T2[c4+2][r]*s; hh=f2bf(vn); nh.z=hh; nl.z=f2bf(vn-bf2f(hh));
    vn=T2[c4+3][r]*s; hh=f2bf(vn); nh.w=hh; nl.w=f2bf(vn-bf2f(hh));
    vt=T1[r][c4+0]*s; hh=f2bf(vt); th.x=hh; tl.x=f2bf(vt-bf2f(hh));
    vt=T1[r][c4+1]*s; hh=f2bf(vt); th.y=hh; tl.y=f2bf(vt-bf2f(hh));
    vt=T1[r][c4+2]*s; hh=f2bf(vt); th.z=hh; tl.z=f2bf(vt-bf2f(hh));
    vt=T1[r][c4+3]*s; hh=f2bf(vt); th.w=hh; tl.w=f2bf(vt-bf2f(hh));
  }
  *(ushort4*)(zh+o)=nh; *(ushort4*)(zl+o)=nl;
  *(ushort4*)(zth+o)=th; *(ushort4*)(ztl+o)=tl;
}

// ---------------- hi/lo split bf16 MFMA batched GEMM (pinv chain) -----------
// Tile 32(M)x64(N), BK=128, 2 k-steps, grid 512 blocks (2/CU)
// MODE 0: C=A@B (emit normal+trans)    MODE 1: C=15I-7X+acc (trans only)
// MODE 2: C=13I-acc (trans only)       MODE 3: C=0.25*acc (normal+trans)
// MODE 4: C=acc (trans only, hi only; Ndim=64)
// PREC 0: single bf16 product; PREC 1: hi/lo 3-product (f32-equivalent)
template<int MODE, int PREC>
__global__ __launch_bounds__(256) void k_bmm3(
    const unsigned short* __restrict__ Ah, const unsigned short* __restrict__ Al,
    const unsigned short* __restrict__ Bth, const unsigned short* __restrict__ Btl,
    const unsigned short* __restrict__ Xh, const unsigned short* __restrict__ Xl,
    unsigned short* __restrict__ Cnh, unsigned short* __restrict__ Cnl,
    unsigned short* __restrict__ Cth, unsigned short* __restrict__ Ctl,
    int Ndim)
{
  __shared__ unsigned short AsH[32*136], BsH[64*136];
  __shared__ unsigned short AsL[PREC?32*136:8], BsL[PREC?64*136:8];
  int bh=blockIdx.z;
  int n0=blockIdx.x*64, m0=blockIdx.y*32;
  int t=threadIdx.x, lane=t&63, w=t>>6;
  int c=lane&15, g=lane>>4;
  int wr=(w>>1)*16, wc=(w&1)*32;
  f32x4 acc[2];
  acc[0]=(f32x4){0.f,0.f,0.f,0.f};
  acc[1]=(f32x4){0.f,0.f,0.f,0.f};
  size_t Abase=(size_t)bh*65536;
  size_t Bbase=(size_t)bh*(size_t)Ndim*256;
  int r=t>>3, k16=(t&7)*16;
  const unsigned short* ApH =Ah +Abase+(size_t)(m0+r)*256+k16;
  const unsigned short* BpH0=Bth+Bbase+(size_t)(n0+r)*256+k16;
  const unsigned short* BpH1=Bth+Bbase+(size_t)(n0+32+r)*256+k16;
  const unsigned short* ApL =Al +Abase+(size_t)(m0+r)*256+k16;
  const unsigned short* BpL0=Btl+Bbase+(size_t)(n0+r)*256+k16;
  const unsigned short* BpL1=Btl+Bbase+(size_t)(n0+32+r)*256+k16;
  short8v rah[2],rbh0[2],rbh1[2], ral[2],rbl0[2],rbl1[2];
  #pragma unroll
  for(int i=0;i<2;i++){
    rah[i] =*(const short8v*)(ApH +i*8);
    rbh0[i]=*(const short8v*)(BpH0+i*8);
    rbh1[i]=*(const short8v*)(BpH1+i*8);
    if constexpr(PREC==1){
      ral[i] =*(const short8v*)(ApL +i*8);
      rbl0[i]=*(const short8v*)(BpL0+i*8);
      rbl1[i]=*(const short8v*)(BpL1+i*8);
    }
  }
  int k0=0;
  for(;;){
    __syncthreads();
    #pragma unroll
    for(int i=0;i<2;i++){
      *(short8v*)(AsH + r*136 + k16 + i*8)=rah[i];
      *(short8v*)(BsH + r*136 + k16 + i*8)=rbh0[i];
      *(short8v*)(BsH + (r+32)*136 + k16 + i*8)=rbh1[i];
      if constexpr(PREC==1){
        *(short8v*)(AsL + r*136 + k16 + i*8)=ral[i];
        *(short8v*)(BsL + r*136 + k16 + i*8)=rbl0[i];
        *(short8v*)(BsL + (r+32)*136 + k16 + i*8)=rbl1[i];
      }
    }
    __syncthreads();
    int kn=k0+128;
    if(kn<256){
      #pragma unroll
      for(int i=0;i<2;i++){
        rah[i] =*(const short8v*)(ApH +kn+i*8);
        rbh0[i]=*(const short8v*)(BpH0+kn+i*8);
        rbh1[i]=*(const short8v*)(BpH1+kn+i*8);
        if constexpr(PREC==1){
          ral[i] =*(const short8v*)(ApL +kn+i*8);
          rbl0[i]=*(const short8v*)(BpL0+kn+i*8);
          rbl1[i]=*(const short8v*)(BpL1+kn+i*8);
        }
      }
    }
    #pragma unroll
    for(int ks=0;ks<4;ks++){
      short8v af=*(const short8v*)(AsH+(wr+c)*136 + ks*32 + g*8);
      short8v alf;
      if constexpr(PREC==1) alf=*(const short8v*)(AsL+(wr+c)*136 + ks*32 + g*8);
      #pragma unroll
      for(int nt=0;nt<2;nt++){
        short8v bf=*(const short8v*)(BsH+(wc+nt*16+c)*136 + ks*32 + g*8);
        acc[nt]=__builtin_amdgcn_mfma_f32_16x16x32_bf16(af,bf,acc[nt],0,0,0);
        if constexpr(PREC==1){
          short8v blf=*(const short8v*)(BsL+(wc+nt*16+c)*136 + ks*32 + g*8);
          acc[nt]=__builtin_amdgcn_mfma_f32_16x16x32_bf16(af,blf,acc[nt],0,0,0);
          acc[nt]=__builtin_amdgcn_mfma_f32_16x16x32_bf16(alf,bf,acc[nt],0,0,0);
        }
      }
    }
    if(kn>=256) break;
    k0=kn;
  }
  int rb=m0+wr+g*4;
  #pragma unroll
  for(int nt=0;nt<2;nt++){
    int cc=n0+wc+nt*16+c;
    float vv[4];
    #pragma unroll
    for(int j=0;j<4;j++){
      float a=acc[nt][j];
      int rr=rb+j;
      if(MODE==1){
        float xv=bf2f(Xh[Abase+(size_t)rr*256+cc])+bf2f(Xl[Abase+(size_t)rr*256+cc]);
        a=(rr==cc?15.f:0.f)-7.f*xv+a;
      } else if(MODE==2){
        a=(rr==cc?13.f:0.f)-a;
      } else if(MODE==3){
        a*=0.25f;
      }
      vv[j]=a;
    }
    if(MODE==0||MODE==3){
      #pragma unroll
      for(int j=0;j<4;j++){
        unsigned short hh=f2bf(vv[j]);
        Cnh[Abase+(size_t)(rb+j)*256+cc]=hh;
        Cnl[Abase+(size_t)(rb+j)*256+cc]=f2bf(vv[j]-bf2f(hh));
      }
    }
    {
      ushort4 hv, lv;
      hv.x=f2bf(vv[0]); hv.y=f2bf(vv[1]); hv.z=f2bf(vv[2]); hv.w=f2bf(vv[3]);
      lv.x=f2bf(vv[0]-bf2f(hv.x)); lv.y=f2bf(vv[1]-bf2f(hv.y));
      lv.z=f2bf(vv[2]-bf2f(hv.z)); lv.w=f2bf(vv[3]-bf2f(hv.w));
      size_t co=((size_t)bh*Ndim+cc)*256+rb;
      *(ushort4*)(Cth+co)=hv;
      if(MODE!=4) *(ushort4*)(Ctl+co)=lv;
    }
  }
}

// ---------------- attn3@v : MFMA flash, split-K 16 chunks x 2 row-halves -----
__global__ __launch_bounds__(512) void k_attn3m(
    const unsigned short* __restrict__ qlb,
    const unsigned short* __restrict__ kb,
    const unsigned short* __restrict__ vtb,
    float* __restrict__ pacc, float* __restrict__ pms)
{
  __shared__ unsigned short Ks[64*72];
  __shared__ unsigned short Vs[64*72];
  int ck=blockIdx.x, rh=blockIdx.y, bh=blockIdx.z;
  int t=threadIdx.x, lane=t&63, w=t>>6;
  int c=lane&15, g=lane>>4;
  int qrow0=rh*128 + w*16;          // this wave's 16 q-rows: qrow0 + c
  short8v Qf[2];
  #pragma unroll
  for(int kw=0;kw<2;kw++)
    Qf[kw]=*(const short8v*)(qlb + ((size_t)bh*LM + qrow0 + c)*HD + kw*32 + g*8);
  f32x4 accO[4];
  float mrun=-3e38f, srun=0.f;
  #pragma unroll
  for(int d=0;d<4;d++) accO[d]=(f32x4){0.f,0.f,0.f,0.f};
  int sr=t>>3, sgk=t&7;
  for(int sc=0;sc<16;++sc){
    int key0=ck*1024 + sc*64;
    __syncthreads();
    *(short8v*)(Ks + sr*72 + sgk*8) =
      *(const short8v*)(kb + ((size_t)bh*NPAD + key0 + sr)*HD + sgk*8);
    *(short8v*)(Vs + sr*72 + sgk*8) =
      *(const short8v*)(vtb + ((size_t)bh*HD + sr)*NPAD + key0 + sgk*8);
    __syncthreads();
    f32x4 s[4];
    #pragma unroll
    for(int mt=0;mt<4;mt++){
      short8v a0=*(const short8v*)(Ks + (mt*16+c)*72 + g*8);
      short8v a1=*(const short8v*)(Ks + (mt*16+c)*72 + 32 + g*8);
      f32x4 z=(f32x4){0.f,0.f,0.f,0.f};
      z=__builtin_amdgcn_mfma_f32_16x16x32_bf16(a0,Qf[0],z,0,0,0);
      z=__builtin_amdgcn_mfma_f32_16x16x32_bf16(a1,Qf[1],z,0,0,0);
      s[mt]=z;
    }
    unsigned U[4][2];
    {
      float cm=-3e38f;
      #pragma unroll
      for(int mt=0;mt<4;mt++)
        #pragma unroll
        for(int j=0;j<4;j++) cm=fmaxf(cm,s[mt][j]);
      cm=fmaxf(cm,__shfl_xor(cm,16));
      cm=fmaxf(cm,__shfl_xor(cm,32));
      float mnew=fmaxf(mrun,cm);
      float f=__expf(mrun-mnew);
      mrun=mnew;
      float ps=0.f;
      #pragma unroll
      for(int mt=0;mt<4;mt++){
        float p0=__expf(s[mt][0]-mnew);
        float p1=__expf(s[mt][1]-mnew);
        float p2=__expf(s[mt][2]-mnew);
        float p3=__expf(s[mt][3]-mnew);
        ps+=p0+p1+p2+p3;
        U[mt][0]=cvtpk(p0,p1);
        U[mt][1]=cvtpk(p2,p3);
      }
      ps+=__shfl_xor(ps,16); ps+=__shfl_xor(ps,32);
      srun=srun*f+ps;
      #pragma unroll
      for(int d=0;d<4;d++){
        accO[d][0]*=f; accO[d][1]*=f; accO[d][2]*=f; accO[d][3]*=f;
      }
    }
    #pragma unroll
    for(int kw=0;kw<2;kw++){
      union{unsigned u[4]; short8v v;} pk;
      #pragma unroll
      for(int wd=0;wd<4;wd++){
        int sl=c+16*(((g&1)<<1)+(wd>>1));
        unsigned va=(unsigned)__shfl((int)U[kw*2  ][wd&1],sl);
        unsigned vb=(unsigned)__shfl((int)U[kw*2+1][wd&1],sl);
        pk.u[wd]=(lane>=32)?vb:va;
      }
      #pragma unroll
      for(int d=0;d<4;d++){
        short8v vf=*(const short8v*)(Vs + (d*16+c)*72 + kw*32 + g*8);
        accO[d]=__builtin_amdgcn_mfma_f32_16x16x32_bf16(vf,pk.v,accO[d],0,0,0);
      }
    }
  }
  size_t pb=((size_t)bh*16+ck)*LM;
  int q=qrow0+c;
  #pragma unroll
  for(int d=0;d<4;d++)
    *(f32x4*)(pacc + (pb+q)*HD + d*16 + g*4)=accO[d];
  if(g==0){ pms[(pb+q)*2]=mrun; pms[(pb+q)*2+1]=srun; }
}
__global__ __launch_bounds__(256) void k_attn3vc(
    const float* __restrict__ pacc, const float* __restrict__ pms,
    unsigned short* __restrict__ a3vth, unsigned short* __restrict__ a3vtl)
{
  int gid=blockIdx.x*4+(threadIdx.x>>6);
  int bh=gid>>8, row=gid&255, lane=threadIdx.x&63;
  float M=-3e38f;
  float ms[16], ss[16];
  #pragma unroll
  for(int c=0;c<16;c++){
    size_t pb=((size_t)bh*16+c)*LM+row;
    ms[c]=pms[pb*2]; ss[c]=pms[pb*2+1];
    M=fmaxf(M,ms[c]);
  }
  float S=0.f,a=0.f;
  #pragma unroll
  for(int c=0;c<16;c++){
    float f=__expf(ms[c]-M);
    S+=ss[c]*f;
    a+=pacc[(((size_t)bh*16+c)*LM+row)*HD+lane]*f;
  }
  float v=a/S;
  unsigned short hi=f2bf(v);
  a3vth[((size_t)bh*HD+lane)*LM+row]=hi;
  a3vtl[((size_t)bh*HD+lane)*LM+row]=f2bf(v-bf2f(hi));
}

// ---------------- attn1 @ W2 : MFMA, 256 landmarks one-shot; bf16 out --------
__global__ __launch_bounds__(512) void k_attn1m(
    const unsigned short* __restrict__ qb,
    const unsigned short* __restrict__ klb,
    const unsigned short* __restrict__ w2t,
    unsigned short* __restrict__ aohb)
{
  __shared__ unsigned short klS[256*72];
  __shared__ unsigned short w2S[64*264];
  int qt=blockIdx.x, bh=blockIdx.y;
  int t=threadIdx.x, lane=t&63, w=t>>6;
  int c=lane&15, g=lane>>4;
  {
    int r=t>>1, hf=t&1;
    const short8v* s=(const short8v*)(klb + ((size_t)bh*LM+r)*HD + hf*32);
    short8v* d=(short8v*)(klS + r*72 + hf*32);
    d[0]=s[0]; d[1]=s[1]; d[2]=s[2]; d[3]=s[3];
    int r2=t>>3, sg2=t&7;
    const short8v* s2=(const short8v*)(w2t + ((size_t)bh*HD+r2)*LM + sg2*32);
    short8v* d2=(short8v*)(w2S + r2*264 + sg2*32);
    d2[0]=s2[0]; d2[1]=s2[1]; d2[2]=s2[2]; d2[3]=s2[3];
  }
  __syncthreads();
  int q0=qt*256 + w*32;
  #pragma unroll
  for(int n=0;n<2;n++){
    const unsigned short* qrow=qb + ((size_t)bh*NPAD + q0 + n*16 + c)*HD;
    short8v qf0=*(const short8v*)(qrow + g*8);
    short8v qf1=*(const short8v*)(qrow + 32 + g*8);
    f32x4 s[16];
    #pragma unroll
    for(int mt=0;mt<16;mt++){
      short8v a0=*(const short8v*)(klS + (mt*16+c)*72 + g*8);
      short8v a1=*(const short8v*)(klS + (mt*16+c)*72 + 32 + g*8);
      f32x4 z=(f32x4){0.f,0.f,0.f,0.f};
      z=__builtin_amdgcn_mfma_f32_16x16x32_bf16(a0,qf0,z,0,0,0);
      z=__builtin_amdgcn_mfma_f32_16x16x32_bf16(a1,qf1,z,0,0,0);
      s[mt]=z;
    }
    float M=-3e38f;
    #pragma unroll
    for(int mt=0;mt<16;mt++)
      #pragma unroll
      for(int j=0;j<4;j++) M=fmaxf(M,s[mt][j]);
    M=fmaxf(M,__shfl_xor(M,16));
    M=fmaxf(M,__shfl_xor(M,32));
    float sum=0.f;
    unsigned U[16][2];
    #pragma unroll
    for(int mt=0;mt<16;mt++){
      float p0=__expf(s[mt][0]-M);
      float p1=__expf(s[mt][1]-M);
      float p2=__expf(s[mt][2]-M);
      float p3=__expf(s[mt][3]-M);
      sum+=p0+p1+p2+p3;
      U[mt][0]=cvtpk(p0,p1);
      U[mt][1]=cvtpk(p2,p3);
    }
    sum+=__shfl_xor(sum,16); sum+=__shfl_xor(sum,32);
    float inv=1.f/sum;
    f32x4 accO[4];
    #pragma unroll
    for(int d=0;d<4;d++) accO[d]=(f32x4){0.f,0.f,0.f,0.f};
    #pragma unroll
    for(int kw=0;kw<8;kw++){
      union{unsigned u[4]; short8v v;} pk;
      #pragma unroll
      for(int wd=0;wd<4;wd++){
        int sl=c+16*(((g&1)<<1)+(wd>>1));
        unsigned va=(unsigned)__shfl((int)U[kw*2  ][wd&1],sl);
        unsigned vb=(unsigned)__shfl((int)U[kw*2+1][wd&1],sl);
        pk.u[wd]=(lane>=32)?vb:va;
      }
      #pragma unroll
      for(int d=0;d<4;d++){
        short8v vf=*(const short8v*)(w2S + (d*16+c)*264 + kw*32 + g*8);
        accO[d]=__builtin_amdgcn_mfma_f32_16x16x32_bf16(vf,pk.v,accO[d],0,0,0);
      }
    }
    int q=q0+n*16+c;
    #pragma unroll
    for(int d=0;d<4;d++){
      f32x4 o=accO[d];
      uint2 pk2;
      pk2.x=cvtpk(o[0]*inv, o[1]*inv);
      pk2.y=cvtpk(o[2]*inv, o[3]*inv);
      *(uint2*)(aohb + ((size_t)bh*NPAD+q)*HD + d*16 + g*4)=pk2;
    }
  }
}

// ---------------- depthwise 33-tap conv from vt; aoh bf16 += -----------------
__global__ __launch_bounds__(256) void k_resconv2(
    const unsigned short* __restrict__ vt, const float* __restrict__ rw,
    unsigned short* __restrict__ aohb){
  int bx=blockIdx.x, bh=blockIdx.y;
  int t=threadIdx.x, d=t&63, g=t>>6;
  int i0=bx*32+g*8;
  int hh=bh&7;
  const unsigned short* vr=vt + ((size_t)bh*HD + d)*NPAD;
  float wv[40];
  int start=i0-16;
  if(start>=0 && start+40<=NPAD){
    #pragma unroll
    for(int b=0;b<5;b++){
      short8v v8=*(const short8v*)(vr+start+b*8);
      #pragma unroll
      for(int j=0;j<8;j++) wv[b*8+j]=bf2f((unsigned short)v8[j]);
    }
  } else {
    #pragma unroll
    for(int t2=0;t2<40;t2++){
      int src=start+t2;
      wv[t2]=(src>=0&&src<NPAD)?bf2f(vr[src]):0.f;
    }
  }
  const float* wt=rw+hh*33;
  #pragma unroll
  for(int p=0;p<8;p++){
    float a=0.f;
    #pragma unroll
    for(int tk=0;tk<33;tk++) a+=wv[p+tk]*wt[tk];
    size_t o=((size_t)bh*NPAD+i0+p)*HD+d;
    aohb[o]=f2bf(bf2f(aohb[o])+a);
  }
}

// ---------------- PPEG weight prep: combined 7x7 tap table (bf16) -----------
__global__ void k_wprep(const float* __restrict__ w7, const float* __restrict__ b7,
                        const float* __restrict__ w5, const float* __restrict__ b5,
                        const float* __restrict__ w3, const float* __restrict__ b3,
                        unsigned short* __restrict__ wcat){
  int t=blockIdx.x*256+threadIdx.x;
  if(t>=50*512) return;
  int r=t>>9, c=t&511;
  float v;
  if(r<49){
    int ky=r/7, kx=r%7;
    v=w7[(size_t)c*49+r];
    if(ky>=1&&ky<=5&&kx>=1&&kx<=5) v+=w5[(size_t)c*25+(ky-1)*5+(kx-1)];
    if(ky>=2&&ky<=4&&kx>=2&&kx<=4) v+=w3[(size_t)c*9+(ky-2)*3+(kx-2)];
  } else {
    v=b7[c]+b5[c]+b3[c];
  }
  wcat[t]=f2bf(v);
}

// ---------------- PPEG: 8x8 tile x 32ch, [ch][pos] patch, packed-f32 FMA ----
__global__ __launch_bounds__(256,4) void k_ppeg4(
    const float* __restrict__ src, const unsigned short* __restrict__ wcat,
    float* __restrict__ dst)
{
  __shared__ float patch[32][198];   // [ch][14x14 halo + pad2] (same 31744B total)
  __shared__ float wsf[50][32];
  int bx=blockIdx.x;
  int cz=blockIdx.y, bb=blockIdx.z;
  int t=threadIdx.x, c=t&31, g=t>>5;   // 32ch x 8 groups
  int ty0=(bx>>4)*8, tx0=(bx&15)*8;
  const float* base=src+((size_t)bb*NTOK+1)*DM + cz*32 + c;
  #pragma unroll
  for(int i=0;i<25;i++){
    int p=g+8*i;
    if(p<196){
      int py=p/14, px=p%14;
      int yy=ty0-3+py, xx=tx0-3+px;
      float v=0.f;
      if(yy>=0&&yy<127&&xx>=0&&xx<127) v=base[(size_t)(yy*127+xx)*DM];
      patch[c][p]=v;
    }
  }
  #pragma unroll
  for(int i=0;i<7;i++){
    int r=g+8*i; if(r<50) wsf[r][c]=bf2f(wcat[(size_t)r*DM + cz*32 + c]);
  }
  __syncthreads();
  float bias=wsf[49][c];
  f32x2 acc2[4];
  #pragma unroll
  for(int j=0;j<4;j++){
    acc2[j][0]=patch[c][(g+3)*14+(j+3)]+bias;   // exact identity
    acc2[j][1]=patch[c][(g+3)*14+(j+7)]+bias;
  }
  #pragma unroll
  for(int ky=0;ky<7;ky++){
    float win[14];
    #pragma unroll
    for(int x2=0;x2<7;x2++){
      f32x2 wp=*(const f32x2*)(&patch[c][(g+ky)*14+2*x2]);  // 8B-aligned (even offs)
      win[2*x2]=wp[0]; win[2*x2+1]=wp[1];
    }
    #pragma unroll
    for(int kx=0;kx<7;kx++){
      float wv=wsf[ky*7+kx][c];
      f32x2 w2={wv,wv};
      #pragma unroll
      for(int j=0;j<4;j++){
        f32x2 v2={win[j+kx],win[j+4+kx]};
        acc2[j]=__builtin_elementwise_fma(v2,w2,acc2[j]);  // v_pk_fma_f32
      }
    }
  }
  int y=ty0+g;
  if(y<127){
    #pragma unroll
    for(int j=0;j<4;j++){
      int x=tx0+j;
      if(x<127)
        dst[((size_t)bb*NTOK+1+(size_t)(y*127+x))*DM + cz*32 + c]=acc2[j][0];
      int x4=tx0+j+4;
      if(x4<127)
        dst[((size_t)bb*NTOK+1+(size_t)(y*127+x4))*DM + cz*32 + c]=acc2[j][1];
    }
  }
}

// copy cls row h -> dst
__global__ void k_cpcls(const float* __restrict__ h, float* __restrict__ dst){
  int t=blockIdx.x*256+threadIdx.x;
  if(t<2*DM) dst[(size_t)(t>>9)*NTOK*DM + (t&511)]=h[(size_t)(t>>9)*NTOK*DM + (t&511)];
}

// ---------------- final: LN(h[:,0]) @ fc2 + b ----------------
__global__ __launch_bounds__(256) void k_final(
    const float* __restrict__ h, const float* __restrict__ g, const float* __restrict__ bta,
    const float* __restrict__ w, const float* __restrict__ fb, float* __restrict__ out)
{
  int bb=blockIdx.x, t=threadIdx.x;
  const float* src=h+(size_t)bb*NTOK*DM;
  float x0=src[t], x1=src[t+256];
  __shared__ float s4[4];
  float mu=block_sum256(x0+x1,s4)*(1.f/512.f);
  float d0=x0-mu, d1=x1-mu;
  float var=block_sum256(d0*d0+d1*d1,s4)*(1.f/512.f);
  float rst=rsqrtf(var+1e-5f);
  float y0=d0*rst*g[t]+bta[t], y1=d1*rst*g[t+256]+bta[t+256];
  float dot=block_sum256(y0*w[t]+y1*w[t+256],s4);
  if(t==0) out[bb]=dot+fb[0];
}

// =======================================================================
extern "C" void kernel_launch(void* const* d_in, const int* in_sizes, int n_in,
                              void* d_out, int out_size, void* d_ws, size_t ws_size,
                              hipStream_t stream){
  (void)in_sizes; (void)n_in; (void)out_size; (void)ws_size;
  const float* features=(const float*)d_in[0];
  const float* fc1_w  =(const float*)d_in[1];
  const float* fc1_b  =(const float*)d_in[2];
  const float* cls_tok=(const float*)d_in[3];
  const float* fc2_w  =(const float*)d_in[24];
  const float* fc2_b  =(const float*)d_in[25];
  float* out=(float*)d_out;

  char* wp=(char*)d_ws;
  auto allocB=[&](size_t bytes)->char*{
    char* p=wp; wp+=((bytes+255)/256)*256; return p;
  };
  float* h    =(float*)allocB((size_t)NB*NTOK*DM*4);
  float* h2   =(float*)allocB((size_t)NB*NTOK*DM*4);
  unsigned short* vb  =(unsigned short*)allocB((size_t)NB*NPAD*DM*2);
  unsigned short* xlnb=(unsigned short*)allocB((size_t)NB*NPAD*DM*2);
  unsigned short* qb  =(unsigned short*)allocB((size_t)NB*NPAD*DM*2);
  unsigned short* kb  =(unsigned short*)allocB((size_t)NB*NPAD*DM*2);
  unsigned short* vtb =(unsigned short*)allocB((size_t)NB*NPAD*DM*2);
  unsigned short* aohb=(unsigned short*)allocB((size_t)NB*NPAD*DM*2);
  unsigned short* wtf=(unsigned short*)allocB((size_t)512*1024*2);
  unsigned short* wtq=(unsigned short*)allocB((size_t)1536*512*2);
  unsigned short* wtp=(unsigned short*)allocB((size_t)512*512*2);
  float* ql =(float*)allocB((size_t)16*LM*HD*4);
  float* kl =(float*)allocB((size_t)16*LM*HD*4);
  unsigned short* qlb=(unsigned short*)allocB((size_t)16*LM*HD*2);
  unsigned short* klb=(unsigned short*)allocB((size_t)16*LM*HD*2);
  float* attn2=(float*)allocB((size_t)16*LM*LM*4);
  unsigned short* a2h=(unsigned short*)allocB((size_t)16*LM*LM*2);
  unsigned short* a2l=(unsigned short*)allocB((size_t)16*LM*LM*2);
  unsigned short* zb[8];
  for(int i=0;i<8;i++) zb[i]=(unsigned short*)allocB((size_t)16*LM*LM*2);
  unsigned short* Abh=(unsigned short*)allocB((size_t)16*LM*LM*2);
  unsigned short* Abl=(unsigned short*)allocB((size_t)16*LM*LM*2);
  unsigned short* Abth=(unsigned short*)allocB((size_t)16*LM*LM*2);
  unsigned short* Abtl=(unsigned short*)allocB((size_t)16*LM*LM*2);
  unsigned short* Ubth=(unsigned short*)allocB((size_t)16*LM*LM*2);
  unsigned short* Ubtl=(unsigned short*)allocB((size_t)16*LM*LM*2);
  unsigned short* Tbth=(unsigned short*)allocB((size_t)16*LM*LM*2);
  unsigned short* Tbtl=(unsigned short*)allocB((size_t)16*LM*LM*2);
  unsigned short* a3vth=(unsigned short*)allocB((size_t)16*HD*LM*2);
  unsigned short* a3vtl=(unsigned short*)allocB((size_t)16*HD*LM*2);
  unsigned short* w2t=(unsigned short*)allocB((size_t)16*HD*LM*2);
  float* pacc=(float*)allocB((size_t)16*16*LM*HD*4);
  float* pms =(float*)allocB((size_t)16*16*LM*2*4);
  float* cs  =(float*)allocB(4096*4);
  float* scl =(float*)allocB(64*4);

  auto nystrom=[&](float* hbuf, const float* ng, const float* nbias, const float* qkvw,
                   const float* outw, const float* outb, const float* resw){
    k_lnpad<<<NB*NPAD/4,256,0,stream>>>(hbuf, ng, nbias, xlnb);
    k_wconv_t<<<dim3(16,48),256,0,stream>>>(qkvw, wtq, 512, 1536);
    k_mfma_gemm<1,0><<<dim3(12,256),256,0,stream>>>(xlnb, wtq, 32768,1536,512,
                                                    nullptr, qb, kb, vb);
    k_lmean2<<<8192,64,0,stream>>>(qb, kb, ql, qlb, kl, klb);
    k_vtrans<<<dim3(256,16),256,0,stream>>>(vb, vtb);
    k_attn2<<<4096,256,0,stream>>>(ql, kl, attn2, a2h, a2l);
    k_colsumA<<<dim3(16,16),256,0,stream>>>(attn2, pacc);
    k_colsumB<<<16,256,0,stream>>>(pacc, cs);
    k_pinvscale<<<1,256,0,stream>>>(cs, scl);
    k_zinit_hl<<<1024,256,0,stream>>>(attn2, scl, zb[0],zb[1],zb[2],zb[3]);
    unsigned short *zch=zb[0],*zcl=zb[1],*zcth=zb[2],*zctl=zb[3];
    unsigned short *znh=zb[4],*znl=zb[5],*znth=zb[6],*zntl=zb[7];
    for(int it=0;it<6;it++){
      if(it<5){
        k_bmm3<0,0><<<dim3(4,8,16),256,0,stream>>>(a2h,a2l, zcth,zctl, nullptr,nullptr,
                                                   Abh,Abl, Abth,Abtl, 256);
        k_bmm3<1,0><<<dim3(4,8,16),256,0,stream>>>(Abh,Abl, Abth,Abtl, Abh,Abl,
                                                   nullptr,nullptr, Ubth,Ubtl, 256);
        k_bmm3<2,0><<<dim3(4,8,16),256,0,stream>>>(Abh,Abl, Ubth,Ubtl, nullptr,nullptr,
                                                   nullptr,nullptr, Tbth,Tbtl, 256);
        k_bmm3<3,0><<<dim3(4,8,16),256,0,stream>>>(zch,zcl, Tbth,Tbtl, nullptr,nullptr,
                                                   znh,znl, znth,zntl, 256);
      } else {
        k_bmm3<0,1><<<dim3(4,8,16),256,0,stream>>>(a2h,a2l, zcth,zctl, nullptr,nullptr,
                                                   Abh,Abl, Abth,Abtl, 256);
        k_bmm3<1,1><<<dim3(4,8,16),256,0,stream>>>(Abh,Abl, Abth,Abtl, Abh,Abl,
                                                   nullptr,nullptr, Ubth,Ubtl, 256);
        k_bmm3<2,1><<<dim3(4,8,16),256,0,stream>>>(Abh,Abl, Ubth,Ubtl, nullptr,nullptr,
                                                   nullptr,nullptr, Tbth,Tbtl, 256);
        k_bmm3<3,1><<<dim3(4,8,16),256,0,stream>>>(zch,zcl, Tbth,Tbtl, nullptr,nullptr,
                                                   znh,znl, znth,zntl, 256);
      }
      unsigned short* tp;
      tp=zch; zch=znh; znh=tp;  tp=zcl; zcl=znl; znl=tp;
      tp=zcth; zcth=znth; znth=tp;  tp=zctl; zctl=zntl; zntl=tp;
    }
    k_attn3m<<<dim3(16,2,16),512,0,stream>>>(qlb, kb, vtb, pacc, pms);
    k_attn3vc<<<1024,256,0,stream>>>(pacc, pms, a3vth, a3vtl);
    k_bmm3<4,1><<<dim3(1,8,16),256,0,stream>>>(zch,zcl, a3vth,a3vtl, nullptr,nullptr,
                                               nullptr,nullptr, w2t,nullptr, 64);
    k_attn1m<<<dim3(64,16),512,0,stream>>>(qb, klb, w2t, aohb);
    k_resconv2<<<dim3(512,16),256,0,stream>>>(vtb, resw, aohb);
    k_wconv_t<<<dim3(16,16),256,0,stream>>>(outw, wtp, 512, 512);
    k_mfma_gemm<2,3><<<dim3(4,256),256,0,stream>>>(aohb, wtp, 32768,512,512,
                                                   outb, hbuf, nullptr, nullptr);
  };

  // fc1: features -> bf16 (h2 overlay), then MFMA GEMM via global_load_lds
  unsigned short* featbf=(unsigned short*)h2;   // dead before PPEG
  k_f2bf4<<<32000,256,0,stream>>>(features, featbf, 32000*1024/4);
  k_wconv_t<<<dim3(32,16),256,0,stream>>>(fc1_w, wtf, 1024, 512);
  k_mfma_gemm<0,0><<<dim3(4,250),256,0,stream>>>(featbf, wtf, 32000,512,1024,
                                                 fc1_b, h, nullptr, nullptr);
  k_cls<<<4,256,0,stream>>>(cls_tok, h);

  // layer 1 attention (on h)
  nystrom(h, (const float*)d_in[4],(const float*)d_in[5],(const float*)d_in[6],
          (const float*)d_in[7],(const float*)d_in[8],(const float*)d_in[9]);

  // PPEG: combined-tap stencil h -> h2 (no copy-back; layer 2 runs on h2)
  {
    unsigned short* wcat=(unsigned short*)attn2;  // free at this point
    k_wprep<<<100,256,0,stream>>>(
        (const float*)d_in[10],(const float*)d_in[11],
        (const float*)d_in[12],(const float*)d_in[13],
        (const float*)d_in[14],(const float*)d_in[15], wcat);
    k_cpcls<<<4,256,0,stream>>>(h, h2);
    k_ppeg4<<<dim3(256,16,2),256,0,stream>>>(h, wcat, h2);
  }

  // layer 2 attention (on h2)
  nystrom(h2, (const float*)d_in[16],(const float*)d_in[17],(const float*)d_in[18],
          (const float*)d_in[19],(const float*)d_in[20],(const float*)d_in[21]);

  // final LN(h2[:,0]) @ fc2
  k_final<<<2,256,0,stream>>>(h2,(const float*)d_in[22],(const float*)d_in[23],
                              fc2_w, fc2_b, out);
}